// Round 6
// baseline (264.037 us; speedup 1.0000x reference)
//
#include <hip/hip_runtime.h>
#include <math.h>
#include <stdint.h>

#define N_NODES 50000
#define N_EDGES 800000
#define IN_FEATS 128
#define HIDDEN 64
#define SCAN_BLK 256
#define SCAN_ELEMS 1024  // 4 per thread
#define NREP 8           // histogram replicas (atomic line-contention / 8)

// --- replicated degree histogram: 4 edges/thread (int4), replica = (e>>8)&7 ---
__global__ __launch_bounds__(256) void deg_rep_kernel(const int* __restrict__ src,
                                                      const int* __restrict__ dst,
                                                      int* __restrict__ drep_out,
                                                      int* __restrict__ drep_in) {
    int t = blockIdx.x * 256 + threadIdx.x;
    int e0 = t * 4;
    if (e0 >= N_EDGES) return;
    int rN = ((e0 >> 8) & (NREP - 1)) * N_NODES;  // uniform within the 4-edge group
    int4 s4 = *reinterpret_cast<const int4*>(src + e0);
    int4 d4 = *reinterpret_cast<const int4*>(dst + e0);
    atomicAdd(&drep_out[rN + s4.x], 1);
    atomicAdd(&drep_out[rN + s4.y], 1);
    atomicAdd(&drep_out[rN + s4.z], 1);
    atomicAdd(&drep_out[rN + s4.w], 1);
    atomicAdd(&drep_in[rN + d4.x], 1);
    atomicAdd(&drep_in[rN + d4.y], 1);
    atomicAdd(&drep_in[rN + d4.z], 1);
    atomicAdd(&drep_in[rN + d4.w], 1);
}

// --- sum replicas -> deg_in (for scan) ; fused c_src/c_dst = rsqrt(max(deg,1)) ---
__global__ __launch_bounds__(256) void degsum_kernel(const int* __restrict__ drep_out,
                                                     const int* __restrict__ drep_in,
                                                     int* __restrict__ deg_in,
                                                     float* __restrict__ cs,
                                                     float* __restrict__ cd) {
    int v = blockIdx.x * 256 + threadIdx.x;
    if (v >= N_NODES) return;
    int so = 0, si = 0;
#pragma unroll
    for (int r = 0; r < NREP; ++r) {
        so += drep_out[r * N_NODES + v];
        si += drep_in[r * N_NODES + v];
    }
    deg_in[v] = si;
    cs[v] = rsqrtf(fmaxf((float)so, 1.0f));
    cd[v] = rsqrtf(fmaxf((float)si, 1.0f));
}

// --- scan stage 1: per-block exclusive scan of 1024 elements, emit block sums ---
__global__ __launch_bounds__(SCAN_BLK) void scan1_kernel(const int* __restrict__ deg,
                                                         int* __restrict__ offs,
                                                         int* __restrict__ bsum) {
    __shared__ int sums[SCAN_BLK];
    int t = threadIdx.x;
    int base = blockIdx.x * SCAN_ELEMS + t * 4;
    int d0 = (base + 0 < N_NODES) ? deg[base + 0] : 0;
    int d1 = (base + 1 < N_NODES) ? deg[base + 1] : 0;
    int d2 = (base + 2 < N_NODES) ? deg[base + 2] : 0;
    int d3 = (base + 3 < N_NODES) ? deg[base + 3] : 0;
    sums[t] = d0 + d1 + d2 + d3;
    __syncthreads();
    for (int o = 1; o < SCAN_BLK; o <<= 1) {
        int v = (t >= o) ? sums[t - o] : 0;
        __syncthreads();
        sums[t] += v;
        __syncthreads();
    }
    int excl = (t == 0) ? 0 : sums[t - 1];
    if (base + 0 < N_NODES) offs[base + 0] = excl;
    if (base + 1 < N_NODES) offs[base + 1] = excl + d0;
    if (base + 2 < N_NODES) offs[base + 2] = excl + d0 + d1;
    if (base + 3 < N_NODES) offs[base + 3] = excl + d0 + d1 + d2;
    if (t == SCAN_BLK - 1) bsum[blockIdx.x] = sums[SCAN_BLK - 1];
}

// --- scan stage 2: single wave exclusive scan of block sums (nb <= 64) ---
__global__ __launch_bounds__(64) void scan2_kernel(int* __restrict__ bsum, int nb) {
    int t = threadIdx.x;
    int v = (t < nb) ? bsum[t] : 0;
    int s = v;
#pragma unroll
    for (int o = 1; o < 64; o <<= 1) {
        int u = __shfl_up(s, o, 64);
        if (t >= o) s += u;
    }
    if (t < nb) bsum[t] = s - v;  // exclusive
}

// --- scan stage 3: finalize offs AND per-replica base offsets ---
__global__ __launch_bounds__(256) void scan3_base_kernel(int* __restrict__ offs,
                                                         const int* __restrict__ bsum,
                                                         const int* __restrict__ drep_in,
                                                         int* __restrict__ baserep) {
    int i = blockIdx.x * 256 + threadIdx.x;
    if (i >= N_NODES) return;
    int off = offs[i] + bsum[i >> 10];  // SCAN_ELEMS = 1024
    offs[i] = off;
    int run = off;
#pragma unroll
    for (int r = 0; r < NREP; ++r) {
        baserep[r * N_NODES + i] = run;
        run += drep_in[r * N_NODES + i];
    }
    if (i == 0) offs[N_NODES] = N_EDGES;  // every dst < N, total = N_EDGES
}

// --- fill CSR, replica-partitioned: 4 edges/thread, same e->r map as deg_rep ---
__global__ __launch_bounds__(256) void bucket_rep_kernel(const int* __restrict__ src,
                                                         const int* __restrict__ dst,
                                                         const int* __restrict__ baserep,
                                                         int* __restrict__ cntrep,
                                                         int* __restrict__ csr_src) {
    int t = blockIdx.x * 256 + threadIdx.x;
    int e0 = t * 4;
    if (e0 >= N_EDGES) return;
    int rN = ((e0 >> 8) & (NREP - 1)) * N_NODES;
    int4 s4 = *reinterpret_cast<const int4*>(src + e0);
    int4 d4 = *reinterpret_cast<const int4*>(dst + e0);
    int p0 = atomicAdd(&cntrep[rN + d4.x], 1);
    int p1 = atomicAdd(&cntrep[rN + d4.y], 1);
    int p2 = atomicAdd(&cntrep[rN + d4.z], 1);
    int p3 = atomicAdd(&cntrep[rN + d4.w], 1);
    csr_src[baserep[rN + d4.x] + p0] = s4.x;
    csr_src[baserep[rN + d4.y] + p1] = s4.y;
    csr_src[baserep[rN + d4.z] + p2] = s4.z;
    csr_src[baserep[rN + d4.w] + p3] = s4.w;
}

// --- y[v,:] = c_src[v] * (h[v,:] @ W) ---
// LDS-tiled: 32-row x tile staged coalesced; W as float4 per (k-quad, col).
// k4 loop unrolled only 2x: full unroll spilled (VGPR=256, 800 MB scratch, 4x slower).
template <int K>
__global__ __launch_bounds__(256) void gemm_scaled_kernel(const float* __restrict__ h,
                                                          const float* __restrict__ c_src,
                                                          const float* __restrict__ W,
                                                          float* __restrict__ y) {
    constexpr int KQ = K / 4;  // float4s per row
    __shared__ float4 Ws4[KQ * HIDDEN];
    __shared__ float4 Xs[32 * KQ];
    for (int idx = threadIdx.x; idx < KQ * HIDDEN; idx += 256) {
        int k4 = idx >> 6, col = idx & 63;
        Ws4[idx] = make_float4(W[(4 * k4 + 0) * HIDDEN + col], W[(4 * k4 + 1) * HIDDEN + col],
                               W[(4 * k4 + 2) * HIDDEN + col], W[(4 * k4 + 3) * HIDDEN + col]);
    }
    int wid = threadIdx.x >> 6, lane = threadIdx.x & 63;
    for (int base = blockIdx.x * 32; base < N_NODES; base += gridDim.x * 32) {
        int nrows = min(32, N_NODES - base);
        __syncthreads();  // Xs reuse + (first iter) W ready
        const float4* src4 = reinterpret_cast<const float4*>(h + (size_t)base * K);
        for (int idx = threadIdx.x; idx < nrows * KQ; idx += 256) Xs[idx] = src4[idx];
        __syncthreads();
        int r0 = wid * 8;
        if (base + r0 >= N_NODES) continue;
        float acc[8] = {0.f, 0.f, 0.f, 0.f, 0.f, 0.f, 0.f, 0.f};
#pragma unroll 2
        for (int k4 = 0; k4 < KQ; ++k4) {
            float4 w = Ws4[k4 * 64 + lane];
#pragma unroll
            for (int r = 0; r < 8; ++r) {
                float4 a = Xs[(r0 + r) * KQ + k4];
                acc[r] = fmaf(a.x, w.x, fmaf(a.y, w.y, fmaf(a.z, w.z, fmaf(a.w, w.w, acc[r]))));
            }
        }
#pragma unroll
        for (int r = 0; r < 8; ++r) {
            int row = base + r0 + r;
            if (row < N_NODES) y[(size_t)row * HIDDEN + lane] = acc[r] * c_src[row];
        }
    }
}

// --- layer1 aggregate: 4 edges/iter per wave (4 slots x 16 lanes x float4) + bias/relu ---
__global__ __launch_bounds__(256) void gather_relu_kernel(const float* __restrict__ y,
                                                          const int* __restrict__ offs,
                                                          const int* __restrict__ csr_src,
                                                          const float* __restrict__ c_dst,
                                                          const float* __restrict__ b1,
                                                          float* __restrict__ h) {
    int wid = threadIdx.x >> 6, l = threadIdx.x & 63;
    int g = l >> 4, q = l & 15;
    int v = blockIdx.x * 4 + wid;  // grid exact: 12500 * 4 = 50000
    int beg = offs[v], end = offs[v + 1];
    float4 acc = make_float4(0.f, 0.f, 0.f, 0.f);
    int k = beg;
    for (; k + 4 <= end; k += 4) {
        int s = csr_src[k + g];
        float4 vy = *reinterpret_cast<const float4*>(y + (long)s * HIDDEN + q * 4);
        acc.x += vy.x; acc.y += vy.y; acc.z += vy.z; acc.w += vy.w;
    }
    int rem = end - k;
    if (g < rem) {
        int s = csr_src[k + g];
        float4 vy = *reinterpret_cast<const float4*>(y + (long)s * HIDDEN + q * 4);
        acc.x += vy.x; acc.y += vy.y; acc.z += vy.z; acc.w += vy.w;
    }
    // combine the 4 slots: lanes {q, q+16, q+32, q+48}
    acc.x += __shfl_xor(acc.x, 16, 64); acc.y += __shfl_xor(acc.y, 16, 64);
    acc.z += __shfl_xor(acc.z, 16, 64); acc.w += __shfl_xor(acc.w, 16, 64);
    acc.x += __shfl_xor(acc.x, 32, 64); acc.y += __shfl_xor(acc.y, 32, 64);
    acc.z += __shfl_xor(acc.z, 32, 64); acc.w += __shfl_xor(acc.w, 32, 64);
    if (g == 0) {
        float c = c_dst[v];
        float4 b = *reinterpret_cast<const float4*>(b1 + q * 4);
        float4 r;
        r.x = fmaxf(fmaf(c, acc.x, b.x), 0.f);
        r.y = fmaxf(fmaf(c, acc.y, b.y), 0.f);
        r.z = fmaxf(fmaf(c, acc.z, b.z), 0.f);
        r.w = fmaxf(fmaf(c, acc.w, b.w), 0.f);
        *reinterpret_cast<float4*>(h + (long)v * HIDDEN + q * 4) = r;
    }
}

// --- layer2 aggregate + bias + We dot-products -> a_s, a_d ---
__global__ __launch_bounds__(256) void gather_logit_kernel(const float* __restrict__ y,
                                                           const int* __restrict__ offs,
                                                           const int* __restrict__ csr_src,
                                                           const float* __restrict__ c_dst,
                                                           const float* __restrict__ b2,
                                                           const float* __restrict__ We,
                                                           float* __restrict__ a_s,
                                                           float* __restrict__ a_d) {
    int wid = threadIdx.x >> 6, l = threadIdx.x & 63;
    int g = l >> 4, q = l & 15;
    int v = blockIdx.x * 4 + wid;
    int beg = offs[v], end = offs[v + 1];
    float4 acc = make_float4(0.f, 0.f, 0.f, 0.f);
    int k = beg;
    for (; k + 4 <= end; k += 4) {
        int s = csr_src[k + g];
        float4 vy = *reinterpret_cast<const float4*>(y + (long)s * HIDDEN + q * 4);
        acc.x += vy.x; acc.y += vy.y; acc.z += vy.z; acc.w += vy.w;
    }
    int rem = end - k;
    if (g < rem) {
        int s = csr_src[k + g];
        float4 vy = *reinterpret_cast<const float4*>(y + (long)s * HIDDEN + q * 4);
        acc.x += vy.x; acc.y += vy.y; acc.z += vy.z; acc.w += vy.w;
    }
    acc.x += __shfl_xor(acc.x, 16, 64); acc.y += __shfl_xor(acc.y, 16, 64);
    acc.z += __shfl_xor(acc.z, 16, 64); acc.w += __shfl_xor(acc.w, 16, 64);
    acc.x += __shfl_xor(acc.x, 32, 64); acc.y += __shfl_xor(acc.y, 32, 64);
    acc.z += __shfl_xor(acc.z, 32, 64); acc.w += __shfl_xor(acc.w, 32, 64);
    float c = c_dst[v];
    float4 b = *reinterpret_cast<const float4*>(b2 + q * 4);
    float4 ws = *reinterpret_cast<const float4*>(We + q * 4);
    float4 wd = *reinterpret_cast<const float4*>(We + HIDDEN + q * 4);
    float hx = fmaf(c, acc.x, b.x), hy = fmaf(c, acc.y, b.y);
    float hz = fmaf(c, acc.z, b.z), hw = fmaf(c, acc.w, b.w);
    float ps = hx * ws.x + hy * ws.y + hz * ws.z + hw * ws.w;
    float pd = hx * wd.x + hy * wd.y + hz * wd.z + hw * wd.w;
    // reduce within 16-lane group (garbage in slots g>0 never crosses in)
#pragma unroll
    for (int o = 1; o <= 8; o <<= 1) {
        ps += __shfl_xor(ps, o, 64);
        pd += __shfl_xor(pd, o, 64);
    }
    if (l == 0) {
        a_s[v] = ps;
        a_d[v] = pd;
    }
}

// --- out[e] = sigmoid(a_s[src] + a_d[dst] + efeat.Wf + be) ---
__global__ __launch_bounds__(256) void edge_out_kernel(const int* __restrict__ src,
                                                       const int* __restrict__ dst,
                                                       const float* __restrict__ efeat,
                                                       const float* __restrict__ We,
                                                       const float* __restrict__ be,
                                                       const float* __restrict__ a_s,
                                                       const float* __restrict__ a_d,
                                                       float* __restrict__ out) {
    int e = blockIdx.x * 256 + threadIdx.x;
    if (e >= N_EDGES) return;
    float logit = a_s[src[e]] + a_d[dst[e]]
                + efeat[(long)e * 3 + 0] * We[2 * HIDDEN + 0]
                + efeat[(long)e * 3 + 1] * We[2 * HIDDEN + 1]
                + efeat[(long)e * 3 + 2] * We[2 * HIDDEN + 2]
                + be[0];
    out[e] = 1.0f / (1.0f + expf(-logit));
}

extern "C" void kernel_launch(void* const* d_in, const int* in_sizes, int n_in,
                              void* d_out, int out_size, void* d_ws, size_t ws_size,
                              hipStream_t stream) {
    const float* x     = (const float*)d_in[0];
    const float* efeat = (const float*)d_in[1];
    const int*   src   = (const int*)d_in[2];
    const int*   dst   = (const int*)d_in[3];
    const float* W1    = (const float*)d_in[4];
    const float* b1    = (const float*)d_in[5];
    const float* W2    = (const float*)d_in[6];
    const float* b2    = (const float*)d_in[7];
    const float* We    = (const float*)d_in[8];
    const float* be    = (const float*)d_in[9];
    float* out = (float*)d_out;

    // 256B-aligned workspace carve-up (float4/int4 paths require 16B alignment)
    char* p = (char*)d_ws;
    auto alloc = [&](size_t bytes) {
        char* r = p;
        p += (bytes + 255) & ~(size_t)255;
        return r;
    };
    float* c_src   = (float*)alloc((size_t)N_NODES * 4);
    float* c_dst   = (float*)alloc((size_t)N_NODES * 4);
    float* a_s     = (float*)alloc((size_t)N_NODES * 4);
    float* a_d     = (float*)alloc((size_t)N_NODES * 4);
    int*   deg_in  = (int*)alloc((size_t)N_NODES * 4);
    int*   offs    = (int*)alloc((size_t)(N_NODES + 1) * 4);
    int*   bsum    = (int*)alloc(64 * 4);
    int*   csr_src = (int*)alloc((size_t)N_EDGES * 4);
    float* bufA    = (float*)alloc((size_t)N_NODES * HIDDEN * 4);
    float* bufB    = (float*)alloc((size_t)N_NODES * HIDDEN * 4);

    // CSR-build replicas live inside bufA (12.8 MB; unused until GEMM1 writes it):
    // [drep_out 8N | drep_in 8N | cntrep 8N] ints = 9.6 MB, then baserep 8N in bufB head.
    int* drep_out = (int*)bufA;
    int* drep_in  = drep_out + NREP * N_NODES;
    int* cntrep   = drep_in + NREP * N_NODES;
    int* baserep  = (int*)bufB;

    const int NB_SCAN = (N_NODES + SCAN_ELEMS - 1) / SCAN_ELEMS;  // 49
    const int NB_E4   = (N_EDGES / 4 + 255) / 256;                // 782
    const int NB_V    = (N_NODES + 255) / 256;                    // 196

    // degrees (replicated) -> deg_in, c_src, c_dst ; CSR build (replica-partitioned)
    hipMemsetAsync(drep_out, 0, (size_t)3 * NREP * N_NODES * 4, stream);
    deg_rep_kernel<<<NB_E4, 256, 0, stream>>>(src, dst, drep_out, drep_in);
    degsum_kernel<<<NB_V, 256, 0, stream>>>(drep_out, drep_in, deg_in, c_src, c_dst);
    scan1_kernel<<<NB_SCAN, SCAN_BLK, 0, stream>>>(deg_in, offs, bsum);
    scan2_kernel<<<1, 64, 0, stream>>>(bsum, NB_SCAN);
    scan3_base_kernel<<<NB_V, 256, 0, stream>>>(offs, bsum, drep_in, baserep);
    bucket_rep_kernel<<<NB_E4, 256, 0, stream>>>(src, dst, baserep, cntrep, csr_src);

    // layer 1: y1 = (x*c_src)@W1 ; h1 = relu(c_dst * gather + b1)
    const int NT1 = (N_NODES + 31) / 32;  // 1563 tiles
    gemm_scaled_kernel<IN_FEATS><<<NT1, 256, 0, stream>>>(x, c_src, W1, bufA);
    gather_relu_kernel<<<N_NODES / 4, 256, 0, stream>>>(bufA, offs, csr_src, c_dst, b1, bufB);

    // layer 2: y2 = (h1*c_src)@W2 ; fused gather + bias + We-dot -> a_s/a_d
    gemm_scaled_kernel<HIDDEN><<<NT1, 256, 0, stream>>>(bufB, c_src, W2, bufA);
    gather_logit_kernel<<<N_NODES / 4, 256, 0, stream>>>(bufA, offs, csr_src, c_dst, b2, We, a_s, a_d);

    // edge output
    edge_out_kernel<<<N_EDGES / 256, 256, 0, stream>>>(src, dst, efeat, We, be, a_s, a_d, out);
}

// Round 7
// 198.390 us; speedup vs baseline: 1.3309x; 1.3309x over previous
//
#include <hip/hip_runtime.h>
#include <math.h>
#include <stdint.h>

#define N_NODES 50000
#define N_EDGES 800000
#define IN_FEATS 128
#define HIDDEN 64
#define SCAN_BLK 256
#define SCAN_ELEMS 1024  // 4 per thread

// CSR build partitioning: 8 node-ranges x 32 edge-chunks, all counting in LDS.
// Rationale (r6 post-mortem): device atomics write ~32B through to HBM each
// (WRITE_SIZE == n_atomics*32, invariant under 8x replication) -> reduce atomic
// COUNT to zero, don't spread them.
#define RSPLIT 8
#define CSPLIT 32
#define RANGE (N_NODES / RSPLIT)   // 6250 nodes per range (2x25KB LDS hist)
#define CHUNK (N_EDGES / CSPLIT)   // 25000 edges per chunk (exact)

// --- per-(range,chunk) in/out degree histograms in LDS; plain stores out ---
__global__ __launch_bounds__(256) void hist_kernel(const int* __restrict__ src,
                                                   const int* __restrict__ dst,
                                                   int* __restrict__ partial_out,
                                                   int* __restrict__ partial_in) {
    __shared__ int ho[RANGE];
    __shared__ int hi_[RANGE];
    int r = blockIdx.x & (RSPLIT - 1);
    int c = blockIdx.x >> 3;
    int lo = r * RANGE;
    for (int i = threadIdx.x; i < RANGE; i += 256) { ho[i] = 0; hi_[i] = 0; }
    __syncthreads();
    const int4* s4 = reinterpret_cast<const int4*>(src + c * CHUNK);
    const int4* d4 = reinterpret_cast<const int4*>(dst + c * CHUNK);
    for (int i = threadIdx.x; i < CHUNK / 4; i += 256) {
        int4 s = s4[i], d = d4[i];
        unsigned u;
        u = (unsigned)(s.x - lo); if (u < RANGE) atomicAdd(&ho[u], 1);
        u = (unsigned)(s.y - lo); if (u < RANGE) atomicAdd(&ho[u], 1);
        u = (unsigned)(s.z - lo); if (u < RANGE) atomicAdd(&ho[u], 1);
        u = (unsigned)(s.w - lo); if (u < RANGE) atomicAdd(&ho[u], 1);
        u = (unsigned)(d.x - lo); if (u < RANGE) atomicAdd(&hi_[u], 1);
        u = (unsigned)(d.y - lo); if (u < RANGE) atomicAdd(&hi_[u], 1);
        u = (unsigned)(d.z - lo); if (u < RANGE) atomicAdd(&hi_[u], 1);
        u = (unsigned)(d.w - lo); if (u < RANGE) atomicAdd(&hi_[u], 1);
    }
    __syncthreads();
    for (int i = threadIdx.x; i < RANGE; i += 256) {
        partial_out[c * N_NODES + lo + i] = ho[i];
        partial_in[c * N_NODES + lo + i] = hi_[i];
    }
}

// --- sum partials -> deg_in (for scan) ; fused c_src/c_dst = rsqrt(max(deg,1)) ---
__global__ __launch_bounds__(256) void degsum_kernel(const int* __restrict__ partial_out,
                                                     const int* __restrict__ partial_in,
                                                     int* __restrict__ deg_in,
                                                     float* __restrict__ cs,
                                                     float* __restrict__ cd) {
    int v = blockIdx.x * 256 + threadIdx.x;
    if (v >= N_NODES) return;
    int so = 0, si = 0;
#pragma unroll
    for (int c = 0; c < CSPLIT; ++c) {
        so += partial_out[c * N_NODES + v];
        si += partial_in[c * N_NODES + v];
    }
    deg_in[v] = si;
    cs[v] = rsqrtf(fmaxf((float)so, 1.0f));
    cd[v] = rsqrtf(fmaxf((float)si, 1.0f));
}

// --- scan stage 1: per-block exclusive scan of 1024 elements, emit block sums ---
__global__ __launch_bounds__(SCAN_BLK) void scan1_kernel(const int* __restrict__ deg,
                                                         int* __restrict__ offs,
                                                         int* __restrict__ bsum) {
    __shared__ int sums[SCAN_BLK];
    int t = threadIdx.x;
    int base = blockIdx.x * SCAN_ELEMS + t * 4;
    int d0 = (base + 0 < N_NODES) ? deg[base + 0] : 0;
    int d1 = (base + 1 < N_NODES) ? deg[base + 1] : 0;
    int d2 = (base + 2 < N_NODES) ? deg[base + 2] : 0;
    int d3 = (base + 3 < N_NODES) ? deg[base + 3] : 0;
    sums[t] = d0 + d1 + d2 + d3;
    __syncthreads();
    for (int o = 1; o < SCAN_BLK; o <<= 1) {
        int v = (t >= o) ? sums[t - o] : 0;
        __syncthreads();
        sums[t] += v;
        __syncthreads();
    }
    int excl = (t == 0) ? 0 : sums[t - 1];
    if (base + 0 < N_NODES) offs[base + 0] = excl;
    if (base + 1 < N_NODES) offs[base + 1] = excl + d0;
    if (base + 2 < N_NODES) offs[base + 2] = excl + d0 + d1;
    if (base + 3 < N_NODES) offs[base + 3] = excl + d0 + d1 + d2;
    if (t == SCAN_BLK - 1) bsum[blockIdx.x] = sums[SCAN_BLK - 1];
}

// --- scan stage 2: single wave exclusive scan of block sums (nb <= 64) ---
__global__ __launch_bounds__(64) void scan2_kernel(int* __restrict__ bsum, int nb) {
    int t = threadIdx.x;
    int v = (t < nb) ? bsum[t] : 0;
    int s = v;
#pragma unroll
    for (int o = 1; o < 64; o <<= 1) {
        int u = __shfl_up(s, o, 64);
        if (t >= o) s += u;
    }
    if (t < nb) bsum[t] = s - v;  // exclusive
}

// --- scan stage 3: finalize offs AND per-chunk base offsets base[c][v] ---
__global__ __launch_bounds__(256) void scan3_base_kernel(int* __restrict__ offs,
                                                         const int* __restrict__ bsum,
                                                         const int* __restrict__ partial_in,
                                                         int* __restrict__ base) {
    int v = blockIdx.x * 256 + threadIdx.x;
    if (v >= N_NODES) return;
    int off = offs[v] + bsum[v >> 10];  // SCAN_ELEMS = 1024
    offs[v] = off;
    int run = off;
#pragma unroll
    for (int c = 0; c < CSPLIT; ++c) {
        base[c * N_NODES + v] = run;
        run += partial_in[c * N_NODES + v];
    }
    if (v == 0) offs[N_NODES] = N_EDGES;  // every dst < N, total = N_EDGES
}

// --- CSR fill, atomic-free (global): slot via LDS atomicAdd, unique by (c,v) ---
__global__ __launch_bounds__(256) void bucketp_kernel(const int* __restrict__ src,
                                                      const int* __restrict__ dst,
                                                      const int* __restrict__ base,
                                                      int* __restrict__ csr_src) {
    __shared__ int cnt[RANGE];
    int r = blockIdx.x & (RSPLIT - 1);
    int c = blockIdx.x >> 3;
    int lo = r * RANGE;
    for (int i = threadIdx.x; i < RANGE; i += 256) cnt[i] = 0;
    __syncthreads();
    const int4* s4 = reinterpret_cast<const int4*>(src + c * CHUNK);
    const int4* d4 = reinterpret_cast<const int4*>(dst + c * CHUNK);
    const int* basec = base + c * N_NODES;
    for (int i = threadIdx.x; i < CHUNK / 4; i += 256) {
        int4 s = s4[i], d = d4[i];
        unsigned u;
        u = (unsigned)(d.x - lo);
        if (u < RANGE) { int pos = atomicAdd(&cnt[u], 1); csr_src[basec[d.x] + pos] = s.x; }
        u = (unsigned)(d.y - lo);
        if (u < RANGE) { int pos = atomicAdd(&cnt[u], 1); csr_src[basec[d.y] + pos] = s.y; }
        u = (unsigned)(d.z - lo);
        if (u < RANGE) { int pos = atomicAdd(&cnt[u], 1); csr_src[basec[d.z] + pos] = s.z; }
        u = (unsigned)(d.w - lo);
        if (u < RANGE) { int pos = atomicAdd(&cnt[u], 1); csr_src[basec[d.w] + pos] = s.w; }
    }
}

// --- y[v,:] = c_src[v] * (h[v,:] @ W) ---
// LDS-tiled: 32-row x tile staged coalesced; W as float4 per (k-quad, col).
// k4 loop unrolled only 2x: full unroll spilled (VGPR=256, 800 MB scratch, 4x slower).
template <int K>
__global__ __launch_bounds__(256) void gemm_scaled_kernel(const float* __restrict__ h,
                                                          const float* __restrict__ c_src,
                                                          const float* __restrict__ W,
                                                          float* __restrict__ y) {
    constexpr int KQ = K / 4;  // float4s per row
    __shared__ float4 Ws4[KQ * HIDDEN];
    __shared__ float4 Xs[32 * KQ];
    for (int idx = threadIdx.x; idx < KQ * HIDDEN; idx += 256) {
        int k4 = idx >> 6, col = idx & 63;
        Ws4[idx] = make_float4(W[(4 * k4 + 0) * HIDDEN + col], W[(4 * k4 + 1) * HIDDEN + col],
                               W[(4 * k4 + 2) * HIDDEN + col], W[(4 * k4 + 3) * HIDDEN + col]);
    }
    int wid = threadIdx.x >> 6, lane = threadIdx.x & 63;
    for (int base = blockIdx.x * 32; base < N_NODES; base += gridDim.x * 32) {
        int nrows = min(32, N_NODES - base);
        __syncthreads();  // Xs reuse + (first iter) W ready
        const float4* src4 = reinterpret_cast<const float4*>(h + (size_t)base * K);
        for (int idx = threadIdx.x; idx < nrows * KQ; idx += 256) Xs[idx] = src4[idx];
        __syncthreads();
        int r0 = wid * 8;
        if (base + r0 >= N_NODES) continue;
        float acc[8] = {0.f, 0.f, 0.f, 0.f, 0.f, 0.f, 0.f, 0.f};
#pragma unroll 2
        for (int k4 = 0; k4 < KQ; ++k4) {
            float4 w = Ws4[k4 * 64 + lane];
#pragma unroll
            for (int r = 0; r < 8; ++r) {
                float4 a = Xs[(r0 + r) * KQ + k4];
                acc[r] = fmaf(a.x, w.x, fmaf(a.y, w.y, fmaf(a.z, w.z, fmaf(a.w, w.w, acc[r]))));
            }
        }
#pragma unroll
        for (int r = 0; r < 8; ++r) {
            int row = base + r0 + r;
            if (row < N_NODES) y[(size_t)row * HIDDEN + lane] = acc[r] * c_src[row];
        }
    }
}

// --- layer1 aggregate: 4 edges/iter per wave (4 slots x 16 lanes x float4) + bias/relu ---
__global__ __launch_bounds__(256) void gather_relu_kernel(const float* __restrict__ y,
                                                          const int* __restrict__ offs,
                                                          const int* __restrict__ csr_src,
                                                          const float* __restrict__ c_dst,
                                                          const float* __restrict__ b1,
                                                          float* __restrict__ h) {
    int wid = threadIdx.x >> 6, l = threadIdx.x & 63;
    int g = l >> 4, q = l & 15;
    int v = blockIdx.x * 4 + wid;  // grid exact: 12500 * 4 = 50000
    int beg = offs[v], end = offs[v + 1];
    float4 acc = make_float4(0.f, 0.f, 0.f, 0.f);
    int k = beg;
    for (; k + 4 <= end; k += 4) {
        int s = csr_src[k + g];
        float4 vy = *reinterpret_cast<const float4*>(y + (long)s * HIDDEN + q * 4);
        acc.x += vy.x; acc.y += vy.y; acc.z += vy.z; acc.w += vy.w;
    }
    int rem = end - k;
    if (g < rem) {
        int s = csr_src[k + g];
        float4 vy = *reinterpret_cast<const float4*>(y + (long)s * HIDDEN + q * 4);
        acc.x += vy.x; acc.y += vy.y; acc.z += vy.z; acc.w += vy.w;
    }
    // combine the 4 slots: lanes {q, q+16, q+32, q+48}
    acc.x += __shfl_xor(acc.x, 16, 64); acc.y += __shfl_xor(acc.y, 16, 64);
    acc.z += __shfl_xor(acc.z, 16, 64); acc.w += __shfl_xor(acc.w, 16, 64);
    acc.x += __shfl_xor(acc.x, 32, 64); acc.y += __shfl_xor(acc.y, 32, 64);
    acc.z += __shfl_xor(acc.z, 32, 64); acc.w += __shfl_xor(acc.w, 32, 64);
    if (g == 0) {
        float c = c_dst[v];
        float4 b = *reinterpret_cast<const float4*>(b1 + q * 4);
        float4 r;
        r.x = fmaxf(fmaf(c, acc.x, b.x), 0.f);
        r.y = fmaxf(fmaf(c, acc.y, b.y), 0.f);
        r.z = fmaxf(fmaf(c, acc.z, b.z), 0.f);
        r.w = fmaxf(fmaf(c, acc.w, b.w), 0.f);
        *reinterpret_cast<float4*>(h + (long)v * HIDDEN + q * 4) = r;
    }
}

// --- layer2 aggregate + bias + We dot-products -> a_s, a_d ---
__global__ __launch_bounds__(256) void gather_logit_kernel(const float* __restrict__ y,
                                                           const int* __restrict__ offs,
                                                           const int* __restrict__ csr_src,
                                                           const float* __restrict__ c_dst,
                                                           const float* __restrict__ b2,
                                                           const float* __restrict__ We,
                                                           float* __restrict__ a_s,
                                                           float* __restrict__ a_d) {
    int wid = threadIdx.x >> 6, l = threadIdx.x & 63;
    int g = l >> 4, q = l & 15;
    int v = blockIdx.x * 4 + wid;
    int beg = offs[v], end = offs[v + 1];
    float4 acc = make_float4(0.f, 0.f, 0.f, 0.f);
    int k = beg;
    for (; k + 4 <= end; k += 4) {
        int s = csr_src[k + g];
        float4 vy = *reinterpret_cast<const float4*>(y + (long)s * HIDDEN + q * 4);
        acc.x += vy.x; acc.y += vy.y; acc.z += vy.z; acc.w += vy.w;
    }
    int rem = end - k;
    if (g < rem) {
        int s = csr_src[k + g];
        float4 vy = *reinterpret_cast<const float4*>(y + (long)s * HIDDEN + q * 4);
        acc.x += vy.x; acc.y += vy.y; acc.z += vy.z; acc.w += vy.w;
    }
    acc.x += __shfl_xor(acc.x, 16, 64); acc.y += __shfl_xor(acc.y, 16, 64);
    acc.z += __shfl_xor(acc.z, 16, 64); acc.w += __shfl_xor(acc.w, 16, 64);
    acc.x += __shfl_xor(acc.x, 32, 64); acc.y += __shfl_xor(acc.y, 32, 64);
    acc.z += __shfl_xor(acc.z, 32, 64); acc.w += __shfl_xor(acc.w, 32, 64);
    float c = c_dst[v];
    float4 b = *reinterpret_cast<const float4*>(b2 + q * 4);
    float4 ws = *reinterpret_cast<const float4*>(We + q * 4);
    float4 wd = *reinterpret_cast<const float4*>(We + HIDDEN + q * 4);
    float hx = fmaf(c, acc.x, b.x), hy = fmaf(c, acc.y, b.y);
    float hz = fmaf(c, acc.z, b.z), hw = fmaf(c, acc.w, b.w);
    float ps = hx * ws.x + hy * ws.y + hz * ws.z + hw * ws.w;
    float pd = hx * wd.x + hy * wd.y + hz * wd.z + hw * wd.w;
    // reduce within 16-lane group (garbage in slots g>0 never crosses in)
#pragma unroll
    for (int o = 1; o <= 8; o <<= 1) {
        ps += __shfl_xor(ps, o, 64);
        pd += __shfl_xor(pd, o, 64);
    }
    if (l == 0) {
        a_s[v] = ps;
        a_d[v] = pd;
    }
}

// --- out[e] = sigmoid(a_s[src] + a_d[dst] + efeat.Wf + be), 4 edges/thread ---
__global__ __launch_bounds__(256) void edge_out_kernel(const int* __restrict__ src,
                                                       const int* __restrict__ dst,
                                                       const float* __restrict__ efeat,
                                                       const float* __restrict__ We,
                                                       const float* __restrict__ be,
                                                       const float* __restrict__ a_s,
                                                       const float* __restrict__ a_d,
                                                       float* __restrict__ out) {
    int t = blockIdx.x * 256 + threadIdx.x;
    int e0 = t * 4;
    if (e0 >= N_EDGES) return;
    float w0 = We[2 * HIDDEN + 0], w1 = We[2 * HIDDEN + 1], w2 = We[2 * HIDDEN + 2];
    float b = be[0];
    int4 s = *reinterpret_cast<const int4*>(src + e0);
    int4 d = *reinterpret_cast<const int4*>(dst + e0);
    const float4* f = reinterpret_cast<const float4*>(efeat + (long)e0 * 3);
    float4 f0 = f[0], f1 = f[1], f2 = f[2];
    float4 o;
    float z;
    z = a_s[s.x] + a_d[d.x] + f0.x * w0 + f0.y * w1 + f0.z * w2 + b;
    o.x = 1.0f / (1.0f + __expf(-z));
    z = a_s[s.y] + a_d[d.y] + f0.w * w0 + f1.x * w1 + f1.y * w2 + b;
    o.y = 1.0f / (1.0f + __expf(-z));
    z = a_s[s.z] + a_d[d.z] + f1.z * w0 + f1.w * w1 + f2.x * w2 + b;
    o.z = 1.0f / (1.0f + __expf(-z));
    z = a_s[s.w] + a_d[d.w] + f2.y * w0 + f2.z * w1 + f2.w * w2 + b;
    o.w = 1.0f / (1.0f + __expf(-z));
    *reinterpret_cast<float4*>(out + e0) = o;
}

extern "C" void kernel_launch(void* const* d_in, const int* in_sizes, int n_in,
                              void* d_out, int out_size, void* d_ws, size_t ws_size,
                              hipStream_t stream) {
    const float* x     = (const float*)d_in[0];
    const float* efeat = (const float*)d_in[1];
    const int*   src   = (const int*)d_in[2];
    const int*   dst   = (const int*)d_in[3];
    const float* W1    = (const float*)d_in[4];
    const float* b1    = (const float*)d_in[5];
    const float* W2    = (const float*)d_in[6];
    const float* b2    = (const float*)d_in[7];
    const float* We    = (const float*)d_in[8];
    const float* be    = (const float*)d_in[9];
    float* out = (float*)d_out;

    // 256B-aligned workspace carve-up (float4/int4 paths require 16B alignment)
    char* p = (char*)d_ws;
    auto alloc = [&](size_t bytes) {
        char* r = p;
        p += (bytes + 255) & ~(size_t)255;
        return r;
    };
    float* c_src   = (float*)alloc((size_t)N_NODES * 4);
    float* c_dst   = (float*)alloc((size_t)N_NODES * 4);
    float* a_s     = (float*)alloc((size_t)N_NODES * 4);
    float* a_d     = (float*)alloc((size_t)N_NODES * 4);
    int*   deg_in  = (int*)alloc((size_t)N_NODES * 4);
    int*   offs    = (int*)alloc((size_t)(N_NODES + 1) * 4);
    int*   bsum    = (int*)alloc(64 * 4);
    int*   csr_src = (int*)alloc((size_t)N_EDGES * 4);
    float* bufA    = (float*)alloc((size_t)N_NODES * HIDDEN * 4);
    float* bufB    = (float*)alloc((size_t)N_NODES * HIDDEN * 4);

    // CSR-build partials alias bufA/bufB (dead before GEMM1/gather write them):
    // partial_out, partial_in: CSPLIT*N ints = 6.4 MB each (bufA = 12.8 MB);
    // base: CSPLIT*N ints = 6.4 MB (bufB head). All fully overwritten -> no memset.
    int* partial_out = (int*)bufA;
    int* partial_in  = partial_out + CSPLIT * N_NODES;
    int* base        = (int*)bufB;

    const int NB_SCAN = (N_NODES + SCAN_ELEMS - 1) / SCAN_ELEMS;  // 49
    const int NB_V    = (N_NODES + 255) / 256;                    // 196

    // degrees + CSR, zero global atomics
    hist_kernel<<<RSPLIT * CSPLIT, 256, 0, stream>>>(src, dst, partial_out, partial_in);
    degsum_kernel<<<NB_V, 256, 0, stream>>>(partial_out, partial_in, deg_in, c_src, c_dst);
    scan1_kernel<<<NB_SCAN, SCAN_BLK, 0, stream>>>(deg_in, offs, bsum);
    scan2_kernel<<<1, 64, 0, stream>>>(bsum, NB_SCAN);
    scan3_base_kernel<<<NB_V, 256, 0, stream>>>(offs, bsum, partial_in, base);
    bucketp_kernel<<<RSPLIT * CSPLIT, 256, 0, stream>>>(src, dst, base, csr_src);

    // layer 1: y1 = (x*c_src)@W1 ; h1 = relu(c_dst * gather + b1)
    const int NT1 = (N_NODES + 31) / 32;  // 1563 tiles
    gemm_scaled_kernel<IN_FEATS><<<NT1, 256, 0, stream>>>(x, c_src, W1, bufA);
    gather_relu_kernel<<<N_NODES / 4, 256, 0, stream>>>(bufA, offs, csr_src, c_dst, b1, bufB);

    // layer 2: y2 = (h1*c_src)@W2 ; fused gather + bias + We-dot -> a_s/a_d
    gemm_scaled_kernel<HIDDEN><<<NT1, 256, 0, stream>>>(bufB, c_src, W2, bufA);
    gather_logit_kernel<<<N_NODES / 4, 256, 0, stream>>>(bufA, offs, csr_src, c_dst, b2, We, a_s, a_d);

    // edge output
    edge_out_kernel<<<(N_EDGES / 4 + 255) / 256, 256, 0, stream>>>(src, dst, efeat, We, be, a_s, a_d, out);
}

// Round 8
// 152.590 us; speedup vs baseline: 1.7304x; 1.3002x over previous
//
#include <hip/hip_runtime.h>
#include <math.h>
#include <stdint.h>

#define N_NODES 50000
#define N_EDGES 800000
#define IN_FEATS 128
#define HIDDEN 64
#define SCAN_BLK 256
#define SCAN_ELEMS 1024  // 4 per thread

// CSR build partitioning: 8 node-ranges x 32 edge-chunks, all counting in LDS.
// (r6 post-mortem: device atomics write ~32B through to HBM each; WRITE_SIZE
// was invariant under 8x replica spreading -> reduce atomic COUNT to zero.)
#define RSPLIT 8
#define CSPLIT 32
#define RANGE (N_NODES / RSPLIT)   // 6250 nodes per range (2x25KB LDS hist)
#define CHUNK (N_EDGES / CSPLIT)   // 25000 edges per chunk (exact)

// --- per-(range,chunk) in/out degree histograms in LDS; plain stores out ---
__global__ __launch_bounds__(256) void hist_kernel(const int* __restrict__ src,
                                                   const int* __restrict__ dst,
                                                   int* __restrict__ partial_out,
                                                   int* __restrict__ partial_in) {
    __shared__ int ho[RANGE];
    __shared__ int hi_[RANGE];
    int r = blockIdx.x & (RSPLIT - 1);
    int c = blockIdx.x >> 3;
    int lo = r * RANGE;
    for (int i = threadIdx.x; i < RANGE; i += 256) { ho[i] = 0; hi_[i] = 0; }
    __syncthreads();
    const int4* s4 = reinterpret_cast<const int4*>(src + c * CHUNK);
    const int4* d4 = reinterpret_cast<const int4*>(dst + c * CHUNK);
    for (int i = threadIdx.x; i < CHUNK / 4; i += 256) {
        int4 s = s4[i], d = d4[i];
        unsigned u;
        u = (unsigned)(s.x - lo); if (u < RANGE) atomicAdd(&ho[u], 1);
        u = (unsigned)(s.y - lo); if (u < RANGE) atomicAdd(&ho[u], 1);
        u = (unsigned)(s.z - lo); if (u < RANGE) atomicAdd(&ho[u], 1);
        u = (unsigned)(s.w - lo); if (u < RANGE) atomicAdd(&ho[u], 1);
        u = (unsigned)(d.x - lo); if (u < RANGE) atomicAdd(&hi_[u], 1);
        u = (unsigned)(d.y - lo); if (u < RANGE) atomicAdd(&hi_[u], 1);
        u = (unsigned)(d.z - lo); if (u < RANGE) atomicAdd(&hi_[u], 1);
        u = (unsigned)(d.w - lo); if (u < RANGE) atomicAdd(&hi_[u], 1);
    }
    __syncthreads();
    for (int i = threadIdx.x; i < RANGE; i += 256) {
        partial_out[c * N_NODES + lo + i] = ho[i];
        partial_in[c * N_NODES + lo + i] = hi_[i];
    }
}

// --- sum partials -> deg_in (for scan) ; fused c_src/c_dst = rsqrt(max(deg,1)) ---
__global__ __launch_bounds__(256) void degsum_kernel(const int* __restrict__ partial_out,
                                                     const int* __restrict__ partial_in,
                                                     int* __restrict__ deg_in,
                                                     float* __restrict__ cs,
                                                     float* __restrict__ cd) {
    int v = blockIdx.x * 256 + threadIdx.x;
    if (v >= N_NODES) return;
    int so = 0, si = 0;
#pragma unroll
    for (int c = 0; c < CSPLIT; ++c) {
        so += partial_out[c * N_NODES + v];
        si += partial_in[c * N_NODES + v];
    }
    deg_in[v] = si;
    cs[v] = rsqrtf(fmaxf((float)so, 1.0f));
    cd[v] = rsqrtf(fmaxf((float)si, 1.0f));
}

// --- scan stage 1: per-block exclusive scan of 1024 elements, emit block sums ---
__global__ __launch_bounds__(SCAN_BLK) void scan1_kernel(const int* __restrict__ deg,
                                                         int* __restrict__ offs,
                                                         int* __restrict__ bsum) {
    __shared__ int sums[SCAN_BLK];
    int t = threadIdx.x;
    int base = blockIdx.x * SCAN_ELEMS + t * 4;
    int d0 = (base + 0 < N_NODES) ? deg[base + 0] : 0;
    int d1 = (base + 1 < N_NODES) ? deg[base + 1] : 0;
    int d2 = (base + 2 < N_NODES) ? deg[base + 2] : 0;
    int d3 = (base + 3 < N_NODES) ? deg[base + 3] : 0;
    sums[t] = d0 + d1 + d2 + d3;
    __syncthreads();
    for (int o = 1; o < SCAN_BLK; o <<= 1) {
        int v = (t >= o) ? sums[t - o] : 0;
        __syncthreads();
        sums[t] += v;
        __syncthreads();
    }
    int excl = (t == 0) ? 0 : sums[t - 1];
    if (base + 0 < N_NODES) offs[base + 0] = excl;
    if (base + 1 < N_NODES) offs[base + 1] = excl + d0;
    if (base + 2 < N_NODES) offs[base + 2] = excl + d0 + d1;
    if (base + 3 < N_NODES) offs[base + 3] = excl + d0 + d1 + d2;
    if (t == SCAN_BLK - 1) bsum[blockIdx.x] = sums[SCAN_BLK - 1];
}

// --- scan stage 2: single wave exclusive scan of block sums (nb <= 64) ---
__global__ __launch_bounds__(64) void scan2_kernel(int* __restrict__ bsum, int nb) {
    int t = threadIdx.x;
    int v = (t < nb) ? bsum[t] : 0;
    int s = v;
#pragma unroll
    for (int o = 1; o < 64; o <<= 1) {
        int u = __shfl_up(s, o, 64);
        if (t >= o) s += u;
    }
    if (t < nb) bsum[t] = s - v;  // exclusive
}

// --- scan stage 3: finalize offs AND per-chunk base offsets base[c][v] ---
__global__ __launch_bounds__(256) void scan3_base_kernel(int* __restrict__ offs,
                                                         const int* __restrict__ bsum,
                                                         const int* __restrict__ partial_in,
                                                         int* __restrict__ base) {
    int v = blockIdx.x * 256 + threadIdx.x;
    if (v >= N_NODES) return;
    int off = offs[v] + bsum[v >> 10];  // SCAN_ELEMS = 1024
    offs[v] = off;
    int run = off;
#pragma unroll
    for (int c = 0; c < CSPLIT; ++c) {
        base[c * N_NODES + v] = run;
        run += partial_in[c * N_NODES + v];
    }
    if (v == 0) offs[N_NODES] = N_EDGES;  // every dst < N, total = N_EDGES
}

// --- CSR fill, atomic-free (global): slot via LDS atomicAdd, unique by (c,v) ---
__global__ __launch_bounds__(256) void bucketp_kernel(const int* __restrict__ src,
                                                      const int* __restrict__ dst,
                                                      const int* __restrict__ base,
                                                      int* __restrict__ csr_src) {
    __shared__ int cnt[RANGE];
    int r = blockIdx.x & (RSPLIT - 1);
    int c = blockIdx.x >> 3;
    int lo = r * RANGE;
    for (int i = threadIdx.x; i < RANGE; i += 256) cnt[i] = 0;
    __syncthreads();
    const int4* s4 = reinterpret_cast<const int4*>(src + c * CHUNK);
    const int4* d4 = reinterpret_cast<const int4*>(dst + c * CHUNK);
    const int* basec = base + c * N_NODES;
    for (int i = threadIdx.x; i < CHUNK / 4; i += 256) {
        int4 s = s4[i], d = d4[i];
        unsigned u;
        u = (unsigned)(d.x - lo);
        if (u < RANGE) { int pos = atomicAdd(&cnt[u], 1); csr_src[basec[d.x] + pos] = s.x; }
        u = (unsigned)(d.y - lo);
        if (u < RANGE) { int pos = atomicAdd(&cnt[u], 1); csr_src[basec[d.y] + pos] = s.y; }
        u = (unsigned)(d.z - lo);
        if (u < RANGE) { int pos = atomicAdd(&cnt[u], 1); csr_src[basec[d.z] + pos] = s.z; }
        u = (unsigned)(d.w - lo);
        if (u < RANGE) { int pos = atomicAdd(&cnt[u], 1); csr_src[basec[d.w] + pos] = s.w; }
    }
}

// --- w2s = W2@Ws, w2d = W2@Wd (64-vecs); w2c = {Ws.b2, Wd.b2} ---
__global__ __launch_bounds__(128) void w2prep_kernel(const float* __restrict__ W2,
                                                     const float* __restrict__ We,
                                                     const float* __restrict__ b2,
                                                     float* __restrict__ w2s,
                                                     float* __restrict__ w2d,
                                                     float* __restrict__ w2c) {
    int t = threadIdx.x;
    if (t < 64) {
        float s = 0.f, d = 0.f;
        for (int j = 0; j < HIDDEN; ++j) {
            float w = W2[t * HIDDEN + j];
            s = fmaf(w, We[j], s);
            d = fmaf(w, We[HIDDEN + j], d);
        }
        w2s[t] = s;
        w2d[t] = d;
    } else if (t == 64) {
        float s = 0.f, d = 0.f;
        for (int j = 0; j < HIDDEN; ++j) {
            s = fmaf(We[j], b2[j], s);
            d = fmaf(We[HIDDEN + j], b2[j], d);
        }
        w2c[0] = s;
        w2c[1] = d;
    }
}

// --- y[v,:] = c_src[v] * (h[v,:] @ W) ---
// LDS-tiled: 32-row x tile staged coalesced; W as float4 per (k-quad, col).
// k4 loop unrolled only 2x: full unroll spilled (VGPR=256, 800 MB scratch, 4x slower).
template <int K>
__global__ __launch_bounds__(256) void gemm_scaled_kernel(const float* __restrict__ h,
                                                          const float* __restrict__ c_src,
                                                          const float* __restrict__ W,
                                                          float* __restrict__ y) {
    constexpr int KQ = K / 4;  // float4s per row
    __shared__ float4 Ws4[KQ * HIDDEN];
    __shared__ float4 Xs[32 * KQ];
    for (int idx = threadIdx.x; idx < KQ * HIDDEN; idx += 256) {
        int k4 = idx >> 6, col = idx & 63;
        Ws4[idx] = make_float4(W[(4 * k4 + 0) * HIDDEN + col], W[(4 * k4 + 1) * HIDDEN + col],
                               W[(4 * k4 + 2) * HIDDEN + col], W[(4 * k4 + 3) * HIDDEN + col]);
    }
    int wid = threadIdx.x >> 6, lane = threadIdx.x & 63;
    for (int base = blockIdx.x * 32; base < N_NODES; base += gridDim.x * 32) {
        int nrows = min(32, N_NODES - base);
        __syncthreads();  // Xs reuse + (first iter) W ready
        const float4* src4 = reinterpret_cast<const float4*>(h + (size_t)base * K);
        for (int idx = threadIdx.x; idx < nrows * KQ; idx += 256) Xs[idx] = src4[idx];
        __syncthreads();
        int r0 = wid * 8;
        if (base + r0 >= N_NODES) continue;
        float acc[8] = {0.f, 0.f, 0.f, 0.f, 0.f, 0.f, 0.f, 0.f};
#pragma unroll 2
        for (int k4 = 0; k4 < KQ; ++k4) {
            float4 w = Ws4[k4 * 64 + lane];
#pragma unroll
            for (int r = 0; r < 8; ++r) {
                float4 a = Xs[(r0 + r) * KQ + k4];
                acc[r] = fmaf(a.x, w.x, fmaf(a.y, w.y, fmaf(a.z, w.z, fmaf(a.w, w.w, acc[r]))));
            }
        }
#pragma unroll
        for (int r = 0; r < 8; ++r) {
            int row = base + r0 + r;
            if (row < N_NODES) y[(size_t)row * HIDDEN + lane] = acc[r] * c_src[row];
        }
    }
}

// --- layer1 gather + fused h1/relu + layer-2 collapse to scalars:
//     agg(q) = sum over in-edges of y1[src]; h1 = relu(c_dst*agg + b1);
//     t[v] = c_src[v] * (h1 . w2s, h1 . w2d)   (h1 never stored) ---
__global__ __launch_bounds__(256) void gather_t_kernel(const float* __restrict__ y,
                                                       const int* __restrict__ offs,
                                                       const int* __restrict__ csr_src,
                                                       const float* __restrict__ c_src,
                                                       const float* __restrict__ c_dst,
                                                       const float* __restrict__ b1,
                                                       const float* __restrict__ w2s,
                                                       const float* __restrict__ w2d,
                                                       float2* __restrict__ t) {
    int wid = threadIdx.x >> 6, l = threadIdx.x & 63;
    int g = l >> 4, q = l & 15;
    int v = blockIdx.x * 4 + wid;  // grid exact: 12500 * 4 = 50000
    int beg = offs[v], end = offs[v + 1];
    float4 acc = make_float4(0.f, 0.f, 0.f, 0.f);
    int k = beg;
    // 8 edges in flight (2x unroll of the 4-slot scheme) for load-level parallelism
    for (; k + 8 <= end; k += 8) {
        int s0 = csr_src[k + g];
        int s1 = csr_src[k + 4 + g];
        float4 va = *reinterpret_cast<const float4*>(y + (long)s0 * HIDDEN + q * 4);
        float4 vb = *reinterpret_cast<const float4*>(y + (long)s1 * HIDDEN + q * 4);
        acc.x += va.x; acc.y += va.y; acc.z += va.z; acc.w += va.w;
        acc.x += vb.x; acc.y += vb.y; acc.z += vb.z; acc.w += vb.w;
    }
    if (k + 4 <= end) {
        int s = csr_src[k + g];
        float4 vy = *reinterpret_cast<const float4*>(y + (long)s * HIDDEN + q * 4);
        acc.x += vy.x; acc.y += vy.y; acc.z += vy.z; acc.w += vy.w;
        k += 4;
    }
    int rem = end - k;
    if (g < rem) {
        int s = csr_src[k + g];
        float4 vy = *reinterpret_cast<const float4*>(y + (long)s * HIDDEN + q * 4);
        acc.x += vy.x; acc.y += vy.y; acc.z += vy.z; acc.w += vy.w;
    }
    // combine the 4 slots: all lanes end with the full agg quad for their q
    acc.x += __shfl_xor(acc.x, 16, 64); acc.y += __shfl_xor(acc.y, 16, 64);
    acc.z += __shfl_xor(acc.z, 16, 64); acc.w += __shfl_xor(acc.w, 16, 64);
    acc.x += __shfl_xor(acc.x, 32, 64); acc.y += __shfl_xor(acc.y, 32, 64);
    acc.z += __shfl_xor(acc.z, 32, 64); acc.w += __shfl_xor(acc.w, 32, 64);
    float c = c_dst[v];
    float4 b = *reinterpret_cast<const float4*>(b1 + q * 4);
    float hx = fmaxf(fmaf(c, acc.x, b.x), 0.f);
    float hy = fmaxf(fmaf(c, acc.y, b.y), 0.f);
    float hz = fmaxf(fmaf(c, acc.z, b.z), 0.f);
    float hw = fmaxf(fmaf(c, acc.w, b.w), 0.f);
    float4 ws = *reinterpret_cast<const float4*>(w2s + q * 4);
    float4 wd = *reinterpret_cast<const float4*>(w2d + q * 4);
    float ps = hx * ws.x + hy * ws.y + hz * ws.z + hw * ws.w;
    float pd = hx * wd.x + hy * wd.y + hz * wd.z + hw * wd.w;
#pragma unroll
    for (int o = 1; o <= 8; o <<= 1) {
        ps += __shfl_xor(ps, o, 64);
        pd += __shfl_xor(pd, o, 64);
    }
    if (l == 0) {
        float cs = c_src[v];
        t[v] = make_float2(cs * ps, cs * pd);
    }
}

// --- layer2 scalar gather: a_s[v] = c_dst[v]*sum(t_s[src in-edges]) + Ws.b2 ---
__global__ __launch_bounds__(256) void gather2_kernel(const float2* __restrict__ t,
                                                      const int* __restrict__ offs,
                                                      const int* __restrict__ csr_src,
                                                      const float* __restrict__ c_dst,
                                                      const float* __restrict__ w2c,
                                                      float* __restrict__ a_s,
                                                      float* __restrict__ a_d) {
    int wid = threadIdx.x >> 6, l = threadIdx.x & 63;
    int sub = l >> 4, q = l & 15;
    int v = blockIdx.x * 16 + wid * 4 + sub;  // grid exact: 3125 * 16 = 50000
    int beg = offs[v], end = offs[v + 1];
    float ps = 0.f, pd = 0.f;
    for (int k = beg + q; k < end; k += 16) {
        float2 tv = t[csr_src[k]];
        ps += tv.x;
        pd += tv.y;
    }
#pragma unroll
    for (int o = 1; o <= 8; o <<= 1) {
        ps += __shfl_xor(ps, o, 64);
        pd += __shfl_xor(pd, o, 64);
    }
    if (q == 0) {
        float c = c_dst[v];
        a_s[v] = fmaf(c, ps, w2c[0]);
        a_d[v] = fmaf(c, pd, w2c[1]);
    }
}

// --- out[e] = sigmoid(a_s[src] + a_d[dst] + efeat.Wf + be), 4 edges/thread ---
__global__ __launch_bounds__(256) void edge_out_kernel(const int* __restrict__ src,
                                                       const int* __restrict__ dst,
                                                       const float* __restrict__ efeat,
                                                       const float* __restrict__ We,
                                                       const float* __restrict__ be,
                                                       const float* __restrict__ a_s,
                                                       const float* __restrict__ a_d,
                                                       float* __restrict__ out) {
    int t = blockIdx.x * 256 + threadIdx.x;
    int e0 = t * 4;
    if (e0 >= N_EDGES) return;
    float w0 = We[2 * HIDDEN + 0], w1 = We[2 * HIDDEN + 1], w2 = We[2 * HIDDEN + 2];
    float b = be[0];
    int4 s = *reinterpret_cast<const int4*>(src + e0);
    int4 d = *reinterpret_cast<const int4*>(dst + e0);
    const float4* f = reinterpret_cast<const float4*>(efeat + (long)e0 * 3);
    float4 f0 = f[0], f1 = f[1], f2 = f[2];
    float4 o;
    float z;
    z = a_s[s.x] + a_d[d.x] + f0.x * w0 + f0.y * w1 + f0.z * w2 + b;
    o.x = 1.0f / (1.0f + __expf(-z));
    z = a_s[s.y] + a_d[d.y] + f0.w * w0 + f1.x * w1 + f1.y * w2 + b;
    o.y = 1.0f / (1.0f + __expf(-z));
    z = a_s[s.z] + a_d[d.z] + f1.z * w0 + f1.w * w1 + f2.x * w2 + b;
    o.z = 1.0f / (1.0f + __expf(-z));
    z = a_s[s.w] + a_d[d.w] + f2.y * w0 + f2.z * w1 + f2.w * w2 + b;
    o.w = 1.0f / (1.0f + __expf(-z));
    *reinterpret_cast<float4*>(out + e0) = o;
}

extern "C" void kernel_launch(void* const* d_in, const int* in_sizes, int n_in,
                              void* d_out, int out_size, void* d_ws, size_t ws_size,
                              hipStream_t stream) {
    const float* x     = (const float*)d_in[0];
    const float* efeat = (const float*)d_in[1];
    const int*   src   = (const int*)d_in[2];
    const int*   dst   = (const int*)d_in[3];
    const float* W1    = (const float*)d_in[4];
    const float* b1    = (const float*)d_in[5];
    const float* W2    = (const float*)d_in[6];
    const float* b2    = (const float*)d_in[7];
    const float* We    = (const float*)d_in[8];
    const float* be    = (const float*)d_in[9];
    float* out = (float*)d_out;

    // 256B-aligned workspace carve-up (float4/int4 paths require 16B alignment)
    char* p = (char*)d_ws;
    auto alloc = [&](size_t bytes) {
        char* r = p;
        p += (bytes + 255) & ~(size_t)255;
        return r;
    };
    float* c_src   = (float*)alloc((size_t)N_NODES * 4);
    float* c_dst   = (float*)alloc((size_t)N_NODES * 4);
    float* a_s     = (float*)alloc((size_t)N_NODES * 4);
    float* a_d     = (float*)alloc((size_t)N_NODES * 4);
    int*   deg_in  = (int*)alloc((size_t)N_NODES * 4);
    int*   offs    = (int*)alloc((size_t)(N_NODES + 1) * 4);
    int*   bsum    = (int*)alloc(64 * 4);
    float* w2s     = (float*)alloc(HIDDEN * 4);
    float* w2d     = (float*)alloc(HIDDEN * 4);
    float* w2c     = (float*)alloc(2 * 4);
    int*   csr_src = (int*)alloc((size_t)N_EDGES * 4);
    float* bufA    = (float*)alloc((size_t)N_NODES * HIDDEN * 4);  // partials -> y1
    float* bufB    = (float*)alloc((size_t)CSPLIT * N_NODES * 4);  // base -> t

    // CSR-build partials alias bufA/bufB (dead before y1/t are written):
    int* partial_out = (int*)bufA;
    int* partial_in  = partial_out + CSPLIT * N_NODES;  // NOTE: 2*CSPLIT*N = 12.8MB = bufA exactly
    int* base        = (int*)bufB;
    float2* t        = (float2*)bufB;  // 400 KB, written after base is dead

    const int NB_SCAN = (N_NODES + SCAN_ELEMS - 1) / SCAN_ELEMS;  // 49
    const int NB_V    = (N_NODES + 255) / 256;                    // 196

    // degrees + CSR, zero global atomics
    hist_kernel<<<RSPLIT * CSPLIT, 256, 0, stream>>>(src, dst, partial_out, partial_in);
    degsum_kernel<<<NB_V, 256, 0, stream>>>(partial_out, partial_in, deg_in, c_src, c_dst);
    scan1_kernel<<<NB_SCAN, SCAN_BLK, 0, stream>>>(deg_in, offs, bsum);
    scan2_kernel<<<1, 64, 0, stream>>>(bsum, NB_SCAN);
    scan3_base_kernel<<<NB_V, 256, 0, stream>>>(offs, bsum, partial_in, base);
    bucketp_kernel<<<RSPLIT * CSPLIT, 256, 0, stream>>>(src, dst, base, csr_src);

    // layer-2 collapse precompute (independent of CSR)
    w2prep_kernel<<<1, 128, 0, stream>>>(W2, We, b2, w2s, w2d, w2c);

    // layer 1 GEMM: y1 = (x*c_src)@W1  (overwrites partials in bufA — after scan3)
    const int NT1 = (N_NODES + 31) / 32;  // 1563 tiles
    gemm_scaled_kernel<IN_FEATS><<<NT1, 256, 0, stream>>>(x, c_src, W1, bufA);

    // fused gather1 + relu + layer-2 dots -> t  (overwrites base in bufB — after bucketp)
    gather_t_kernel<<<N_NODES / 4, 256, 0, stream>>>(bufA, offs, csr_src, c_src, c_dst,
                                                     b1, w2s, w2d, t);

    // layer-2 scalar gather -> a_s, a_d
    gather2_kernel<<<N_NODES / 16, 256, 0, stream>>>(t, offs, csr_src, c_dst, w2c, a_s, a_d);

    // edge output
    edge_out_kernel<<<(N_EDGES / 4 + 255) / 256, 256, 0, stream>>>(src, dst, efeat, We, be,
                                                                   a_s, a_d, out);
}

// Round 9
// 127.152 us; speedup vs baseline: 2.0766x; 1.2001x over previous
//
#include <hip/hip_runtime.h>
#include <math.h>
#include <stdint.h>

#define N_NODES 50000
#define N_EDGES 800000
#define IN_FEATS 128
#define HIDDEN 64
#define SCAN_BLK 256
#define SCAN_ELEMS 1024  // 4 per thread

// CSR build: 32 edge-chunks x (in|out) x 2 node-halves, counts in LDS (packed
// 2 nodes per u32 -- max per-chunk count 25000 < 2^15, no cross-half carry).
// The in-histogram pass ALSO emits each edge's slot index (epos, u16) so the
// CSR fill is a single coalesced pass (no 8x edge re-scan, no global atomics).
#define CSPLIT 32
#define CHUNK (N_EDGES / CSPLIT)   // 25000 edges, exact
#define NHALF (N_NODES / 2)        // 25000 nodes per half
#define NHWORDS (NHALF / 2)        // 12500 packed u32 (50 KB LDS)

// --- per-(chunk, kind, half) packed histograms in LDS; epos out for kind=in ---
__global__ __launch_bounds__(256) void hist2_kernel(const int* __restrict__ src,
                                                    const int* __restrict__ dst,
                                                    unsigned short* __restrict__ epos,
                                                    unsigned* __restrict__ pin,
                                                    unsigned* __restrict__ pout) {
    __shared__ unsigned cnt[NHWORDS];
    int b = blockIdx.x;            // 128 blocks
    int c = b >> 2;
    int kind = (b >> 1) & 1;       // 0 = in (dst) + epos, 1 = out (src)
    int half = b & 1;
    int lo = half * NHALF;
    for (int i = threadIdx.x; i < NHWORDS; i += 256) cnt[i] = 0;
    __syncthreads();
    if (kind == 0) {
        const int4* d4 = reinterpret_cast<const int4*>(dst + c * CHUNK);
        for (int i = threadIdx.x; i < CHUNK / 4; i += 256) {
            int4 d = d4[i];
            int e = c * CHUNK + i * 4;
            unsigned u, old;
            u = (unsigned)(d.x - lo);
            if (u < NHALF) { old = atomicAdd(&cnt[u >> 1], 1u << ((u & 1) * 16));
                             epos[e + 0] = (unsigned short)(old >> ((u & 1) * 16)); }
            u = (unsigned)(d.y - lo);
            if (u < NHALF) { old = atomicAdd(&cnt[u >> 1], 1u << ((u & 1) * 16));
                             epos[e + 1] = (unsigned short)(old >> ((u & 1) * 16)); }
            u = (unsigned)(d.z - lo);
            if (u < NHALF) { old = atomicAdd(&cnt[u >> 1], 1u << ((u & 1) * 16));
                             epos[e + 2] = (unsigned short)(old >> ((u & 1) * 16)); }
            u = (unsigned)(d.w - lo);
            if (u < NHALF) { old = atomicAdd(&cnt[u >> 1], 1u << ((u & 1) * 16));
                             epos[e + 3] = (unsigned short)(old >> ((u & 1) * 16)); }
        }
    } else {
        const int4* s4 = reinterpret_cast<const int4*>(src + c * CHUNK);
        for (int i = threadIdx.x; i < CHUNK / 4; i += 256) {
            int4 s = s4[i];
            unsigned u;
            u = (unsigned)(s.x - lo); if (u < NHALF) atomicAdd(&cnt[u >> 1], 1u << ((u & 1) * 16));
            u = (unsigned)(s.y - lo); if (u < NHALF) atomicAdd(&cnt[u >> 1], 1u << ((u & 1) * 16));
            u = (unsigned)(s.z - lo); if (u < NHALF) atomicAdd(&cnt[u >> 1], 1u << ((u & 1) * 16));
            u = (unsigned)(s.w - lo); if (u < NHALF) atomicAdd(&cnt[u >> 1], 1u << ((u & 1) * 16));
        }
    }
    __syncthreads();
    unsigned* outp = (kind ? pout : pin) + c * (2 * NHWORDS) + half * NHWORDS;
    for (int i = threadIdx.x; i < NHWORDS; i += 256) outp[i] = cnt[i];
}

// --- sum packed partials -> deg_in ; fused c = rsqrt(max(deg,1)), 2 nodes/thread ---
__global__ __launch_bounds__(256) void degsum2_kernel(const unsigned* __restrict__ pin,
                                                      const unsigned* __restrict__ pout,
                                                      int* __restrict__ deg_in,
                                                      float* __restrict__ cs,
                                                      float* __restrict__ cd) {
    int w = blockIdx.x * 256 + threadIdx.x;  // packed word = nodes (2w, 2w+1)
    if (w >= N_NODES / 2) return;
    unsigned si0 = 0, si1 = 0, so0 = 0, so1 = 0;
#pragma unroll
    for (int c = 0; c < CSPLIT; ++c) {
        unsigned a = pin[c * (N_NODES / 2) + w];
        unsigned b = pout[c * (N_NODES / 2) + w];
        si0 += a & 0xffff; si1 += a >> 16;
        so0 += b & 0xffff; so1 += b >> 16;
    }
    deg_in[2 * w + 0] = (int)si0;
    deg_in[2 * w + 1] = (int)si1;
    cs[2 * w + 0] = rsqrtf(fmaxf((float)so0, 1.0f));
    cs[2 * w + 1] = rsqrtf(fmaxf((float)so1, 1.0f));
    cd[2 * w + 0] = rsqrtf(fmaxf((float)si0, 1.0f));
    cd[2 * w + 1] = rsqrtf(fmaxf((float)si1, 1.0f));
}

// --- scan stage 1: per-block exclusive scan of 1024 elements, emit block sums ---
__global__ __launch_bounds__(SCAN_BLK) void scan1_kernel(const int* __restrict__ deg,
                                                         int* __restrict__ offs,
                                                         int* __restrict__ bsum) {
    __shared__ int sums[SCAN_BLK];
    int t = threadIdx.x;
    int base = blockIdx.x * SCAN_ELEMS + t * 4;
    int d0 = (base + 0 < N_NODES) ? deg[base + 0] : 0;
    int d1 = (base + 1 < N_NODES) ? deg[base + 1] : 0;
    int d2 = (base + 2 < N_NODES) ? deg[base + 2] : 0;
    int d3 = (base + 3 < N_NODES) ? deg[base + 3] : 0;
    sums[t] = d0 + d1 + d2 + d3;
    __syncthreads();
    for (int o = 1; o < SCAN_BLK; o <<= 1) {
        int v = (t >= o) ? sums[t - o] : 0;
        __syncthreads();
        sums[t] += v;
        __syncthreads();
    }
    int excl = (t == 0) ? 0 : sums[t - 1];
    if (base + 0 < N_NODES) offs[base + 0] = excl;
    if (base + 1 < N_NODES) offs[base + 1] = excl + d0;
    if (base + 2 < N_NODES) offs[base + 2] = excl + d0 + d1;
    if (base + 3 < N_NODES) offs[base + 3] = excl + d0 + d1 + d2;
    if (t == SCAN_BLK - 1) bsum[blockIdx.x] = sums[SCAN_BLK - 1];
}

// --- scan stage 2: single wave exclusive scan of block sums (nb <= 64) ---
__global__ __launch_bounds__(64) void scan2_kernel(int* __restrict__ bsum, int nb) {
    int t = threadIdx.x;
    int v = (t < nb) ? bsum[t] : 0;
    int s = v;
#pragma unroll
    for (int o = 1; o < 64; o <<= 1) {
        int u = __shfl_up(s, o, 64);
        if (t >= o) s += u;
    }
    if (t < nb) bsum[t] = s - v;  // exclusive
}

// --- scan stage 3: finalize offs AND per-chunk base offsets base[c][v] ---
__global__ __launch_bounds__(256) void scan3_base_kernel(int* __restrict__ offs,
                                                         const int* __restrict__ bsum,
                                                         const unsigned* __restrict__ pin,
                                                         int* __restrict__ base) {
    int v = blockIdx.x * 256 + threadIdx.x;
    if (v >= N_NODES) return;
    int off = offs[v] + bsum[v >> 10];  // SCAN_ELEMS = 1024
    offs[v] = off;
    int run = off;
    int sh = (v & 1) * 16;
#pragma unroll
    for (int c = 0; c < CSPLIT; ++c) {
        base[c * N_NODES + v] = run;
        run += (int)((pin[c * (N_NODES / 2) + (v >> 1)] >> sh) & 0xffff);
    }
    if (v == 0) offs[N_NODES] = N_EDGES;
}

// --- CSR fill, single coalesced pass: slot = base[c][dst] + epos ---
__global__ __launch_bounds__(256) void fill_kernel(const int* __restrict__ src,
                                                   const int* __restrict__ dst,
                                                   const unsigned short* __restrict__ epos,
                                                   const int* __restrict__ base,
                                                   int* __restrict__ csr_src) {
    int t = blockIdx.x * 256 + threadIdx.x;
    int e0 = t * 4;
    if (e0 >= N_EDGES) return;
    int c = e0 / CHUNK;  // CHUNK % 4 == 0 -> uniform over the 4 edges
    const int* basec = base + c * N_NODES;
    int4 s = *reinterpret_cast<const int4*>(src + e0);
    int4 d = *reinterpret_cast<const int4*>(dst + e0);
    ushort4 ep = *reinterpret_cast<const ushort4*>(epos + e0);
    csr_src[basec[d.x] + ep.x] = s.x;
    csr_src[basec[d.y] + ep.y] = s.y;
    csr_src[basec[d.z] + ep.z] = s.z;
    csr_src[basec[d.w] + ep.w] = s.w;
}

// --- w2s = W2@Ws, w2d = W2@Wd (64-vecs); w2c = {Ws.b2, Wd.b2} ---
__global__ __launch_bounds__(128) void w2prep_kernel(const float* __restrict__ W2,
                                                     const float* __restrict__ We,
                                                     const float* __restrict__ b2,
                                                     float* __restrict__ w2s,
                                                     float* __restrict__ w2d,
                                                     float* __restrict__ w2c) {
    int t = threadIdx.x;
    if (t < 64) {
        float s = 0.f, d = 0.f;
        for (int j = 0; j < HIDDEN; ++j) {
            float w = W2[t * HIDDEN + j];
            s = fmaf(w, We[j], s);
            d = fmaf(w, We[HIDDEN + j], d);
        }
        w2s[t] = s;
        w2d[t] = d;
    } else if (t == 64) {
        float s = 0.f, d = 0.f;
        for (int j = 0; j < HIDDEN; ++j) {
            s = fmaf(We[j], b2[j], s);
            d = fmaf(We[HIDDEN + j], b2[j], d);
        }
        w2c[0] = s;
        w2c[1] = d;
    }
}

// --- y[v,:] = bf16( c_src[v] * (x[v,:] @ W1) ) ---
// LDS-tiled as before; bf16 RNE output halves the gather table to 6.4 MB
// (1 cache line per edge instead of 2). k4 unroll kept at 2 (full spills).
template <int K>
__global__ __launch_bounds__(256) void gemm_scaled_kernel(const float* __restrict__ h,
                                                          const float* __restrict__ c_src,
                                                          const float* __restrict__ W,
                                                          unsigned short* __restrict__ yb) {
    constexpr int KQ = K / 4;
    __shared__ float4 Ws4[KQ * HIDDEN];
    __shared__ float4 Xs[32 * KQ];
    for (int idx = threadIdx.x; idx < KQ * HIDDEN; idx += 256) {
        int k4 = idx >> 6, col = idx & 63;
        Ws4[idx] = make_float4(W[(4 * k4 + 0) * HIDDEN + col], W[(4 * k4 + 1) * HIDDEN + col],
                               W[(4 * k4 + 2) * HIDDEN + col], W[(4 * k4 + 3) * HIDDEN + col]);
    }
    int wid = threadIdx.x >> 6, lane = threadIdx.x & 63;
    for (int base = blockIdx.x * 32; base < N_NODES; base += gridDim.x * 32) {
        int nrows = min(32, N_NODES - base);
        __syncthreads();
        const float4* src4 = reinterpret_cast<const float4*>(h + (size_t)base * K);
        for (int idx = threadIdx.x; idx < nrows * KQ; idx += 256) Xs[idx] = src4[idx];
        __syncthreads();
        int r0 = wid * 8;
        if (base + r0 >= N_NODES) continue;
        float acc[8] = {0.f, 0.f, 0.f, 0.f, 0.f, 0.f, 0.f, 0.f};
#pragma unroll 2
        for (int k4 = 0; k4 < KQ; ++k4) {
            float4 w = Ws4[k4 * 64 + lane];
#pragma unroll
            for (int r = 0; r < 8; ++r) {
                float4 a = Xs[(r0 + r) * KQ + k4];
                acc[r] = fmaf(a.x, w.x, fmaf(a.y, w.y, fmaf(a.z, w.z, fmaf(a.w, w.w, acc[r]))));
            }
        }
#pragma unroll
        for (int r = 0; r < 8; ++r) {
            int row = base + r0 + r;
            if (row < N_NODES) {
                unsigned u = __float_as_uint(acc[r] * c_src[row]);
                u = (u + 0x7FFF + ((u >> 16) & 1)) >> 16;  // RNE to bf16
                yb[(size_t)row * HIDDEN + lane] = (unsigned short)u;
            }
        }
    }
}

// --- layer1 gather (bf16 y, 8 edges/iter: 8 slots x 8 lanes x uint4=16B=full row
//     per 2 groups) + fused relu/bias + layer-2 collapse -> t[v] (float2) ---
__global__ __launch_bounds__(256) void gather_t_kernel(const unsigned short* __restrict__ y,
                                                       const int* __restrict__ offs,
                                                       const int* __restrict__ csr_src,
                                                       const float* __restrict__ c_src,
                                                       const float* __restrict__ c_dst,
                                                       const float* __restrict__ b1,
                                                       const float* __restrict__ w2s,
                                                       const float* __restrict__ w2d,
                                                       float2* __restrict__ t) {
    int wid = threadIdx.x >> 6, l = threadIdx.x & 63;
    int slot = l >> 3, q8 = l & 7;  // 8 edge-slots x 8 feature-octets
    int v = blockIdx.x * 4 + wid;   // grid exact: 12500 * 4 = 50000
    int beg = offs[v], end = offs[v + 1];
    float acc[8] = {0.f, 0.f, 0.f, 0.f, 0.f, 0.f, 0.f, 0.f};
    int k = beg;
    for (; k + 8 <= end; k += 8) {
        int s = csr_src[k + slot];
        uint4 r = *reinterpret_cast<const uint4*>(y + (size_t)s * HIDDEN + q8 * 8);
        acc[0] += __uint_as_float(r.x << 16);
        acc[1] += __uint_as_float(r.x & 0xffff0000u);
        acc[2] += __uint_as_float(r.y << 16);
        acc[3] += __uint_as_float(r.y & 0xffff0000u);
        acc[4] += __uint_as_float(r.z << 16);
        acc[5] += __uint_as_float(r.z & 0xffff0000u);
        acc[6] += __uint_as_float(r.w << 16);
        acc[7] += __uint_as_float(r.w & 0xffff0000u);
    }
    if (slot < end - k) {
        int s = csr_src[k + slot];
        uint4 r = *reinterpret_cast<const uint4*>(y + (size_t)s * HIDDEN + q8 * 8);
        acc[0] += __uint_as_float(r.x << 16);
        acc[1] += __uint_as_float(r.x & 0xffff0000u);
        acc[2] += __uint_as_float(r.y << 16);
        acc[3] += __uint_as_float(r.y & 0xffff0000u);
        acc[4] += __uint_as_float(r.z << 16);
        acc[5] += __uint_as_float(r.z & 0xffff0000u);
        acc[6] += __uint_as_float(r.w << 16);
        acc[7] += __uint_as_float(r.w & 0xffff0000u);
    }
    // combine 8 slots (lanes with equal q8)
#pragma unroll
    for (int i = 0; i < 8; ++i) {
        acc[i] += __shfl_xor(acc[i], 8, 64);
        acc[i] += __shfl_xor(acc[i], 16, 64);
        acc[i] += __shfl_xor(acc[i], 32, 64);
    }
    float c = c_dst[v];
    float4 ba = *reinterpret_cast<const float4*>(b1 + q8 * 8);
    float4 bb = *reinterpret_cast<const float4*>(b1 + q8 * 8 + 4);
    float4 wsa = *reinterpret_cast<const float4*>(w2s + q8 * 8);
    float4 wsb = *reinterpret_cast<const float4*>(w2s + q8 * 8 + 4);
    float4 wda = *reinterpret_cast<const float4*>(w2d + q8 * 8);
    float4 wdb = *reinterpret_cast<const float4*>(w2d + q8 * 8 + 4);
    float h0 = fmaxf(fmaf(c, acc[0], ba.x), 0.f);
    float h1 = fmaxf(fmaf(c, acc[1], ba.y), 0.f);
    float h2 = fmaxf(fmaf(c, acc[2], ba.z), 0.f);
    float h3 = fmaxf(fmaf(c, acc[3], ba.w), 0.f);
    float h4 = fmaxf(fmaf(c, acc[4], bb.x), 0.f);
    float h5 = fmaxf(fmaf(c, acc[5], bb.y), 0.f);
    float h6 = fmaxf(fmaf(c, acc[6], bb.z), 0.f);
    float h7 = fmaxf(fmaf(c, acc[7], bb.w), 0.f);
    float ps = h0 * wsa.x + h1 * wsa.y + h2 * wsa.z + h3 * wsa.w
             + h4 * wsb.x + h5 * wsb.y + h6 * wsb.z + h7 * wsb.w;
    float pd = h0 * wda.x + h1 * wda.y + h2 * wda.z + h3 * wda.w
             + h4 * wdb.x + h5 * wdb.y + h6 * wdb.z + h7 * wdb.w;
#pragma unroll
    for (int o = 1; o <= 4; o <<= 1) {
        ps += __shfl_xor(ps, o, 64);
        pd += __shfl_xor(pd, o, 64);
    }
    if (l == 0) {
        float cs = c_src[v];
        t[v] = make_float2(cs * ps, cs * pd);
    }
}

// --- layer2 scalar gather: a_s[v] = c_dst[v]*sum(t_s over in-edges) + Ws.b2 ---
__global__ __launch_bounds__(256) void gather2_kernel(const float2* __restrict__ t,
                                                      const int* __restrict__ offs,
                                                      const int* __restrict__ csr_src,
                                                      const float* __restrict__ c_dst,
                                                      const float* __restrict__ w2c,
                                                      float* __restrict__ a_s,
                                                      float* __restrict__ a_d) {
    int wid = threadIdx.x >> 6, l = threadIdx.x & 63;
    int sub = l >> 4, q = l & 15;
    int v = blockIdx.x * 16 + wid * 4 + sub;  // grid exact: 3125 * 16 = 50000
    int beg = offs[v], end = offs[v + 1];
    float ps = 0.f, pd = 0.f;
    for (int k = beg + q; k < end; k += 16) {
        float2 tv = t[csr_src[k]];
        ps += tv.x;
        pd += tv.y;
    }
#pragma unroll
    for (int o = 1; o <= 8; o <<= 1) {
        ps += __shfl_xor(ps, o, 64);
        pd += __shfl_xor(pd, o, 64);
    }
    if (q == 0) {
        float c = c_dst[v];
        a_s[v] = fmaf(c, ps, w2c[0]);
        a_d[v] = fmaf(c, pd, w2c[1]);
    }
}

// --- out[e] = sigmoid(a_s[src] + a_d[dst] + efeat.Wf + be), 4 edges/thread ---
__global__ __launch_bounds__(256) void edge_out_kernel(const int* __restrict__ src,
                                                       const int* __restrict__ dst,
                                                       const float* __restrict__ efeat,
                                                       const float* __restrict__ We,
                                                       const float* __restrict__ be,
                                                       const float* __restrict__ a_s,
                                                       const float* __restrict__ a_d,
                                                       float* __restrict__ out) {
    int t = blockIdx.x * 256 + threadIdx.x;
    int e0 = t * 4;
    if (e0 >= N_EDGES) return;
    float w0 = We[2 * HIDDEN + 0], w1 = We[2 * HIDDEN + 1], w2 = We[2 * HIDDEN + 2];
    float b = be[0];
    int4 s = *reinterpret_cast<const int4*>(src + e0);
    int4 d = *reinterpret_cast<const int4*>(dst + e0);
    const float4* f = reinterpret_cast<const float4*>(efeat + (long)e0 * 3);
    float4 f0 = f[0], f1 = f[1], f2 = f[2];
    float4 o;
    float z;
    z = a_s[s.x] + a_d[d.x] + f0.x * w0 + f0.y * w1 + f0.z * w2 + b;
    o.x = 1.0f / (1.0f + __expf(-z));
    z = a_s[s.y] + a_d[d.y] + f0.w * w0 + f1.x * w1 + f1.y * w2 + b;
    o.y = 1.0f / (1.0f + __expf(-z));
    z = a_s[s.z] + a_d[d.z] + f1.z * w0 + f1.w * w1 + f2.x * w2 + b;
    o.z = 1.0f / (1.0f + __expf(-z));
    z = a_s[s.w] + a_d[d.w] + f2.y * w0 + f2.z * w1 + f2.w * w2 + b;
    o.w = 1.0f / (1.0f + __expf(-z));
    *reinterpret_cast<float4*>(out + e0) = o;
}

extern "C" void kernel_launch(void* const* d_in, const int* in_sizes, int n_in,
                              void* d_out, int out_size, void* d_ws, size_t ws_size,
                              hipStream_t stream) {
    const float* x     = (const float*)d_in[0];
    const float* efeat = (const float*)d_in[1];
    const int*   src   = (const int*)d_in[2];
    const int*   dst   = (const int*)d_in[3];
    const float* W1    = (const float*)d_in[4];
    const float* b1    = (const float*)d_in[5];
    const float* W2    = (const float*)d_in[6];
    const float* b2    = (const float*)d_in[7];
    const float* We    = (const float*)d_in[8];
    const float* be    = (const float*)d_in[9];
    float* out = (float*)d_out;

    // 256B-aligned workspace carve-up; ~27 MB total, no aliasing needed.
    char* p = (char*)d_ws;
    auto alloc = [&](size_t bytes) {
        char* r = p;
        p += (bytes + 255) & ~(size_t)255;
        return r;
    };
    float* c_src   = (float*)alloc((size_t)N_NODES * 4);
    float* c_dst   = (float*)alloc((size_t)N_NODES * 4);
    float* a_s     = (float*)alloc((size_t)N_NODES * 4);
    float* a_d     = (float*)alloc((size_t)N_NODES * 4);
    int*   deg_in  = (int*)alloc((size_t)N_NODES * 4);
    int*   offs    = (int*)alloc((size_t)(N_NODES + 1) * 4);
    int*   bsum    = (int*)alloc(64 * 4);
    float* w2s     = (float*)alloc(HIDDEN * 4);
    float* w2d     = (float*)alloc(HIDDEN * 4);
    float* w2c     = (float*)alloc(2 * 4);
    unsigned*       pin   = (unsigned*)alloc((size_t)CSPLIT * (N_NODES / 2) * 4);  // 3.2 MB
    unsigned*       pout  = (unsigned*)alloc((size_t)CSPLIT * (N_NODES / 2) * 4);  // 3.2 MB
    unsigned short* epos  = (unsigned short*)alloc((size_t)N_EDGES * 2);           // 1.6 MB
    int*            base  = (int*)alloc((size_t)CSPLIT * N_NODES * 4);             // 6.4 MB
    int*            csr_src = (int*)alloc((size_t)N_EDGES * 4);                    // 3.2 MB
    unsigned short* yb    = (unsigned short*)alloc((size_t)N_NODES * HIDDEN * 2);  // 6.4 MB
    float2*         t     = (float2*)alloc((size_t)N_NODES * 8);                   // 400 KB

    const int NB_SCAN = (N_NODES + SCAN_ELEMS - 1) / SCAN_ELEMS;  // 49
    const int NB_V    = (N_NODES + 255) / 256;                    // 196
    const int NB_E4   = (N_EDGES / 4 + 255) / 256;                // 782

    // CSR build: zero global atomics, single edge pass per kind+fill
    hist2_kernel<<<CSPLIT * 4, 256, 0, stream>>>(src, dst, epos, pin, pout);
    degsum2_kernel<<<(N_NODES / 2 + 255) / 256, 256, 0, stream>>>(pin, pout, deg_in, c_src, c_dst);
    scan1_kernel<<<NB_SCAN, SCAN_BLK, 0, stream>>>(deg_in, offs, bsum);
    scan2_kernel<<<1, 64, 0, stream>>>(bsum, NB_SCAN);
    scan3_base_kernel<<<NB_V, 256, 0, stream>>>(offs, bsum, pin, base);
    fill_kernel<<<NB_E4, 256, 0, stream>>>(src, dst, epos, base, csr_src);

    // layer-2 collapse precompute (independent of CSR)
    w2prep_kernel<<<1, 128, 0, stream>>>(W2, We, b2, w2s, w2d, w2c);

    // layer 1 GEMM: yb = bf16((x*c_src)@W1)
    const int NT1 = (N_NODES + 31) / 32;  // 1563 tiles
    gemm_scaled_kernel<IN_FEATS><<<NT1, 256, 0, stream>>>(x, c_src, W1, yb);

    // fused gather1 + relu + layer-2 dots -> t
    gather_t_kernel<<<N_NODES / 4, 256, 0, stream>>>(yb, offs, csr_src, c_src, c_dst,
                                                     b1, w2s, w2d, t);

    // layer-2 scalar gather -> a_s, a_d
    gather2_kernel<<<N_NODES / 16, 256, 0, stream>>>(t, offs, csr_src, c_dst, w2c, a_s, a_d);

    // edge output
    edge_out_kernel<<<NB_E4, 256, 0, stream>>>(src, dst, efeat, We, be, a_s, a_d, out);
}

// Round 10
// 119.453 us; speedup vs baseline: 2.2104x; 1.0644x over previous
//
#include <hip/hip_runtime.h>
#include <math.h>
#include <stdint.h>

#define N_NODES 50000
#define N_EDGES 800000
#define IN_FEATS 128
#define HIDDEN 64

// CSR build: 32 edge-chunks x (in|out) x 2 node-halves, counts in LDS (packed
// 2 nodes per u32 -- max per-chunk count 25000 < 2^15, no cross-half carry).
// The in-histogram pass ALSO emits each edge's slot index (epos, u16) so the
// CSR fill is a single coalesced pass. Zero global atomics anywhere (r6
// post-mortem: device atomics write ~32B through to HBM each; spreading them
// doesn't help -- only reducing their count to zero does).
#define CSPLIT 32
#define CHUNK (N_EDGES / CSPLIT)   // 25000 edges, exact
#define NHALF (N_NODES / 2)        // 25000 nodes per half
#define NHWORDS (NHALF / 2)        // 12500 packed u32 (50 KB LDS)

// --- per-(chunk, kind, half) packed histograms in LDS; epos out for kind=in ---
__global__ __launch_bounds__(256) void hist2_kernel(const int* __restrict__ src,
                                                    const int* __restrict__ dst,
                                                    unsigned short* __restrict__ epos,
                                                    unsigned* __restrict__ pin,
                                                    unsigned* __restrict__ pout) {
    __shared__ unsigned cnt[NHWORDS];
    int b = blockIdx.x;            // 128 blocks
    int c = b >> 2;
    int kind = (b >> 1) & 1;       // 0 = in (dst) + epos, 1 = out (src)
    int half = b & 1;
    int lo = half * NHALF;
    for (int i = threadIdx.x; i < NHWORDS; i += 256) cnt[i] = 0;
    __syncthreads();
    if (kind == 0) {
        const int4* d4 = reinterpret_cast<const int4*>(dst + c * CHUNK);
        for (int i = threadIdx.x; i < CHUNK / 4; i += 256) {
            int4 d = d4[i];
            int e = c * CHUNK + i * 4;
            unsigned u, old;
            u = (unsigned)(d.x - lo);
            if (u < NHALF) { old = atomicAdd(&cnt[u >> 1], 1u << ((u & 1) * 16));
                             epos[e + 0] = (unsigned short)(old >> ((u & 1) * 16)); }
            u = (unsigned)(d.y - lo);
            if (u < NHALF) { old = atomicAdd(&cnt[u >> 1], 1u << ((u & 1) * 16));
                             epos[e + 1] = (unsigned short)(old >> ((u & 1) * 16)); }
            u = (unsigned)(d.z - lo);
            if (u < NHALF) { old = atomicAdd(&cnt[u >> 1], 1u << ((u & 1) * 16));
                             epos[e + 2] = (unsigned short)(old >> ((u & 1) * 16)); }
            u = (unsigned)(d.w - lo);
            if (u < NHALF) { old = atomicAdd(&cnt[u >> 1], 1u << ((u & 1) * 16));
                             epos[e + 3] = (unsigned short)(old >> ((u & 1) * 16)); }
        }
    } else {
        const int4* s4 = reinterpret_cast<const int4*>(src + c * CHUNK);
        for (int i = threadIdx.x; i < CHUNK / 4; i += 256) {
            int4 s = s4[i];
            unsigned u;
            u = (unsigned)(s.x - lo); if (u < NHALF) atomicAdd(&cnt[u >> 1], 1u << ((u & 1) * 16));
            u = (unsigned)(s.y - lo); if (u < NHALF) atomicAdd(&cnt[u >> 1], 1u << ((u & 1) * 16));
            u = (unsigned)(s.z - lo); if (u < NHALF) atomicAdd(&cnt[u >> 1], 1u << ((u & 1) * 16));
            u = (unsigned)(s.w - lo); if (u < NHALF) atomicAdd(&cnt[u >> 1], 1u << ((u & 1) * 16));
        }
    }
    __syncthreads();
    unsigned* outp = (kind ? pout : pin) + c * (2 * NHWORDS) + half * NHWORDS;
    for (int i = threadIdx.x; i < NHWORDS; i += 256) outp[i] = cnt[i];
}

// --- fused: degree-sum + c_src/c_dst + per-block exclusive scan (blocks 0..48,
//     1024 nodes each, 4/thread) ; block 49 = w2prep (w2s=W2@Ws, w2d=W2@Wd) ---
__global__ __launch_bounds__(256) void prep_kernel(const unsigned* __restrict__ pin,
                                                   const unsigned* __restrict__ pout,
                                                   float* __restrict__ cs,
                                                   float* __restrict__ cd,
                                                   int* __restrict__ offs,
                                                   int* __restrict__ bsum,
                                                   const float* __restrict__ W2,
                                                   const float* __restrict__ We,
                                                   const float* __restrict__ b2,
                                                   float* __restrict__ w2s,
                                                   float* __restrict__ w2d,
                                                   float* __restrict__ w2c) {
    int b = blockIdx.x;
    int t = threadIdx.x;
    if (b == 49) {  // w2prep tail block (no barriers on this path)
        if (t < 64) {
            float s = 0.f, d = 0.f;
            for (int j = 0; j < HIDDEN; ++j) {
                float w = W2[t * HIDDEN + j];
                s = fmaf(w, We[j], s);
                d = fmaf(w, We[HIDDEN + j], d);
            }
            w2s[t] = s;
            w2d[t] = d;
        } else if (t == 64) {
            float s = 0.f, d = 0.f;
            for (int j = 0; j < HIDDEN; ++j) {
                s = fmaf(We[j], b2[j], s);
                d = fmaf(We[HIDDEN + j], b2[j], d);
            }
            w2c[0] = s;
            w2c[1] = d;
        }
        return;
    }
    __shared__ int sums[256];
    int v0 = b * 1024 + t * 4;
    bool ok = v0 < N_NODES;
    unsigned si0 = 0, si1 = 0, si2 = 0, si3 = 0;
    unsigned so0 = 0, so1 = 0, so2 = 0, so3 = 0;
    if (ok) {
        int w0 = v0 >> 1;  // even (v0 % 4 == 0) -> uint2 aligned
#pragma unroll
        for (int c = 0; c < CSPLIT; ++c) {
            uint2 a = *reinterpret_cast<const uint2*>(pin + (size_t)c * (N_NODES / 2) + w0);
            uint2 o = *reinterpret_cast<const uint2*>(pout + (size_t)c * (N_NODES / 2) + w0);
            si0 += a.x & 0xffffu; si1 += a.x >> 16;
            si2 += a.y & 0xffffu; si3 += a.y >> 16;
            so0 += o.x & 0xffffu; so1 += o.x >> 16;
            so2 += o.y & 0xffffu; so3 += o.y >> 16;
        }
        *reinterpret_cast<float4*>(cs + v0) =
            make_float4(rsqrtf(fmaxf((float)so0, 1.f)), rsqrtf(fmaxf((float)so1, 1.f)),
                        rsqrtf(fmaxf((float)so2, 1.f)), rsqrtf(fmaxf((float)so3, 1.f)));
        *reinterpret_cast<float4*>(cd + v0) =
            make_float4(rsqrtf(fmaxf((float)si0, 1.f)), rsqrtf(fmaxf((float)si1, 1.f)),
                        rsqrtf(fmaxf((float)si2, 1.f)), rsqrtf(fmaxf((float)si3, 1.f)));
    }
    int d0 = (int)si0, d1 = (int)si1, d2 = (int)si2, d3 = (int)si3;
    sums[t] = d0 + d1 + d2 + d3;
    __syncthreads();
    for (int o = 1; o < 256; o <<= 1) {
        int v = (t >= o) ? sums[t - o] : 0;
        __syncthreads();
        sums[t] += v;
        __syncthreads();
    }
    int excl = (t == 0) ? 0 : sums[t - 1];
    if (ok) {
        *reinterpret_cast<int4*>(offs + v0) =
            make_int4(excl, excl + d0, excl + d0 + d1, excl + d0 + d1 + d2);
    }
    if (t == 255) bsum[b] = sums[255];
}

// --- finalize offs + per-chunk base offsets; the 49-entry bsum scan is done
//     redundantly per block in the first wave (cheaper than a dedicated launch) ---
__global__ __launch_bounds__(256) void scan3_base_kernel(int* __restrict__ offs,
                                                         const int* __restrict__ bsum,
                                                         const unsigned* __restrict__ pin,
                                                         int* __restrict__ base) {
    __shared__ int sbase[64];
    int t = threadIdx.x;
    if (t < 64) {
        int val = (t < 49) ? bsum[t] : 0;
        int s = val;
#pragma unroll
        for (int o = 1; o < 64; o <<= 1) {
            int u = __shfl_up(s, o, 64);
            if (t >= o) s += u;
        }
        sbase[t] = s - val;  // exclusive
    }
    __syncthreads();
    int v = blockIdx.x * 256 + t;
    if (v >= N_NODES) return;
    int off = offs[v] + sbase[v >> 10];
    offs[v] = off;
    int run = off;
    int sh = (v & 1) * 16;
#pragma unroll
    for (int c = 0; c < CSPLIT; ++c) {
        base[(size_t)c * N_NODES + v] = run;
        run += (int)((pin[(size_t)c * (N_NODES / 2) + (v >> 1)] >> sh) & 0xffffu);
    }
    if (v == 0) offs[N_NODES] = N_EDGES;
}

// --- CSR fill, single coalesced pass: slot = base[c][dst] + epos ---
__global__ __launch_bounds__(256) void fill_kernel(const int* __restrict__ src,
                                                   const int* __restrict__ dst,
                                                   const unsigned short* __restrict__ epos,
                                                   const int* __restrict__ base,
                                                   int* __restrict__ csr_src) {
    int t = blockIdx.x * 256 + threadIdx.x;
    int e0 = t * 4;
    if (e0 >= N_EDGES) return;
    int c = e0 / CHUNK;  // CHUNK % 4 == 0 -> uniform over the 4 edges
    const int* basec = base + (size_t)c * N_NODES;
    int4 s = *reinterpret_cast<const int4*>(src + e0);
    int4 d = *reinterpret_cast<const int4*>(dst + e0);
    ushort4 ep = *reinterpret_cast<const ushort4*>(epos + e0);
    csr_src[basec[d.x] + ep.x] = s.x;
    csr_src[basec[d.y] + ep.y] = s.y;
    csr_src[basec[d.z] + ep.z] = s.z;
    csr_src[basec[d.w] + ep.w] = s.w;
}

// --- y[v,:] = bf16( c_src[v] * (x[v,:] @ W1) ) ---
// LDS-tiled; bf16 RNE output halves the gather table (1 line/edge).
// k4 unroll kept at 2 (full unroll spilled: VGPR=256, 800MB scratch, 4x slower).
template <int K>
__global__ __launch_bounds__(256) void gemm_scaled_kernel(const float* __restrict__ h,
                                                          const float* __restrict__ c_src,
                                                          const float* __restrict__ W,
                                                          unsigned short* __restrict__ yb) {
    constexpr int KQ = K / 4;
    __shared__ float4 Ws4[KQ * HIDDEN];
    __shared__ float4 Xs[32 * KQ];
    for (int idx = threadIdx.x; idx < KQ * HIDDEN; idx += 256) {
        int k4 = idx >> 6, col = idx & 63;
        Ws4[idx] = make_float4(W[(4 * k4 + 0) * HIDDEN + col], W[(4 * k4 + 1) * HIDDEN + col],
                               W[(4 * k4 + 2) * HIDDEN + col], W[(4 * k4 + 3) * HIDDEN + col]);
    }
    int wid = threadIdx.x >> 6, lane = threadIdx.x & 63;
    for (int base = blockIdx.x * 32; base < N_NODES; base += gridDim.x * 32) {
        int nrows = min(32, N_NODES - base);
        __syncthreads();
        const float4* src4 = reinterpret_cast<const float4*>(h + (size_t)base * K);
        for (int idx = threadIdx.x; idx < nrows * KQ; idx += 256) Xs[idx] = src4[idx];
        __syncthreads();
        int r0 = wid * 8;
        if (base + r0 >= N_NODES) continue;
        float acc[8] = {0.f, 0.f, 0.f, 0.f, 0.f, 0.f, 0.f, 0.f};
#pragma unroll 2
        for (int k4 = 0; k4 < KQ; ++k4) {
            float4 w = Ws4[k4 * 64 + lane];
#pragma unroll
            for (int r = 0; r < 8; ++r) {
                float4 a = Xs[(r0 + r) * KQ + k4];
                acc[r] = fmaf(a.x, w.x, fmaf(a.y, w.y, fmaf(a.z, w.z, fmaf(a.w, w.w, acc[r]))));
            }
        }
#pragma unroll
        for (int r = 0; r < 8; ++r) {
            int row = base + r0 + r;
            if (row < N_NODES) {
                unsigned u = __float_as_uint(acc[r] * c_src[row]);
                u = (u + 0x7FFF + ((u >> 16) & 1)) >> 16;  // RNE to bf16
                yb[(size_t)row * HIDDEN + lane] = (unsigned short)u;
            }
        }
    }
}

// --- layer1 gather (bf16 y, 8 slots x 8 lanes x uint4 = 8 edges/iter, 2x-deep
//     main loop = 16 edges in flight) + relu/bias + layer-2 collapse -> t[v] ---
__global__ __launch_bounds__(256) void gather_t_kernel(const unsigned short* __restrict__ y,
                                                       const int* __restrict__ offs,
                                                       const int* __restrict__ csr_src,
                                                       const float* __restrict__ c_src,
                                                       const float* __restrict__ c_dst,
                                                       const float* __restrict__ b1,
                                                       const float* __restrict__ w2s,
                                                       const float* __restrict__ w2d,
                                                       float2* __restrict__ t) {
    int wid = threadIdx.x >> 6, l = threadIdx.x & 63;
    int slot = l >> 3, q8 = l & 7;  // 8 edge-slots x 8 feature-octets
    int v = blockIdx.x * 4 + wid;   // grid exact: 12500 * 4 = 50000
    int beg = offs[v], end = offs[v + 1];
    float acc[8] = {0.f, 0.f, 0.f, 0.f, 0.f, 0.f, 0.f, 0.f};
    int k = beg;
    for (; k + 16 <= end; k += 16) {
        int sA = csr_src[k + slot];
        int sB = csr_src[k + 8 + slot];
        uint4 rA = *reinterpret_cast<const uint4*>(y + (size_t)sA * HIDDEN + q8 * 8);
        uint4 rB = *reinterpret_cast<const uint4*>(y + (size_t)sB * HIDDEN + q8 * 8);
        acc[0] += __uint_as_float(rA.x << 16);
        acc[1] += __uint_as_float(rA.x & 0xffff0000u);
        acc[2] += __uint_as_float(rA.y << 16);
        acc[3] += __uint_as_float(rA.y & 0xffff0000u);
        acc[4] += __uint_as_float(rA.z << 16);
        acc[5] += __uint_as_float(rA.z & 0xffff0000u);
        acc[6] += __uint_as_float(rA.w << 16);
        acc[7] += __uint_as_float(rA.w & 0xffff0000u);
        acc[0] += __uint_as_float(rB.x << 16);
        acc[1] += __uint_as_float(rB.x & 0xffff0000u);
        acc[2] += __uint_as_float(rB.y << 16);
        acc[3] += __uint_as_float(rB.y & 0xffff0000u);
        acc[4] += __uint_as_float(rB.z << 16);
        acc[5] += __uint_as_float(rB.z & 0xffff0000u);
        acc[6] += __uint_as_float(rB.w << 16);
        acc[7] += __uint_as_float(rB.w & 0xffff0000u);
    }
    if (k + 8 <= end) {
        int s = csr_src[k + slot];
        uint4 r = *reinterpret_cast<const uint4*>(y + (size_t)s * HIDDEN + q8 * 8);
        acc[0] += __uint_as_float(r.x << 16);
        acc[1] += __uint_as_float(r.x & 0xffff0000u);
        acc[2] += __uint_as_float(r.y << 16);
        acc[3] += __uint_as_float(r.y & 0xffff0000u);
        acc[4] += __uint_as_float(r.z << 16);
        acc[5] += __uint_as_float(r.z & 0xffff0000u);
        acc[6] += __uint_as_float(r.w << 16);
        acc[7] += __uint_as_float(r.w & 0xffff0000u);
        k += 8;
    }
    if (slot < end - k) {
        int s = csr_src[k + slot];
        uint4 r = *reinterpret_cast<const uint4*>(y + (size_t)s * HIDDEN + q8 * 8);
        acc[0] += __uint_as_float(r.x << 16);
        acc[1] += __uint_as_float(r.x & 0xffff0000u);
        acc[2] += __uint_as_float(r.y << 16);
        acc[3] += __uint_as_float(r.y & 0xffff0000u);
        acc[4] += __uint_as_float(r.z << 16);
        acc[5] += __uint_as_float(r.z & 0xffff0000u);
        acc[6] += __uint_as_float(r.w << 16);
        acc[7] += __uint_as_float(r.w & 0xffff0000u);
    }
    // combine 8 slots (lanes with equal q8)
#pragma unroll
    for (int i = 0; i < 8; ++i) {
        acc[i] += __shfl_xor(acc[i], 8, 64);
        acc[i] += __shfl_xor(acc[i], 16, 64);
        acc[i] += __shfl_xor(acc[i], 32, 64);
    }
    float c = c_dst[v];
    float4 ba = *reinterpret_cast<const float4*>(b1 + q8 * 8);
    float4 bb = *reinterpret_cast<const float4*>(b1 + q8 * 8 + 4);
    float4 wsa = *reinterpret_cast<const float4*>(w2s + q8 * 8);
    float4 wsb = *reinterpret_cast<const float4*>(w2s + q8 * 8 + 4);
    float4 wda = *reinterpret_cast<const float4*>(w2d + q8 * 8);
    float4 wdb = *reinterpret_cast<const float4*>(w2d + q8 * 8 + 4);
    float h0 = fmaxf(fmaf(c, acc[0], ba.x), 0.f);
    float h1 = fmaxf(fmaf(c, acc[1], ba.y), 0.f);
    float h2 = fmaxf(fmaf(c, acc[2], ba.z), 0.f);
    float h3 = fmaxf(fmaf(c, acc[3], ba.w), 0.f);
    float h4 = fmaxf(fmaf(c, acc[4], bb.x), 0.f);
    float h5 = fmaxf(fmaf(c, acc[5], bb.y), 0.f);
    float h6 = fmaxf(fmaf(c, acc[6], bb.z), 0.f);
    float h7 = fmaxf(fmaf(c, acc[7], bb.w), 0.f);
    float ps = h0 * wsa.x + h1 * wsa.y + h2 * wsa.z + h3 * wsa.w
             + h4 * wsb.x + h5 * wsb.y + h6 * wsb.z + h7 * wsb.w;
    float pd = h0 * wda.x + h1 * wda.y + h2 * wda.z + h3 * wda.w
             + h4 * wdb.x + h5 * wdb.y + h6 * wdb.z + h7 * wdb.w;
#pragma unroll
    for (int o = 1; o <= 4; o <<= 1) {
        ps += __shfl_xor(ps, o, 64);
        pd += __shfl_xor(pd, o, 64);
    }
    if (l == 0) {
        float cs = c_src[v];
        t[v] = make_float2(cs * ps, cs * pd);
    }
}

// --- layer2 scalar gather: a_s[v] = c_dst[v]*sum(t_s over in-edges) + Ws.b2 ---
__global__ __launch_bounds__(256) void gather2_kernel(const float2* __restrict__ t,
                                                      const int* __restrict__ offs,
                                                      const int* __restrict__ csr_src,
                                                      const float* __restrict__ c_dst,
                                                      const float* __restrict__ w2c,
                                                      float* __restrict__ a_s,
                                                      float* __restrict__ a_d) {
    int wid = threadIdx.x >> 6, l = threadIdx.x & 63;
    int sub = l >> 4, q = l & 15;
    int v = blockIdx.x * 16 + wid * 4 + sub;  // grid exact: 3125 * 16 = 50000
    int beg = offs[v], end = offs[v + 1];
    float ps = 0.f, pd = 0.f;
    for (int k = beg + q; k < end; k += 16) {
        float2 tv = t[csr_src[k]];
        ps += tv.x;
        pd += tv.y;
    }
#pragma unroll
    for (int o = 1; o <= 8; o <<= 1) {
        ps += __shfl_xor(ps, o, 64);
        pd += __shfl_xor(pd, o, 64);
    }
    if (q == 0) {
        float c = c_dst[v];
        a_s[v] = fmaf(c, ps, w2c[0]);
        a_d[v] = fmaf(c, pd, w2c[1]);
    }
}

// --- out[e] = sigmoid(a_s[src] + a_d[dst] + efeat.Wf + be), 4 edges/thread ---
__global__ __launch_bounds__(256) void edge_out_kernel(const int* __restrict__ src,
                                                       const int* __restrict__ dst,
                                                       const float* __restrict__ efeat,
                                                       const float* __restrict__ We,
                                                       const float* __restrict__ be,
                                                       const float* __restrict__ a_s,
                                                       const float* __restrict__ a_d,
                                                       float* __restrict__ out) {
    int t = blockIdx.x * 256 + threadIdx.x;
    int e0 = t * 4;
    if (e0 >= N_EDGES) return;
    float w0 = We[2 * HIDDEN + 0], w1 = We[2 * HIDDEN + 1], w2 = We[2 * HIDDEN + 2];
    float b = be[0];
    int4 s = *reinterpret_cast<const int4*>(src + e0);
    int4 d = *reinterpret_cast<const int4*>(dst + e0);
    const float4* f = reinterpret_cast<const float4*>(efeat + (long)e0 * 3);
    float4 f0 = f[0], f1 = f[1], f2 = f[2];
    float4 o;
    float z;
    z = a_s[s.x] + a_d[d.x] + f0.x * w0 + f0.y * w1 + f0.z * w2 + b;
    o.x = 1.0f / (1.0f + __expf(-z));
    z = a_s[s.y] + a_d[d.y] + f0.w * w0 + f1.x * w1 + f1.y * w2 + b;
    o.y = 1.0f / (1.0f + __expf(-z));
    z = a_s[s.z] + a_d[d.z] + f1.z * w0 + f1.w * w1 + f2.x * w2 + b;
    o.z = 1.0f / (1.0f + __expf(-z));
    z = a_s[s.w] + a_d[d.w] + f2.y * w0 + f2.z * w1 + f2.w * w2 + b;
    o.w = 1.0f / (1.0f + __expf(-z));
    *reinterpret_cast<float4*>(out + e0) = o;
}

extern "C" void kernel_launch(void* const* d_in, const int* in_sizes, int n_in,
                              void* d_out, int out_size, void* d_ws, size_t ws_size,
                              hipStream_t stream) {
    const float* x     = (const float*)d_in[0];
    const float* efeat = (const float*)d_in[1];
    const int*   src   = (const int*)d_in[2];
    const int*   dst   = (const int*)d_in[3];
    const float* W1    = (const float*)d_in[4];
    const float* b1    = (const float*)d_in[5];
    const float* W2    = (const float*)d_in[6];
    const float* b2    = (const float*)d_in[7];
    const float* We    = (const float*)d_in[8];
    const float* be    = (const float*)d_in[9];
    float* out = (float*)d_out;

    // 256B-aligned workspace carve-up; ~25 MB total.
    char* p = (char*)d_ws;
    auto alloc = [&](size_t bytes) {
        char* r = p;
        p += (bytes + 255) & ~(size_t)255;
        return r;
    };
    float* c_src   = (float*)alloc((size_t)N_NODES * 4);
    float* c_dst   = (float*)alloc((size_t)N_NODES * 4);
    float* a_s     = (float*)alloc((size_t)N_NODES * 4);
    float* a_d     = (float*)alloc((size_t)N_NODES * 4);
    int*   offs    = (int*)alloc((size_t)(N_NODES + 1) * 4);
    int*   bsum    = (int*)alloc(64 * 4);
    float* w2s     = (float*)alloc(HIDDEN * 4);
    float* w2d     = (float*)alloc(HIDDEN * 4);
    float* w2c     = (float*)alloc(2 * 4);
    unsigned*       pin   = (unsigned*)alloc((size_t)CSPLIT * (N_NODES / 2) * 4);  // 3.2 MB
    unsigned*       pout  = (unsigned*)alloc((size_t)CSPLIT * (N_NODES / 2) * 4);  // 3.2 MB
    unsigned short* epos  = (unsigned short*)alloc((size_t)N_EDGES * 2);           // 1.6 MB
    int*            base  = (int*)alloc((size_t)CSPLIT * N_NODES * 4);             // 6.4 MB
    int*            csr_src = (int*)alloc((size_t)N_EDGES * 4);                    // 3.2 MB
    unsigned short* yb    = (unsigned short*)alloc((size_t)N_NODES * HIDDEN * 2);  // 6.4 MB
    float2*         t     = (float2*)alloc((size_t)N_NODES * 8);                   // 400 KB

    const int NB_V  = (N_NODES + 255) / 256;    // 196
    const int NB_E4 = (N_EDGES / 4 + 255) / 256;  // 782

    // CSR build (zero global atomics) + fused degree/scan/w2 prep
    hist2_kernel<<<CSPLIT * 4, 256, 0, stream>>>(src, dst, epos, pin, pout);
    prep_kernel<<<50, 256, 0, stream>>>(pin, pout, c_src, c_dst, offs, bsum,
                                        W2, We, b2, w2s, w2d, w2c);
    scan3_base_kernel<<<NB_V, 256, 0, stream>>>(offs, bsum, pin, base);
    fill_kernel<<<NB_E4, 256, 0, stream>>>(src, dst, epos, base, csr_src);

    // layer 1 GEMM: yb = bf16((x*c_src)@W1)
    const int NT1 = (N_NODES + 31) / 32;  // 1563 tiles
    gemm_scaled_kernel<IN_FEATS><<<NT1, 256, 0, stream>>>(x, c_src, W1, yb);

    // fused gather1 + relu + layer-2 dots -> t
    gather_t_kernel<<<N_NODES / 4, 256, 0, stream>>>(yb, offs, csr_src, c_src, c_dst,
                                                     b1, w2s, w2d, t);

    // layer-2 scalar gather -> a_s, a_d
    gather2_kernel<<<N_NODES / 16, 256, 0, stream>>>(t, offs, csr_src, c_dst, w2c, a_s, a_d);

    // edge output
    edge_out_kernel<<<NB_E4, 256, 0, stream>>>(src, dst, efeat, We, be, a_s, a_d, out);
}

// Round 11
// 102.321 us; speedup vs baseline: 2.5805x; 1.1674x over previous
//
#include <hip/hip_runtime.h>
#include <math.h>
#include <stdint.h>

#define N_NODES 50000
#define N_EDGES 800000
#define IN_FEATS 128
#define HIDDEN 64

// CSR build: 32 edge-chunks x (in|out) x 4 node-quarters, counts in LDS (packed
// 2 nodes per u32). The in-histogram pass ALSO emits each edge's slot index
// (epos, u16) so the CSR fill is a single coalesced pass. Zero global atomics
// (r6 post-mortem: device atomics write ~32B through to HBM each; spreading
// them doesn't help -- only reducing their count to zero does).
#define CSPLIT 32
#define CHUNK (N_EDGES / CSPLIT)   // 25000 edges, exact
#define NQUART (N_NODES / 4)       // 12500 nodes per quarter
#define NQWORDS (NQUART / 2)       // 6250 packed u32 (25 KB LDS)

typedef __attribute__((ext_vector_type(8))) short bf16x8;
typedef __attribute__((ext_vector_type(4))) float f32x4;

__device__ __forceinline__ unsigned short f2bf(float f) {
    unsigned u = __float_as_uint(f);
    u = (u + 0x7FFF + ((u >> 16) & 1)) >> 16;  // RNE
    return (unsigned short)u;
}

// --- per-(chunk, kind, quarter) packed histograms in LDS; epos for kind=in ---
__global__ __launch_bounds__(256) void hist2_kernel(const int* __restrict__ src,
                                                    const int* __restrict__ dst,
                                                    unsigned short* __restrict__ epos,
                                                    unsigned* __restrict__ pin,
                                                    unsigned* __restrict__ pout) {
    __shared__ unsigned cnt[NQWORDS];
    int b = blockIdx.x;            // 256 blocks
    int c = b >> 3;
    int kind = (b >> 2) & 1;       // 0 = in (dst) + epos, 1 = out (src)
    int quar = b & 3;
    int lo = quar * NQUART;
    for (int i = threadIdx.x; i < NQWORDS; i += 256) cnt[i] = 0;
    __syncthreads();
    if (kind == 0) {
        const int4* d4 = reinterpret_cast<const int4*>(dst + c * CHUNK);
        for (int i = threadIdx.x; i < CHUNK / 4; i += 256) {
            int4 d = d4[i];
            int e = c * CHUNK + i * 4;
            unsigned u, old;
            u = (unsigned)(d.x - lo);
            if (u < NQUART) { old = atomicAdd(&cnt[u >> 1], 1u << ((u & 1) * 16));
                              epos[e + 0] = (unsigned short)(old >> ((u & 1) * 16)); }
            u = (unsigned)(d.y - lo);
            if (u < NQUART) { old = atomicAdd(&cnt[u >> 1], 1u << ((u & 1) * 16));
                              epos[e + 1] = (unsigned short)(old >> ((u & 1) * 16)); }
            u = (unsigned)(d.z - lo);
            if (u < NQUART) { old = atomicAdd(&cnt[u >> 1], 1u << ((u & 1) * 16));
                              epos[e + 2] = (unsigned short)(old >> ((u & 1) * 16)); }
            u = (unsigned)(d.w - lo);
            if (u < NQUART) { old = atomicAdd(&cnt[u >> 1], 1u << ((u & 1) * 16));
                              epos[e + 3] = (unsigned short)(old >> ((u & 1) * 16)); }
        }
    } else {
        const int4* s4 = reinterpret_cast<const int4*>(src + c * CHUNK);
        for (int i = threadIdx.x; i < CHUNK / 4; i += 256) {
            int4 s = s4[i];
            unsigned u;
            u = (unsigned)(s.x - lo); if (u < NQUART) atomicAdd(&cnt[u >> 1], 1u << ((u & 1) * 16));
            u = (unsigned)(s.y - lo); if (u < NQUART) atomicAdd(&cnt[u >> 1], 1u << ((u & 1) * 16));
            u = (unsigned)(s.z - lo); if (u < NQUART) atomicAdd(&cnt[u >> 1], 1u << ((u & 1) * 16));
            u = (unsigned)(s.w - lo); if (u < NQUART) atomicAdd(&cnt[u >> 1], 1u << ((u & 1) * 16));
        }
    }
    __syncthreads();
    // global layout identical to the halves version: word w = node/2
    unsigned* outp = (kind ? pout : pin) + c * (N_NODES / 2) + quar * NQWORDS;
    for (int i = threadIdx.x; i < NQWORDS; i += 256) outp[i] = cnt[i];
}

// --- fused: degree-sum + c_src/c_dst + per-block exclusive scan (blocks 0..48,
//     1024 nodes each, 4/thread) ; block 49 = w2prep (w2s=W2@Ws, w2d=W2@Wd) ---
__global__ __launch_bounds__(256) void prep_kernel(const unsigned* __restrict__ pin,
                                                   const unsigned* __restrict__ pout,
                                                   float* __restrict__ cs,
                                                   float* __restrict__ cd,
                                                   int* __restrict__ offs,
                                                   int* __restrict__ bsum,
                                                   const float* __restrict__ W2,
                                                   const float* __restrict__ We,
                                                   const float* __restrict__ b2,
                                                   float* __restrict__ w2s,
                                                   float* __restrict__ w2d,
                                                   float* __restrict__ w2c) {
    int b = blockIdx.x;
    int t = threadIdx.x;
    if (b == 49) {  // w2prep tail block (no barriers on this path)
        if (t < 64) {
            float s = 0.f, d = 0.f;
            for (int j = 0; j < HIDDEN; ++j) {
                float w = W2[t * HIDDEN + j];
                s = fmaf(w, We[j], s);
                d = fmaf(w, We[HIDDEN + j], d);
            }
            w2s[t] = s;
            w2d[t] = d;
        } else if (t == 64) {
            float s = 0.f, d = 0.f;
            for (int j = 0; j < HIDDEN; ++j) {
                s = fmaf(We[j], b2[j], s);
                d = fmaf(We[HIDDEN + j], b2[j], d);
            }
            w2c[0] = s;
            w2c[1] = d;
        }
        return;
    }
    __shared__ int sums[256];
    int v0 = b * 1024 + t * 4;
    bool ok = v0 < N_NODES;
    unsigned si0 = 0, si1 = 0, si2 = 0, si3 = 0;
    unsigned so0 = 0, so1 = 0, so2 = 0, so3 = 0;
    if (ok) {
        int w0 = v0 >> 1;  // even (v0 % 4 == 0) -> uint2 aligned
#pragma unroll
        for (int c = 0; c < CSPLIT; ++c) {
            uint2 a = *reinterpret_cast<const uint2*>(pin + (size_t)c * (N_NODES / 2) + w0);
            uint2 o = *reinterpret_cast<const uint2*>(pout + (size_t)c * (N_NODES / 2) + w0);
            si0 += a.x & 0xffffu; si1 += a.x >> 16;
            si2 += a.y & 0xffffu; si3 += a.y >> 16;
            so0 += o.x & 0xffffu; so1 += o.x >> 16;
            so2 += o.y & 0xffffu; so3 += o.y >> 16;
        }
        *reinterpret_cast<float4*>(cs + v0) =
            make_float4(rsqrtf(fmaxf((float)so0, 1.f)), rsqrtf(fmaxf((float)so1, 1.f)),
                        rsqrtf(fmaxf((float)so2, 1.f)), rsqrtf(fmaxf((float)so3, 1.f)));
        *reinterpret_cast<float4*>(cd + v0) =
            make_float4(rsqrtf(fmaxf((float)si0, 1.f)), rsqrtf(fmaxf((float)si1, 1.f)),
                        rsqrtf(fmaxf((float)si2, 1.f)), rsqrtf(fmaxf((float)si3, 1.f)));
    }
    int d0 = (int)si0, d1 = (int)si1, d2 = (int)si2, d3 = (int)si3;
    sums[t] = d0 + d1 + d2 + d3;
    __syncthreads();
    for (int o = 1; o < 256; o <<= 1) {
        int v = (t >= o) ? sums[t - o] : 0;
        __syncthreads();
        sums[t] += v;
        __syncthreads();
    }
    int excl = (t == 0) ? 0 : sums[t - 1];
    if (ok) {
        *reinterpret_cast<int4*>(offs + v0) =
            make_int4(excl, excl + d0, excl + d0 + d1, excl + d0 + d1 + d2);
    }
    if (t == 255) bsum[b] = sums[255];
}

// --- finalize offs + per-chunk base offsets; the 49-entry bsum scan is done
//     redundantly per block in the first wave (cheaper than a dedicated launch) ---
__global__ __launch_bounds__(256) void scan3_base_kernel(int* __restrict__ offs,
                                                         const int* __restrict__ bsum,
                                                         const unsigned* __restrict__ pin,
                                                         int* __restrict__ base) {
    __shared__ int sbase[64];
    int t = threadIdx.x;
    if (t < 64) {
        int val = (t < 49) ? bsum[t] : 0;
        int s = val;
#pragma unroll
        for (int o = 1; o < 64; o <<= 1) {
            int u = __shfl_up(s, o, 64);
            if (t >= o) s += u;
        }
        sbase[t] = s - val;  // exclusive
    }
    __syncthreads();
    int v = blockIdx.x * 256 + t;
    if (v >= N_NODES) return;
    int off = offs[v] + sbase[v >> 10];
    offs[v] = off;
    int run = off;
    int sh = (v & 1) * 16;
#pragma unroll
    for (int c = 0; c < CSPLIT; ++c) {
        base[(size_t)c * N_NODES + v] = run;
        run += (int)((pin[(size_t)c * (N_NODES / 2) + (v >> 1)] >> sh) & 0xffffu);
    }
    if (v == 0) offs[N_NODES] = N_EDGES;
}

// --- CSR fill, single coalesced pass: slot = base[c][dst] + epos ---
__global__ __launch_bounds__(256) void fill_kernel(const int* __restrict__ src,
                                                   const int* __restrict__ dst,
                                                   const unsigned short* __restrict__ epos,
                                                   const int* __restrict__ base,
                                                   int* __restrict__ csr_src) {
    int t = blockIdx.x * 256 + threadIdx.x;
    int e0 = t * 4;
    if (e0 >= N_EDGES) return;
    int c = e0 / CHUNK;  // CHUNK % 4 == 0 -> uniform over the 4 edges
    const int* basec = base + (size_t)c * N_NODES;
    int4 s = *reinterpret_cast<const int4*>(src + e0);
    int4 d = *reinterpret_cast<const int4*>(dst + e0);
    ushort4 ep = *reinterpret_cast<const ushort4*>(epos + e0);
    csr_src[basec[d.x] + ep.x] = s.x;
    csr_src[basec[d.y] + ep.y] = s.y;
    csr_src[basec[d.z] + ep.z] = s.z;
    csr_src[basec[d.w] + ep.w] = s.w;
}

// --- y[v,:] = bf16( c_src[v] * (x[v,:] @ W1) ) via v_mfma_f32_16x16x32_bf16 ---
// W1 staged once as bf16 fragments in LDS (swizzled: each (nt,kt) frag is a
// contiguous ds_read_b128 per lane), read once into 64 VGPRs. A-frags loaded
// straight from global x (row = lane&15, k = kt*32 + (lane>>4)*8 + j: each row's
// 4 lane-groups cover 128B contiguous). C layout (verified m89):
// col = lane&15, row = (lane>>4)*4 + reg.
__global__ __launch_bounds__(256) void gemm_mfma_kernel(const float* __restrict__ x,
                                                        const float* __restrict__ c_src,
                                                        const float* __restrict__ W,
                                                        unsigned short* __restrict__ yb) {
    __shared__ bf16x8 Bfrag[16][64];  // 16 KB
    for (int idx = threadIdx.x; idx < 16 * 64; idx += 256) {
        int f = idx >> 6, l = idx & 63;
        int nt = f >> 2, kt = f & 3;
        int col = nt * 16 + (l & 15);
        int k0 = kt * 32 + (l >> 4) * 8;
        bf16x8 bv;
#pragma unroll
        for (int j = 0; j < 8; ++j) bv[j] = (short)f2bf(W[(k0 + j) * HIDDEN + col]);
        Bfrag[f][l] = bv;
    }
    __syncthreads();
    int wid = threadIdx.x >> 6, l = threadIdx.x & 63;
    bf16x8 Breg[16];
#pragma unroll
    for (int f = 0; f < 16; ++f) Breg[f] = Bfrag[f][l];

    int row0 = blockIdx.x * 64 + wid * 16;  // this wave's 16-row tile
    int arow = row0 + (l & 15);
    int asafe = min(arow, N_NODES - 1);     // clamp OOB rows (stores guarded)
    const float* xr = x + (size_t)asafe * IN_FEATS + (l >> 4) * 8;
    f32x4 acc0 = {0.f, 0.f, 0.f, 0.f};
    f32x4 acc1 = {0.f, 0.f, 0.f, 0.f};
    f32x4 acc2 = {0.f, 0.f, 0.f, 0.f};
    f32x4 acc3 = {0.f, 0.f, 0.f, 0.f};
#pragma unroll
    for (int kt = 0; kt < 4; ++kt) {
        float4 a0 = *reinterpret_cast<const float4*>(xr + kt * 32);
        float4 a1 = *reinterpret_cast<const float4*>(xr + kt * 32 + 4);
        bf16x8 av;
        av[0] = (short)f2bf(a0.x); av[1] = (short)f2bf(a0.y);
        av[2] = (short)f2bf(a0.z); av[3] = (short)f2bf(a0.w);
        av[4] = (short)f2bf(a1.x); av[5] = (short)f2bf(a1.y);
        av[6] = (short)f2bf(a1.z); av[7] = (short)f2bf(a1.w);
        acc0 = __builtin_amdgcn_mfma_f32_16x16x32_bf16(av, Breg[0 * 4 + kt], acc0, 0, 0, 0);
        acc1 = __builtin_amdgcn_mfma_f32_16x16x32_bf16(av, Breg[1 * 4 + kt], acc1, 0, 0, 0);
        acc2 = __builtin_amdgcn_mfma_f32_16x16x32_bf16(av, Breg[2 * 4 + kt], acc2, 0, 0, 0);
        acc3 = __builtin_amdgcn_mfma_f32_16x16x32_bf16(av, Breg[3 * 4 + kt], acc3, 0, 0, 0);
    }
#pragma unroll
    for (int i = 0; i < 4; ++i) {
        int row = row0 + (l >> 4) * 4 + i;
        if (row < N_NODES) {
            float cs = c_src[row];
            unsigned short* yr = yb + (size_t)row * HIDDEN + (l & 15);
            yr[0]  = f2bf(acc0[i] * cs);
            yr[16] = f2bf(acc1[i] * cs);
            yr[32] = f2bf(acc2[i] * cs);
            yr[48] = f2bf(acc3[i] * cs);
        }
    }
}

// --- layer1 gather (bf16 y, 8 slots x 8 lanes x uint4 = 8 edges/iter, 2x-deep
//     main loop = 16 edges in flight) + relu/bias + layer-2 collapse -> t[v] ---
__global__ __launch_bounds__(256) void gather_t_kernel(const unsigned short* __restrict__ y,
                                                       const int* __restrict__ offs,
                                                       const int* __restrict__ csr_src,
                                                       const float* __restrict__ c_src,
                                                       const float* __restrict__ c_dst,
                                                       const float* __restrict__ b1,
                                                       const float* __restrict__ w2s,
                                                       const float* __restrict__ w2d,
                                                       float2* __restrict__ t) {
    int wid = threadIdx.x >> 6, l = threadIdx.x & 63;
    int slot = l >> 3, q8 = l & 7;  // 8 edge-slots x 8 feature-octets
    int v = blockIdx.x * 4 + wid;   // grid exact: 12500 * 4 = 50000
    int beg = offs[v], end = offs[v + 1];
    float acc[8] = {0.f, 0.f, 0.f, 0.f, 0.f, 0.f, 0.f, 0.f};
    int k = beg;
    for (; k + 16 <= end; k += 16) {
        int sA = csr_src[k + slot];
        int sB = csr_src[k + 8 + slot];
        uint4 rA = *reinterpret_cast<const uint4*>(y + (size_t)sA * HIDDEN + q8 * 8);
        uint4 rB = *reinterpret_cast<const uint4*>(y + (size_t)sB * HIDDEN + q8 * 8);
        acc[0] += __uint_as_float(rA.x << 16);
        acc[1] += __uint_as_float(rA.x & 0xffff0000u);
        acc[2] += __uint_as_float(rA.y << 16);
        acc[3] += __uint_as_float(rA.y & 0xffff0000u);
        acc[4] += __uint_as_float(rA.z << 16);
        acc[5] += __uint_as_float(rA.z & 0xffff0000u);
        acc[6] += __uint_as_float(rA.w << 16);
        acc[7] += __uint_as_float(rA.w & 0xffff0000u);
        acc[0] += __uint_as_float(rB.x << 16);
        acc[1] += __uint_as_float(rB.x & 0xffff0000u);
        acc[2] += __uint_as_float(rB.y << 16);
        acc[3] += __uint_as_float(rB.y & 0xffff0000u);
        acc[4] += __uint_as_float(rB.z << 16);
        acc[5] += __uint_as_float(rB.z & 0xffff0000u);
        acc[6] += __uint_as_float(rB.w << 16);
        acc[7] += __uint_as_float(rB.w & 0xffff0000u);
    }
    if (k + 8 <= end) {
        int s = csr_src[k + slot];
        uint4 r = *reinterpret_cast<const uint4*>(y + (size_t)s * HIDDEN + q8 * 8);
        acc[0] += __uint_as_float(r.x << 16);
        acc[1] += __uint_as_float(r.x & 0xffff0000u);
        acc[2] += __uint_as_float(r.y << 16);
        acc[3] += __uint_as_float(r.y & 0xffff0000u);
        acc[4] += __uint_as_float(r.z << 16);
        acc[5] += __uint_as_float(r.z & 0xffff0000u);
        acc[6] += __uint_as_float(r.w << 16);
        acc[7] += __uint_as_float(r.w & 0xffff0000u);
        k += 8;
    }
    if (slot < end - k) {
        int s = csr_src[k + slot];
        uint4 r = *reinterpret_cast<const uint4*>(y + (size_t)s * HIDDEN + q8 * 8);
        acc[0] += __uint_as_float(r.x << 16);
        acc[1] += __uint_as_float(r.x & 0xffff0000u);
        acc[2] += __uint_as_float(r.y << 16);
        acc[3] += __uint_as_float(r.y & 0xffff0000u);
        acc[4] += __uint_as_float(r.z << 16);
        acc[5] += __uint_as_float(r.z & 0xffff0000u);
        acc[6] += __uint_as_float(r.w << 16);
        acc[7] += __uint_as_float(r.w & 0xffff0000u);
    }
    // combine 8 slots (lanes with equal q8)
#pragma unroll
    for (int i = 0; i < 8; ++i) {
        acc[i] += __shfl_xor(acc[i], 8, 64);
        acc[i] += __shfl_xor(acc[i], 16, 64);
        acc[i] += __shfl_xor(acc[i], 32, 64);
    }
    float c = c_dst[v];
    float4 ba = *reinterpret_cast<const float4*>(b1 + q8 * 8);
    float4 bb = *reinterpret_cast<const float4*>(b1 + q8 * 8 + 4);
    float4 wsa = *reinterpret_cast<const float4*>(w2s + q8 * 8);
    float4 wsb = *reinterpret_cast<const float4*>(w2s + q8 * 8 + 4);
    float4 wda = *reinterpret_cast<const float4*>(w2d + q8 * 8);
    float4 wdb = *reinterpret_cast<const float4*>(w2d + q8 * 8 + 4);
    float h0 = fmaxf(fmaf(c, acc[0], ba.x), 0.f);
    float h1 = fmaxf(fmaf(c, acc[1], ba.y), 0.f);
    float h2 = fmaxf(fmaf(c, acc[2], ba.z), 0.f);
    float h3 = fmaxf(fmaf(c, acc[3], ba.w), 0.f);
    float h4 = fmaxf(fmaf(c, acc[4], bb.x), 0.f);
    float h5 = fmaxf(fmaf(c, acc[5], bb.y), 0.f);
    float h6 = fmaxf(fmaf(c, acc[6], bb.z), 0.f);
    float h7 = fmaxf(fmaf(c, acc[7], bb.w), 0.f);
    float ps = h0 * wsa.x + h1 * wsa.y + h2 * wsa.z + h3 * wsa.w
             + h4 * wsb.x + h5 * wsb.y + h6 * wsb.z + h7 * wsb.w;
    float pd = h0 * wda.x + h1 * wda.y + h2 * wda.z + h3 * wda.w
             + h4 * wdb.x + h5 * wdb.y + h6 * wdb.z + h7 * wdb.w;
#pragma unroll
    for (int o = 1; o <= 4; o <<= 1) {
        ps += __shfl_xor(ps, o, 64);
        pd += __shfl_xor(pd, o, 64);
    }
    if (l == 0) {
        float cs = c_src[v];
        t[v] = make_float2(cs * ps, cs * pd);
    }
}

// --- layer2 scalar gather: a_s[v] = c_dst[v]*sum(t_s over in-edges) + Ws.b2 ---
__global__ __launch_bounds__(256) void gather2_kernel(const float2* __restrict__ t,
                                                      const int* __restrict__ offs,
                                                      const int* __restrict__ csr_src,
                                                      const float* __restrict__ c_dst,
                                                      const float* __restrict__ w2c,
                                                      float* __restrict__ a_s,
                                                      float* __restrict__ a_d) {
    int wid = threadIdx.x >> 6, l = threadIdx.x & 63;
    int sub = l >> 4, q = l & 15;
    int v = blockIdx.x * 16 + wid * 4 + sub;  // grid exact: 3125 * 16 = 50000
    int beg = offs[v], end = offs[v + 1];
    float ps = 0.f, pd = 0.f;
    for (int k = beg + q; k < end; k += 16) {
        float2 tv = t[csr_src[k]];
        ps += tv.x;
        pd += tv.y;
    }
#pragma unroll
    for (int o = 1; o <= 8; o <<= 1) {
        ps += __shfl_xor(ps, o, 64);
        pd += __shfl_xor(pd, o, 64);
    }
    if (q == 0) {
        float c = c_dst[v];
        a_s[v] = fmaf(c, ps, w2c[0]);
        a_d[v] = fmaf(c, pd, w2c[1]);
    }
}

// --- out[e] = sigmoid(a_s[src] + a_d[dst] + efeat.Wf + be), 4 edges/thread ---
__global__ __launch_bounds__(256) void edge_out_kernel(const int* __restrict__ src,
                                                       const int* __restrict__ dst,
                                                       const float* __restrict__ efeat,
                                                       const float* __restrict__ We,
                                                       const float* __restrict__ be,
                                                       const float* __restrict__ a_s,
                                                       const float* __restrict__ a_d,
                                                       float* __restrict__ out) {
    int t = blockIdx.x * 256 + threadIdx.x;
    int e0 = t * 4;
    if (e0 >= N_EDGES) return;
    float w0 = We[2 * HIDDEN + 0], w1 = We[2 * HIDDEN + 1], w2 = We[2 * HIDDEN + 2];
    float b = be[0];
    int4 s = *reinterpret_cast<const int4*>(src + e0);
    int4 d = *reinterpret_cast<const int4*>(dst + e0);
    const float4* f = reinterpret_cast<const float4*>(efeat + (long)e0 * 3);
    float4 f0 = f[0], f1 = f[1], f2 = f[2];
    float4 o;
    float z;
    z = a_s[s.x] + a_d[d.x] + f0.x * w0 + f0.y * w1 + f0.z * w2 + b;
    o.x = 1.0f / (1.0f + __expf(-z));
    z = a_s[s.y] + a_d[d.y] + f0.w * w0 + f1.x * w1 + f1.y * w2 + b;
    o.y = 1.0f / (1.0f + __expf(-z));
    z = a_s[s.z] + a_d[d.z] + f1.z * w0 + f1.w * w1 + f2.x * w2 + b;
    o.z = 1.0f / (1.0f + __expf(-z));
    z = a_s[s.w] + a_d[d.w] + f2.y * w0 + f2.z * w1 + f2.w * w2 + b;
    o.w = 1.0f / (1.0f + __expf(-z));
    *reinterpret_cast<float4*>(out + e0) = o;
}

extern "C" void kernel_launch(void* const* d_in, const int* in_sizes, int n_in,
                              void* d_out, int out_size, void* d_ws, size_t ws_size,
                              hipStream_t stream) {
    const float* x     = (const float*)d_in[0];
    const float* efeat = (const float*)d_in[1];
    const int*   src   = (const int*)d_in[2];
    const int*   dst   = (const int*)d_in[3];
    const float* W1    = (const float*)d_in[4];
    const float* b1    = (const float*)d_in[5];
    const float* W2    = (const float*)d_in[6];
    const float* b2    = (const float*)d_in[7];
    const float* We    = (const float*)d_in[8];
    const float* be    = (const float*)d_in[9];
    float* out = (float*)d_out;

    // 256B-aligned workspace carve-up; ~25 MB total.
    char* p = (char*)d_ws;
    auto alloc = [&](size_t bytes) {
        char* r = p;
        p += (bytes + 255) & ~(size_t)255;
        return r;
    };
    float* c_src   = (float*)alloc((size_t)N_NODES * 4);
    float* c_dst   = (float*)alloc((size_t)N_NODES * 4);
    float* a_s     = (float*)alloc((size_t)N_NODES * 4);
    float* a_d     = (float*)alloc((size_t)N_NODES * 4);
    int*   offs    = (int*)alloc((size_t)(N_NODES + 1) * 4);
    int*   bsum    = (int*)alloc(64 * 4);
    float* w2s     = (float*)alloc(HIDDEN * 4);
    float* w2d     = (float*)alloc(HIDDEN * 4);
    float* w2c     = (float*)alloc(2 * 4);
    unsigned*       pin   = (unsigned*)alloc((size_t)CSPLIT * (N_NODES / 2) * 4);  // 3.2 MB
    unsigned*       pout  = (unsigned*)alloc((size_t)CSPLIT * (N_NODES / 2) * 4);  // 3.2 MB
    unsigned short* epos  = (unsigned short*)alloc((size_t)N_EDGES * 2);           // 1.6 MB
    int*            base  = (int*)alloc((size_t)CSPLIT * N_NODES * 4);             // 6.4 MB
    int*            csr_src = (int*)alloc((size_t)N_EDGES * 4);                    // 3.2 MB
    unsigned short* yb    = (unsigned short*)alloc((size_t)N_NODES * HIDDEN * 2);  // 6.4 MB
    float2*         t     = (float2*)alloc((size_t)N_NODES * 8);                   // 400 KB

    const int NB_V  = (N_NODES + 255) / 256;      // 196
    const int NB_E4 = (N_EDGES / 4 + 255) / 256;  // 782

    // CSR build (zero global atomics) + fused degree/scan/w2 prep
    hist2_kernel<<<CSPLIT * 8, 256, 0, stream>>>(src, dst, epos, pin, pout);
    prep_kernel<<<50, 256, 0, stream>>>(pin, pout, c_src, c_dst, offs, bsum,
                                        W2, We, b2, w2s, w2d, w2c);
    scan3_base_kernel<<<NB_V, 256, 0, stream>>>(offs, bsum, pin, base);
    fill_kernel<<<NB_E4, 256, 0, stream>>>(src, dst, epos, base, csr_src);

    // layer 1 GEMM via MFMA: yb = bf16((x*c_src)@W1)
    gemm_mfma_kernel<<<(N_NODES + 63) / 64, 256, 0, stream>>>(x, c_src, W1, yb);

    // fused gather1 + relu + layer-2 dots -> t
    gather_t_kernel<<<N_NODES / 4, 256, 0, stream>>>(yb, offs, csr_src, c_src, c_dst,
                                                     b1, w2s, w2d, t);

    // layer-2 scalar gather -> a_s, a_d
    gather2_kernel<<<N_NODES / 16, 256, 0, stream>>>(t, offs, csr_src, c_dst, w2c, a_s, a_d);

    // edge output
    edge_out_kernel<<<NB_E4, 256, 0, stream>>>(src, dst, efeat, We, be, a_s, a_d, out);
}

// Round 12
// 100.298 us; speedup vs baseline: 2.6325x; 1.0202x over previous
//
#include <hip/hip_runtime.h>
#include <math.h>
#include <stdint.h>

#define N_NODES 50000
#define N_EDGES 800000
#define IN_FEATS 128
#define HIDDEN 64

// CSR build: 32 edge-chunks x (in|out) x 4 node-quarters, counts in LDS (packed
// 2 nodes per u32). The in-histogram pass ALSO emits each edge's slot index
// (epos, u16) so the CSR fill is a single coalesced pass. Zero global atomics
// (r6 post-mortem: device atomics write ~32B through to HBM each; spreading
// them doesn't help -- only reducing their count to zero does).
#define CSPLIT 32
#define CHUNK (N_EDGES / CSPLIT)   // 25000 edges, exact
#define NQUART (N_NODES / 4)       // 12500 nodes per quarter
#define NQWORDS (NQUART / 2)       // 6250 packed u32 (25 KB LDS)

#define NB_E4 782                  // ceil(200000/256) edge-quad blocks
#define NB_GEMM 782                // ceil(50000/64) 64-row MFMA tiles

typedef __attribute__((ext_vector_type(8))) short bf16x8;
typedef __attribute__((ext_vector_type(4))) float f32x4;

__device__ __forceinline__ unsigned short f2bf(float f) {
    unsigned u = __float_as_uint(f);
    u = (u + 0x7FFF + ((u >> 16) & 1)) >> 16;  // RNE
    return (unsigned short)u;
}

// --- per-(chunk, kind, quarter) packed histograms in LDS; epos for kind=in ---
__global__ __launch_bounds__(256) void hist2_kernel(const int* __restrict__ src,
                                                    const int* __restrict__ dst,
                                                    unsigned short* __restrict__ epos,
                                                    unsigned* __restrict__ pin,
                                                    unsigned* __restrict__ pout) {
    __shared__ unsigned cnt[NQWORDS];
    int b = blockIdx.x;            // 256 blocks
    int c = b >> 3;
    int kind = (b >> 2) & 1;       // 0 = in (dst) + epos, 1 = out (src)
    int quar = b & 3;
    int lo = quar * NQUART;
    for (int i = threadIdx.x; i < NQWORDS; i += 256) cnt[i] = 0;
    __syncthreads();
    if (kind == 0) {
        const int4* d4 = reinterpret_cast<const int4*>(dst + c * CHUNK);
        for (int i = threadIdx.x; i < CHUNK / 4; i += 256) {
            int4 d = d4[i];
            int e = c * CHUNK + i * 4;
            unsigned u, old;
            u = (unsigned)(d.x - lo);
            if (u < NQUART) { old = atomicAdd(&cnt[u >> 1], 1u << ((u & 1) * 16));
                              epos[e + 0] = (unsigned short)(old >> ((u & 1) * 16)); }
            u = (unsigned)(d.y - lo);
            if (u < NQUART) { old = atomicAdd(&cnt[u >> 1], 1u << ((u & 1) * 16));
                              epos[e + 1] = (unsigned short)(old >> ((u & 1) * 16)); }
            u = (unsigned)(d.z - lo);
            if (u < NQUART) { old = atomicAdd(&cnt[u >> 1], 1u << ((u & 1) * 16));
                              epos[e + 2] = (unsigned short)(old >> ((u & 1) * 16)); }
            u = (unsigned)(d.w - lo);
            if (u < NQUART) { old = atomicAdd(&cnt[u >> 1], 1u << ((u & 1) * 16));
                              epos[e + 3] = (unsigned short)(old >> ((u & 1) * 16)); }
        }
    } else {
        const int4* s4 = reinterpret_cast<const int4*>(src + c * CHUNK);
        for (int i = threadIdx.x; i < CHUNK / 4; i += 256) {
            int4 s = s4[i];
            unsigned u;
            u = (unsigned)(s.x - lo); if (u < NQUART) atomicAdd(&cnt[u >> 1], 1u << ((u & 1) * 16));
            u = (unsigned)(s.y - lo); if (u < NQUART) atomicAdd(&cnt[u >> 1], 1u << ((u & 1) * 16));
            u = (unsigned)(s.z - lo); if (u < NQUART) atomicAdd(&cnt[u >> 1], 1u << ((u & 1) * 16));
            u = (unsigned)(s.w - lo); if (u < NQUART) atomicAdd(&cnt[u >> 1], 1u << ((u & 1) * 16));
        }
    }
    __syncthreads();
    // global layout: word w = node/2
    unsigned* outp = (kind ? pout : pin) + c * (N_NODES / 2) + quar * NQWORDS;
    for (int i = threadIdx.x; i < NQWORDS; i += 256) outp[i] = cnt[i];
}

// --- fused: degree-sum + c_src/c_dst + per-block exclusive scan (blocks 0..48,
//     1024 nodes each, 4/thread) ; block 49 = w2prep (w2s=W2@Ws, w2d=W2@Wd) ---
__global__ __launch_bounds__(256) void prep_kernel(const unsigned* __restrict__ pin,
                                                   const unsigned* __restrict__ pout,
                                                   float* __restrict__ cs,
                                                   float* __restrict__ cd,
                                                   int* __restrict__ offs,
                                                   int* __restrict__ bsum,
                                                   const float* __restrict__ W2,
                                                   const float* __restrict__ We,
                                                   const float* __restrict__ b2,
                                                   float* __restrict__ w2s,
                                                   float* __restrict__ w2d,
                                                   float* __restrict__ w2c) {
    int b = blockIdx.x;
    int t = threadIdx.x;
    if (b == 49) {  // w2prep tail block (no barriers on this path)
        if (t < 64) {
            float s = 0.f, d = 0.f;
            for (int j = 0; j < HIDDEN; ++j) {
                float w = W2[t * HIDDEN + j];
                s = fmaf(w, We[j], s);
                d = fmaf(w, We[HIDDEN + j], d);
            }
            w2s[t] = s;
            w2d[t] = d;
        } else if (t == 64) {
            float s = 0.f, d = 0.f;
            for (int j = 0; j < HIDDEN; ++j) {
                s = fmaf(We[j], b2[j], s);
                d = fmaf(We[HIDDEN + j], b2[j], d);
            }
            w2c[0] = s;
            w2c[1] = d;
        }
        return;
    }
    __shared__ int sums[256];
    int v0 = b * 1024 + t * 4;
    bool ok = v0 < N_NODES;
    unsigned si0 = 0, si1 = 0, si2 = 0, si3 = 0;
    unsigned so0 = 0, so1 = 0, so2 = 0, so3 = 0;
    if (ok) {
        int w0 = v0 >> 1;  // even (v0 % 4 == 0) -> uint2 aligned
#pragma unroll
        for (int c = 0; c < CSPLIT; ++c) {
            uint2 a = *reinterpret_cast<const uint2*>(pin + (size_t)c * (N_NODES / 2) + w0);
            uint2 o = *reinterpret_cast<const uint2*>(pout + (size_t)c * (N_NODES / 2) + w0);
            si0 += a.x & 0xffffu; si1 += a.x >> 16;
            si2 += a.y & 0xffffu; si3 += a.y >> 16;
            so0 += o.x & 0xffffu; so1 += o.x >> 16;
            so2 += o.y & 0xffffu; so3 += o.y >> 16;
        }
        *reinterpret_cast<float4*>(cs + v0) =
            make_float4(rsqrtf(fmaxf((float)so0, 1.f)), rsqrtf(fmaxf((float)so1, 1.f)),
                        rsqrtf(fmaxf((float)so2, 1.f)), rsqrtf(fmaxf((float)so3, 1.f)));
        *reinterpret_cast<float4*>(cd + v0) =
            make_float4(rsqrtf(fmaxf((float)si0, 1.f)), rsqrtf(fmaxf((float)si1, 1.f)),
                        rsqrtf(fmaxf((float)si2, 1.f)), rsqrtf(fmaxf((float)si3, 1.f)));
    }
    int d0 = (int)si0, d1 = (int)si1, d2 = (int)si2, d3 = (int)si3;
    sums[t] = d0 + d1 + d2 + d3;
    __syncthreads();
    for (int o = 1; o < 256; o <<= 1) {
        int v = (t >= o) ? sums[t - o] : 0;
        __syncthreads();
        sums[t] += v;
        __syncthreads();
    }
    int excl = (t == 0) ? 0 : sums[t - 1];
    if (ok) {
        *reinterpret_cast<int4*>(offs + v0) =
            make_int4(excl, excl + d0, excl + d0 + d1, excl + d0 + d1 + d2);
    }
    if (t == 255) bsum[b] = sums[255];
}

// --- finalize offs + RELATIVE per-chunk base offsets (u16: rel <= in-deg[v]);
//     the 49-entry bsum scan runs redundantly per block (cheaper than a launch) ---
__global__ __launch_bounds__(256) void scan3_base_kernel(int* __restrict__ offs,
                                                         const int* __restrict__ bsum,
                                                         const unsigned* __restrict__ pin,
                                                         unsigned short* __restrict__ baser) {
    __shared__ int sbase[64];
    int t = threadIdx.x;
    if (t < 64) {
        int val = (t < 49) ? bsum[t] : 0;
        int s = val;
#pragma unroll
        for (int o = 1; o < 64; o <<= 1) {
            int u = __shfl_up(s, o, 64);
            if (t >= o) s += u;
        }
        sbase[t] = s - val;  // exclusive
    }
    __syncthreads();
    int v = blockIdx.x * 256 + t;
    if (v >= N_NODES) return;
    int off = offs[v] + sbase[v >> 10];
    offs[v] = off;
    int rel = 0;
    int sh = (v & 1) * 16;
#pragma unroll
    for (int c = 0; c < CSPLIT; ++c) {
        baser[(size_t)c * N_NODES + v] = (unsigned short)rel;
        rel += (int)((pin[(size_t)c * (N_NODES / 2) + (v >> 1)] >> sh) & 0xffffu);
    }
    if (v == 0) offs[N_NODES] = N_EDGES;
}

// --- FUSED launch: blocks [0, NB_E4) = CSR fill ; blocks [NB_E4, +NB_GEMM) =
//     MFMA GEMM. Independent work (fill needs scan3's offs/baser; gemm needs
//     prep's c_src) -> overlap fill's scattered stores with gemm's MFMA. ---
__global__ __launch_bounds__(256) void fill_gemm_kernel(const int* __restrict__ src,
                                                        const int* __restrict__ dst,
                                                        const unsigned short* __restrict__ epos,
                                                        const int* __restrict__ offs,
                                                        const unsigned short* __restrict__ baser,
                                                        int* __restrict__ csr_src,
                                                        const float* __restrict__ x,
                                                        const float* __restrict__ c_src,
                                                        const float* __restrict__ W,
                                                        unsigned short* __restrict__ yb) {
    __shared__ bf16x8 Bfrag[16][64];  // 16 KB (gemm blocks only)
    if (blockIdx.x < NB_E4) {
        // ---- CSR fill: slot = offs[dst] + baser[c][dst] + epos ----
        int t = blockIdx.x * 256 + threadIdx.x;
        int e0 = t * 4;
        if (e0 >= N_EDGES) return;
        int c = e0 / CHUNK;  // CHUNK % 4 == 0 -> uniform over the 4 edges
        const unsigned short* brc = baser + (size_t)c * N_NODES;
        int4 s = *reinterpret_cast<const int4*>(src + e0);
        int4 d = *reinterpret_cast<const int4*>(dst + e0);
        ushort4 ep = *reinterpret_cast<const ushort4*>(epos + e0);
        csr_src[offs[d.x] + brc[d.x] + ep.x] = s.x;
        csr_src[offs[d.y] + brc[d.y] + ep.y] = s.y;
        csr_src[offs[d.z] + brc[d.z] + ep.z] = s.z;
        csr_src[offs[d.w] + brc[d.w] + ep.w] = s.w;
        return;
    }
    // ---- MFMA GEMM: yb = bf16(c_src * (x @ W1)) ----
    // W1 staged as bf16 fragments in LDS (each (nt,kt) frag contiguous b128/lane),
    // read once into 64 VGPRs. A-frags straight from global x. C layout (m89):
    // col = lane&15, row = (lane>>4)*4 + reg.
    int gb = blockIdx.x - NB_E4;
    for (int idx = threadIdx.x; idx < 16 * 64; idx += 256) {
        int f = idx >> 6, l = idx & 63;
        int nt = f >> 2, kt = f & 3;
        int col = nt * 16 + (l & 15);
        int k0 = kt * 32 + (l >> 4) * 8;
        bf16x8 bv;
#pragma unroll
        for (int j = 0; j < 8; ++j) bv[j] = (short)f2bf(W[(k0 + j) * HIDDEN + col]);
        Bfrag[f][l] = bv;
    }
    __syncthreads();
    int wid = threadIdx.x >> 6, l = threadIdx.x & 63;
    bf16x8 Breg[16];
#pragma unroll
    for (int f = 0; f < 16; ++f) Breg[f] = Bfrag[f][l];

    int row0 = gb * 64 + wid * 16;  // this wave's 16-row tile
    int arow = row0 + (l & 15);
    int asafe = min(arow, N_NODES - 1);  // clamp OOB rows (stores guarded)
    const float* xr = x + (size_t)asafe * IN_FEATS + (l >> 4) * 8;
    f32x4 acc0 = {0.f, 0.f, 0.f, 0.f};
    f32x4 acc1 = {0.f, 0.f, 0.f, 0.f};
    f32x4 acc2 = {0.f, 0.f, 0.f, 0.f};
    f32x4 acc3 = {0.f, 0.f, 0.f, 0.f};
#pragma unroll
    for (int kt = 0; kt < 4; ++kt) {
        float4 a0 = *reinterpret_cast<const float4*>(xr + kt * 32);
        float4 a1 = *reinterpret_cast<const float4*>(xr + kt * 32 + 4);
        bf16x8 av;
        av[0] = (short)f2bf(a0.x); av[1] = (short)f2bf(a0.y);
        av[2] = (short)f2bf(a0.z); av[3] = (short)f2bf(a0.w);
        av[4] = (short)f2bf(a1.x); av[5] = (short)f2bf(a1.y);
        av[6] = (short)f2bf(a1.z); av[7] = (short)f2bf(a1.w);
        acc0 = __builtin_amdgcn_mfma_f32_16x16x32_bf16(av, Breg[0 * 4 + kt], acc0, 0, 0, 0);
        acc1 = __builtin_amdgcn_mfma_f32_16x16x32_bf16(av, Breg[1 * 4 + kt], acc1, 0, 0, 0);
        acc2 = __builtin_amdgcn_mfma_f32_16x16x32_bf16(av, Breg[2 * 4 + kt], acc2, 0, 0, 0);
        acc3 = __builtin_amdgcn_mfma_f32_16x16x32_bf16(av, Breg[3 * 4 + kt], acc3, 0, 0, 0);
    }
#pragma unroll
    for (int i = 0; i < 4; ++i) {
        int row = row0 + (l >> 4) * 4 + i;
        if (row < N_NODES) {
            float cs = c_src[row];
            unsigned short* yr = yb + (size_t)row * HIDDEN + (l & 15);
            yr[0]  = f2bf(acc0[i] * cs);
            yr[16] = f2bf(acc1[i] * cs);
            yr[32] = f2bf(acc2[i] * cs);
            yr[48] = f2bf(acc3[i] * cs);
        }
    }
}

// --- layer1 gather (bf16 y, 8 slots x 8 lanes x uint4 = 8 edges/iter, 2x-deep
//     main loop = 16 edges in flight) + relu/bias + layer-2 collapse -> t[v] ---
__global__ __launch_bounds__(256) void gather_t_kernel(const unsigned short* __restrict__ y,
                                                       const int* __restrict__ offs,
                                                       const int* __restrict__ csr_src,
                                                       const float* __restrict__ c_src,
                                                       const float* __restrict__ c_dst,
                                                       const float* __restrict__ b1,
                                                       const float* __restrict__ w2s,
                                                       const float* __restrict__ w2d,
                                                       float2* __restrict__ t) {
    int wid = threadIdx.x >> 6, l = threadIdx.x & 63;
    int slot = l >> 3, q8 = l & 7;  // 8 edge-slots x 8 feature-octets
    int v = blockIdx.x * 4 + wid;   // grid exact: 12500 * 4 = 50000
    int beg = offs[v], end = offs[v + 1];
    float acc[8] = {0.f, 0.f, 0.f, 0.f, 0.f, 0.f, 0.f, 0.f};
    int k = beg;
    for (; k + 16 <= end; k += 16) {
        int sA = csr_src[k + slot];
        int sB = csr_src[k + 8 + slot];
        uint4 rA = *reinterpret_cast<const uint4*>(y + (size_t)sA * HIDDEN + q8 * 8);
        uint4 rB = *reinterpret_cast<const uint4*>(y + (size_t)sB * HIDDEN + q8 * 8);
        acc[0] += __uint_as_float(rA.x << 16);
        acc[1] += __uint_as_float(rA.x & 0xffff0000u);
        acc[2] += __uint_as_float(rA.y << 16);
        acc[3] += __uint_as_float(rA.y & 0xffff0000u);
        acc[4] += __uint_as_float(rA.z << 16);
        acc[5] += __uint_as_float(rA.z & 0xffff0000u);
        acc[6] += __uint_as_float(rA.w << 16);
        acc[7] += __uint_as_float(rA.w & 0xffff0000u);
        acc[0] += __uint_as_float(rB.x << 16);
        acc[1] += __uint_as_float(rB.x & 0xffff0000u);
        acc[2] += __uint_as_float(rB.y << 16);
        acc[3] += __uint_as_float(rB.y & 0xffff0000u);
        acc[4] += __uint_as_float(rB.z << 16);
        acc[5] += __uint_as_float(rB.z & 0xffff0000u);
        acc[6] += __uint_as_float(rB.w << 16);
        acc[7] += __uint_as_float(rB.w & 0xffff0000u);
    }
    if (k + 8 <= end) {
        int s = csr_src[k + slot];
        uint4 r = *reinterpret_cast<const uint4*>(y + (size_t)s * HIDDEN + q8 * 8);
        acc[0] += __uint_as_float(r.x << 16);
        acc[1] += __uint_as_float(r.x & 0xffff0000u);
        acc[2] += __uint_as_float(r.y << 16);
        acc[3] += __uint_as_float(r.y & 0xffff0000u);
        acc[4] += __uint_as_float(r.z << 16);
        acc[5] += __uint_as_float(r.z & 0xffff0000u);
        acc[6] += __uint_as_float(r.w << 16);
        acc[7] += __uint_as_float(r.w & 0xffff0000u);
        k += 8;
    }
    if (slot < end - k) {
        int s = csr_src[k + slot];
        uint4 r = *reinterpret_cast<const uint4*>(y + (size_t)s * HIDDEN + q8 * 8);
        acc[0] += __uint_as_float(r.x << 16);
        acc[1] += __uint_as_float(r.x & 0xffff0000u);
        acc[2] += __uint_as_float(r.y << 16);
        acc[3] += __uint_as_float(r.y & 0xffff0000u);
        acc[4] += __uint_as_float(r.z << 16);
        acc[5] += __uint_as_float(r.z & 0xffff0000u);
        acc[6] += __uint_as_float(r.w << 16);
        acc[7] += __uint_as_float(r.w & 0xffff0000u);
    }
    // combine 8 slots (lanes with equal q8)
#pragma unroll
    for (int i = 0; i < 8; ++i) {
        acc[i] += __shfl_xor(acc[i], 8, 64);
        acc[i] += __shfl_xor(acc[i], 16, 64);
        acc[i] += __shfl_xor(acc[i], 32, 64);
    }
    float c = c_dst[v];
    float4 ba = *reinterpret_cast<const float4*>(b1 + q8 * 8);
    float4 bb = *reinterpret_cast<const float4*>(b1 + q8 * 8 + 4);
    float4 wsa = *reinterpret_cast<const float4*>(w2s + q8 * 8);
    float4 wsb = *reinterpret_cast<const float4*>(w2s + q8 * 8 + 4);
    float4 wda = *reinterpret_cast<const float4*>(w2d + q8 * 8);
    float4 wdb = *reinterpret_cast<const float4*>(w2d + q8 * 8 + 4);
    float h0 = fmaxf(fmaf(c, acc[0], ba.x), 0.f);
    float h1 = fmaxf(fmaf(c, acc[1], ba.y), 0.f);
    float h2 = fmaxf(fmaf(c, acc[2], ba.z), 0.f);
    float h3 = fmaxf(fmaf(c, acc[3], ba.w), 0.f);
    float h4 = fmaxf(fmaf(c, acc[4], bb.x), 0.f);
    float h5 = fmaxf(fmaf(c, acc[5], bb.y), 0.f);
    float h6 = fmaxf(fmaf(c, acc[6], bb.z), 0.f);
    float h7 = fmaxf(fmaf(c, acc[7], bb.w), 0.f);
    float ps = h0 * wsa.x + h1 * wsa.y + h2 * wsa.z + h3 * wsa.w
             + h4 * wsb.x + h5 * wsb.y + h6 * wsb.z + h7 * wsb.w;
    float pd = h0 * wda.x + h1 * wda.y + h2 * wda.z + h3 * wda.w
             + h4 * wdb.x + h5 * wdb.y + h6 * wdb.z + h7 * wdb.w;
#pragma unroll
    for (int o = 1; o <= 4; o <<= 1) {
        ps += __shfl_xor(ps, o, 64);
        pd += __shfl_xor(pd, o, 64);
    }
    if (l == 0) {
        float cs = c_src[v];
        t[v] = make_float2(cs * ps, cs * pd);
    }
}

// --- layer2 scalar gather: a_s[v] = c_dst[v]*sum(t_s over in-edges) + Ws.b2 ---
__global__ __launch_bounds__(256) void gather2_kernel(const float2* __restrict__ t,
                                                      const int* __restrict__ offs,
                                                      const int* __restrict__ csr_src,
                                                      const float* __restrict__ c_dst,
                                                      const float* __restrict__ w2c,
                                                      float* __restrict__ a_s,
                                                      float* __restrict__ a_d) {
    int wid = threadIdx.x >> 6, l = threadIdx.x & 63;
    int sub = l >> 4, q = l & 15;
    int v = blockIdx.x * 16 + wid * 4 + sub;  // grid exact: 3125 * 16 = 50000
    int beg = offs[v], end = offs[v + 1];
    float ps = 0.f, pd = 0.f;
    for (int k = beg + q; k < end; k += 16) {
        float2 tv = t[csr_src[k]];
        ps += tv.x;
        pd += tv.y;
    }
#pragma unroll
    for (int o = 1; o <= 8; o <<= 1) {
        ps += __shfl_xor(ps, o, 64);
        pd += __shfl_xor(pd, o, 64);
    }
    if (q == 0) {
        float c = c_dst[v];
        a_s[v] = fmaf(c, ps, w2c[0]);
        a_d[v] = fmaf(c, pd, w2c[1]);
    }
}

// --- out[e] = sigmoid(a_s[src] + a_d[dst] + efeat.Wf + be), 4 edges/thread ---
__global__ __launch_bounds__(256) void edge_out_kernel(const int* __restrict__ src,
                                                       const int* __restrict__ dst,
                                                       const float* __restrict__ efeat,
                                                       const float* __restrict__ We,
                                                       const float* __restrict__ be,
                                                       const float* __restrict__ a_s,
                                                       const float* __restrict__ a_d,
                                                       float* __restrict__ out) {
    int t = blockIdx.x * 256 + threadIdx.x;
    int e0 = t * 4;
    if (e0 >= N_EDGES) return;
    float w0 = We[2 * HIDDEN + 0], w1 = We[2 * HIDDEN + 1], w2 = We[2 * HIDDEN + 2];
    float b = be[0];
    int4 s = *reinterpret_cast<const int4*>(src + e0);
    int4 d = *reinterpret_cast<const int4*>(dst + e0);
    const float4* f = reinterpret_cast<const float4*>(efeat + (long)e0 * 3);
    float4 f0 = f[0], f1 = f[1], f2 = f[2];
    float4 o;
    float z;
    z = a_s[s.x] + a_d[d.x] + f0.x * w0 + f0.y * w1 + f0.z * w2 + b;
    o.x = 1.0f / (1.0f + __expf(-z));
    z = a_s[s.y] + a_d[d.y] + f0.w * w0 + f1.x * w1 + f1.y * w2 + b;
    o.y = 1.0f / (1.0f + __expf(-z));
    z = a_s[s.z] + a_d[d.z] + f1.z * w0 + f1.w * w1 + f2.x * w2 + b;
    o.z = 1.0f / (1.0f + __expf(-z));
    z = a_s[s.w] + a_d[d.w] + f2.y * w0 + f2.z * w1 + f2.w * w2 + b;
    o.w = 1.0f / (1.0f + __expf(-z));
    *reinterpret_cast<float4*>(out + e0) = o;
}

extern "C" void kernel_launch(void* const* d_in, const int* in_sizes, int n_in,
                              void* d_out, int out_size, void* d_ws, size_t ws_size,
                              hipStream_t stream) {
    const float* x     = (const float*)d_in[0];
    const float* efeat = (const float*)d_in[1];
    const int*   src   = (const int*)d_in[2];
    const int*   dst   = (const int*)d_in[3];
    const float* W1    = (const float*)d_in[4];
    const float* b1    = (const float*)d_in[5];
    const float* W2    = (const float*)d_in[6];
    const float* b2    = (const float*)d_in[7];
    const float* We    = (const float*)d_in[8];
    const float* be    = (const float*)d_in[9];
    float* out = (float*)d_out;

    // 256B-aligned workspace carve-up; ~22 MB total.
    char* p = (char*)d_ws;
    auto alloc = [&](size_t bytes) {
        char* r = p;
        p += (bytes + 255) & ~(size_t)255;
        return r;
    };
    float* c_src   = (float*)alloc((size_t)N_NODES * 4);
    float* c_dst   = (float*)alloc((size_t)N_NODES * 4);
    float* a_s     = (float*)alloc((size_t)N_NODES * 4);
    float* a_d     = (float*)alloc((size_t)N_NODES * 4);
    int*   offs    = (int*)alloc((size_t)(N_NODES + 1) * 4);
    int*   bsum    = (int*)alloc(64 * 4);
    float* w2s     = (float*)alloc(HIDDEN * 4);
    float* w2d     = (float*)alloc(HIDDEN * 4);
    float* w2c     = (float*)alloc(2 * 4);
    unsigned*       pin   = (unsigned*)alloc((size_t)CSPLIT * (N_NODES / 2) * 4);  // 3.2 MB
    unsigned*       pout  = (unsigned*)alloc((size_t)CSPLIT * (N_NODES / 2) * 4);  // 3.2 MB
    unsigned short* epos  = (unsigned short*)alloc((size_t)N_EDGES * 2);           // 1.6 MB
    unsigned short* baser = (unsigned short*)alloc((size_t)CSPLIT * N_NODES * 2);  // 3.2 MB
    int*            csr_src = (int*)alloc((size_t)N_EDGES * 4);                    // 3.2 MB
    unsigned short* yb    = (unsigned short*)alloc((size_t)N_NODES * HIDDEN * 2);  // 6.4 MB
    float2*         t     = (float2*)alloc((size_t)N_NODES * 8);                   // 400 KB

    const int NB_V = (N_NODES + 255) / 256;  // 196

    // CSR build (zero global atomics) + fused degree/scan/w2 prep
    hist2_kernel<<<CSPLIT * 8, 256, 0, stream>>>(src, dst, epos, pin, pout);
    prep_kernel<<<50, 256, 0, stream>>>(pin, pout, c_src, c_dst, offs, bsum,
                                        W2, We, b2, w2s, w2d, w2c);
    scan3_base_kernel<<<NB_V, 256, 0, stream>>>(offs, bsum, pin, baser);

    // fused: CSR fill (scattered stores) overlapped with MFMA layer-1 GEMM
    fill_gemm_kernel<<<NB_E4 + NB_GEMM, 256, 0, stream>>>(src, dst, epos, offs, baser,
                                                          csr_src, x, c_src, W1, yb);

    // fused gather1 + relu + layer-2 dots -> t
    gather_t_kernel<<<N_NODES / 4, 256, 0, stream>>>(yb, offs, csr_src, c_src, c_dst,
                                                     b1, w2s, w2d, t);

    // layer-2 scalar gather -> a_s, a_d
    gather2_kernel<<<N_NODES / 16, 256, 0, stream>>>(t, offs, csr_src, c_dst, w2c, a_s, a_d);

    // edge output
    edge_out_kernel<<<NB_E4, 256, 0, stream>>>(src, dst, efeat, We, be, a_s, a_d, out);
}

// Round 13
// 97.398 us; speedup vs baseline: 2.7109x; 1.0298x over previous
//
#include <hip/hip_runtime.h>
#include <math.h>
#include <stdint.h>

#define N_NODES 50000
#define N_EDGES 800000
#define IN_FEATS 128
#define HIDDEN 64

// CSR build: 32 edge-chunks x (in|out) x 4 node-quarters, counts in LDS (packed
// 2 nodes per u32). The in-histogram pass ALSO emits each edge's slot index
// (epos, u16) so the CSR fill is a single coalesced pass. Zero global atomics
// (r6 post-mortem: device atomics write ~32B through to HBM each; spreading
// them doesn't help -- only reducing their count to zero does).
#define CSPLIT 32
#define CHUNK (N_EDGES / CSPLIT)   // 25000 edges, exact
#define NQUART (N_NODES / 4)       // 12500 nodes per quarter
#define NQWORDS (NQUART / 2)       // 6250 packed u32 (25 KB LDS)

#define NB_E4 782                  // ceil(200000/256) edge-quad blocks
#define NB_GEMM 782                // ceil(50000/64) 64-row MFMA tiles

typedef __attribute__((ext_vector_type(8))) short bf16x8;
typedef __attribute__((ext_vector_type(4))) float f32x4;

__device__ __forceinline__ unsigned short f2bf(float f) {
    unsigned u = __float_as_uint(f);
    u = (u + 0x7FFF + ((u >> 16) & 1)) >> 16;  // RNE
    return (unsigned short)u;
}

#define ACC8(A, r)                                \
    A[0] += __uint_as_float((r).x << 16);         \
    A[1] += __uint_as_float((r).x & 0xffff0000u); \
    A[2] += __uint_as_float((r).y << 16);         \
    A[3] += __uint_as_float((r).y & 0xffff0000u); \
    A[4] += __uint_as_float((r).z << 16);         \
    A[5] += __uint_as_float((r).z & 0xffff0000u); \
    A[6] += __uint_as_float((r).w << 16);         \
    A[7] += __uint_as_float((r).w & 0xffff0000u);

// --- per-(chunk, kind, quarter) packed histograms in LDS; epos for kind=in ---
__global__ __launch_bounds__(256) void hist2_kernel(const int* __restrict__ src,
                                                    const int* __restrict__ dst,
                                                    unsigned short* __restrict__ epos,
                                                    unsigned* __restrict__ pin,
                                                    unsigned* __restrict__ pout) {
    __shared__ unsigned cnt[NQWORDS];
    int b = blockIdx.x;            // 256 blocks
    int c = b >> 3;
    int kind = (b >> 2) & 1;       // 0 = in (dst) + epos, 1 = out (src)
    int quar = b & 3;
    int lo = quar * NQUART;
    for (int i = threadIdx.x; i < NQWORDS; i += 256) cnt[i] = 0;
    __syncthreads();
    if (kind == 0) {
        const int4* d4 = reinterpret_cast<const int4*>(dst + c * CHUNK);
        for (int i = threadIdx.x; i < CHUNK / 4; i += 256) {
            int4 d = d4[i];
            int e = c * CHUNK + i * 4;
            unsigned u, old;
            u = (unsigned)(d.x - lo);
            if (u < NQUART) { old = atomicAdd(&cnt[u >> 1], 1u << ((u & 1) * 16));
                              epos[e + 0] = (unsigned short)(old >> ((u & 1) * 16)); }
            u = (unsigned)(d.y - lo);
            if (u < NQUART) { old = atomicAdd(&cnt[u >> 1], 1u << ((u & 1) * 16));
                              epos[e + 1] = (unsigned short)(old >> ((u & 1) * 16)); }
            u = (unsigned)(d.z - lo);
            if (u < NQUART) { old = atomicAdd(&cnt[u >> 1], 1u << ((u & 1) * 16));
                              epos[e + 2] = (unsigned short)(old >> ((u & 1) * 16)); }
            u = (unsigned)(d.w - lo);
            if (u < NQUART) { old = atomicAdd(&cnt[u >> 1], 1u << ((u & 1) * 16));
                              epos[e + 3] = (unsigned short)(old >> ((u & 1) * 16)); }
        }
    } else {
        const int4* s4 = reinterpret_cast<const int4*>(src + c * CHUNK);
        for (int i = threadIdx.x; i < CHUNK / 4; i += 256) {
            int4 s = s4[i];
            unsigned u;
            u = (unsigned)(s.x - lo); if (u < NQUART) atomicAdd(&cnt[u >> 1], 1u << ((u & 1) * 16));
            u = (unsigned)(s.y - lo); if (u < NQUART) atomicAdd(&cnt[u >> 1], 1u << ((u & 1) * 16));
            u = (unsigned)(s.z - lo); if (u < NQUART) atomicAdd(&cnt[u >> 1], 1u << ((u & 1) * 16));
            u = (unsigned)(s.w - lo); if (u < NQUART) atomicAdd(&cnt[u >> 1], 1u << ((u & 1) * 16));
        }
    }
    __syncthreads();
    // global layout: word w = node/2
    unsigned* outp = (kind ? pout : pin) + c * (N_NODES / 2) + quar * NQWORDS;
    for (int i = threadIdx.x; i < NQWORDS; i += 256) outp[i] = cnt[i];
}

// --- fused: degree-sum + c_src/c_dst + per-block exclusive scan (blocks 0..48,
//     1024 nodes each, 4/thread) ; block 49 = w2prep (w2s=W2@Ws, w2d=W2@Wd) ---
__global__ __launch_bounds__(256) void prep_kernel(const unsigned* __restrict__ pin,
                                                   const unsigned* __restrict__ pout,
                                                   float* __restrict__ cs,
                                                   float* __restrict__ cd,
                                                   int* __restrict__ offs,
                                                   int* __restrict__ bsum,
                                                   const float* __restrict__ W2,
                                                   const float* __restrict__ We,
                                                   const float* __restrict__ b2,
                                                   float* __restrict__ w2s,
                                                   float* __restrict__ w2d,
                                                   float* __restrict__ w2c) {
    int b = blockIdx.x;
    int t = threadIdx.x;
    if (b == 49) {  // w2prep tail block (no barriers on this path)
        if (t < 64) {
            float s = 0.f, d = 0.f;
            for (int j = 0; j < HIDDEN; ++j) {
                float w = W2[t * HIDDEN + j];
                s = fmaf(w, We[j], s);
                d = fmaf(w, We[HIDDEN + j], d);
            }
            w2s[t] = s;
            w2d[t] = d;
        } else if (t == 64) {
            float s = 0.f, d = 0.f;
            for (int j = 0; j < HIDDEN; ++j) {
                s = fmaf(We[j], b2[j], s);
                d = fmaf(We[HIDDEN + j], b2[j], d);
            }
            w2c[0] = s;
            w2c[1] = d;
        }
        return;
    }
    __shared__ int sums[256];
    int v0 = b * 1024 + t * 4;
    bool ok = v0 < N_NODES;
    unsigned si0 = 0, si1 = 0, si2 = 0, si3 = 0;
    unsigned so0 = 0, so1 = 0, so2 = 0, so3 = 0;
    if (ok) {
        int w0 = v0 >> 1;  // even (v0 % 4 == 0) -> uint2 aligned
#pragma unroll
        for (int c = 0; c < CSPLIT; ++c) {
            uint2 a = *reinterpret_cast<const uint2*>(pin + (size_t)c * (N_NODES / 2) + w0);
            uint2 o = *reinterpret_cast<const uint2*>(pout + (size_t)c * (N_NODES / 2) + w0);
            si0 += a.x & 0xffffu; si1 += a.x >> 16;
            si2 += a.y & 0xffffu; si3 += a.y >> 16;
            so0 += o.x & 0xffffu; so1 += o.x >> 16;
            so2 += o.y & 0xffffu; so3 += o.y >> 16;
        }
        *reinterpret_cast<float4*>(cs + v0) =
            make_float4(rsqrtf(fmaxf((float)so0, 1.f)), rsqrtf(fmaxf((float)so1, 1.f)),
                        rsqrtf(fmaxf((float)so2, 1.f)), rsqrtf(fmaxf((float)so3, 1.f)));
        *reinterpret_cast<float4*>(cd + v0) =
            make_float4(rsqrtf(fmaxf((float)si0, 1.f)), rsqrtf(fmaxf((float)si1, 1.f)),
                        rsqrtf(fmaxf((float)si2, 1.f)), rsqrtf(fmaxf((float)si3, 1.f)));
    }
    int d0 = (int)si0, d1 = (int)si1, d2 = (int)si2, d3 = (int)si3;
    sums[t] = d0 + d1 + d2 + d3;
    __syncthreads();
    for (int o = 1; o < 256; o <<= 1) {
        int v = (t >= o) ? sums[t - o] : 0;
        __syncthreads();
        sums[t] += v;
        __syncthreads();
    }
    int excl = (t == 0) ? 0 : sums[t - 1];
    if (ok) {
        *reinterpret_cast<int4*>(offs + v0) =
            make_int4(excl, excl + d0, excl + d0 + d1, excl + d0 + d1 + d2);
    }
    if (t == 255) bsum[b] = sums[255];
}

// --- finalize offs + RELATIVE per-chunk base offsets (u16: rel <= in-deg[v]);
//     the 49-entry bsum scan runs redundantly per block (cheaper than a launch) ---
__global__ __launch_bounds__(256) void scan3_base_kernel(int* __restrict__ offs,
                                                         const int* __restrict__ bsum,
                                                         const unsigned* __restrict__ pin,
                                                         unsigned short* __restrict__ baser) {
    __shared__ int sbase[64];
    int t = threadIdx.x;
    if (t < 64) {
        int val = (t < 49) ? bsum[t] : 0;
        int s = val;
#pragma unroll
        for (int o = 1; o < 64; o <<= 1) {
            int u = __shfl_up(s, o, 64);
            if (t >= o) s += u;
        }
        sbase[t] = s - val;  // exclusive
    }
    __syncthreads();
    int v = blockIdx.x * 256 + t;
    if (v >= N_NODES) return;
    int off = offs[v] + sbase[v >> 10];
    offs[v] = off;
    int rel = 0;
    int sh = (v & 1) * 16;
#pragma unroll
    for (int c = 0; c < CSPLIT; ++c) {
        baser[(size_t)c * N_NODES + v] = (unsigned short)rel;
        rel += (int)((pin[(size_t)c * (N_NODES / 2) + (v >> 1)] >> sh) & 0xffffu);
    }
    if (v == 0) offs[N_NODES] = N_EDGES;
}

// --- FUSED launch: blocks [0, NB_E4) = CSR fill ; blocks [NB_E4, +NB_GEMM) =
//     MFMA GEMM. Independent work -> overlap scattered stores with MFMA. ---
__global__ __launch_bounds__(256) void fill_gemm_kernel(const int* __restrict__ src,
                                                        const int* __restrict__ dst,
                                                        const unsigned short* __restrict__ epos,
                                                        const int* __restrict__ offs,
                                                        const unsigned short* __restrict__ baser,
                                                        int* __restrict__ csr_src,
                                                        const float* __restrict__ x,
                                                        const float* __restrict__ c_src,
                                                        const float* __restrict__ W,
                                                        unsigned short* __restrict__ yb) {
    __shared__ bf16x8 Bfrag[16][64];  // 16 KB (gemm blocks only)
    if (blockIdx.x < NB_E4) {
        // ---- CSR fill: slot = offs[dst] + baser[c][dst] + epos ----
        int t = blockIdx.x * 256 + threadIdx.x;
        int e0 = t * 4;
        if (e0 >= N_EDGES) return;
        int c = e0 / CHUNK;  // CHUNK % 4 == 0 -> uniform over the 4 edges
        const unsigned short* brc = baser + (size_t)c * N_NODES;
        int4 s = *reinterpret_cast<const int4*>(src + e0);
        int4 d = *reinterpret_cast<const int4*>(dst + e0);
        ushort4 ep = *reinterpret_cast<const ushort4*>(epos + e0);
        csr_src[offs[d.x] + brc[d.x] + ep.x] = s.x;
        csr_src[offs[d.y] + brc[d.y] + ep.y] = s.y;
        csr_src[offs[d.z] + brc[d.z] + ep.z] = s.z;
        csr_src[offs[d.w] + brc[d.w] + ep.w] = s.w;
        return;
    }
    // ---- MFMA GEMM: yb = bf16(c_src * (x @ W1)) ----
    // C layout (m89): col = lane&15, row = (lane>>4)*4 + reg.
    int gb = blockIdx.x - NB_E4;
    for (int idx = threadIdx.x; idx < 16 * 64; idx += 256) {
        int f = idx >> 6, l = idx & 63;
        int nt = f >> 2, kt = f & 3;
        int col = nt * 16 + (l & 15);
        int k0 = kt * 32 + (l >> 4) * 8;
        bf16x8 bv;
#pragma unroll
        for (int j = 0; j < 8; ++j) bv[j] = (short)f2bf(W[(k0 + j) * HIDDEN + col]);
        Bfrag[f][l] = bv;
    }
    __syncthreads();
    int wid = threadIdx.x >> 6, l = threadIdx.x & 63;
    bf16x8 Breg[16];
#pragma unroll
    for (int f = 0; f < 16; ++f) Breg[f] = Bfrag[f][l];

    int row0 = gb * 64 + wid * 16;  // this wave's 16-row tile
    int arow = row0 + (l & 15);
    int asafe = min(arow, N_NODES - 1);  // clamp OOB rows (stores guarded)
    const float* xr = x + (size_t)asafe * IN_FEATS + (l >> 4) * 8;
    f32x4 acc0 = {0.f, 0.f, 0.f, 0.f};
    f32x4 acc1 = {0.f, 0.f, 0.f, 0.f};
    f32x4 acc2 = {0.f, 0.f, 0.f, 0.f};
    f32x4 acc3 = {0.f, 0.f, 0.f, 0.f};
#pragma unroll
    for (int kt = 0; kt < 4; ++kt) {
        float4 a0 = *reinterpret_cast<const float4*>(xr + kt * 32);
        float4 a1 = *reinterpret_cast<const float4*>(xr + kt * 32 + 4);
        bf16x8 av;
        av[0] = (short)f2bf(a0.x); av[1] = (short)f2bf(a0.y);
        av[2] = (short)f2bf(a0.z); av[3] = (short)f2bf(a0.w);
        av[4] = (short)f2bf(a1.x); av[5] = (short)f2bf(a1.y);
        av[6] = (short)f2bf(a1.z); av[7] = (short)f2bf(a1.w);
        acc0 = __builtin_amdgcn_mfma_f32_16x16x32_bf16(av, Breg[0 * 4 + kt], acc0, 0, 0, 0);
        acc1 = __builtin_amdgcn_mfma_f32_16x16x32_bf16(av, Breg[1 * 4 + kt], acc1, 0, 0, 0);
        acc2 = __builtin_amdgcn_mfma_f32_16x16x32_bf16(av, Breg[2 * 4 + kt], acc2, 0, 0, 0);
        acc3 = __builtin_amdgcn_mfma_f32_16x16x32_bf16(av, Breg[3 * 4 + kt], acc3, 0, 0, 0);
    }
#pragma unroll
    for (int i = 0; i < 4; ++i) {
        int row = row0 + (l >> 4) * 4 + i;
        if (row < N_NODES) {
            float cs = c_src[row];
            unsigned short* yr = yb + (size_t)row * HIDDEN + (l & 15);
            yr[0]  = f2bf(acc0[i] * cs);
            yr[16] = f2bf(acc1[i] * cs);
            yr[32] = f2bf(acc2[i] * cs);
            yr[48] = f2bf(acc3[i] * cs);
        }
    }
}

// --- layer1 gather, TWO nodes per wave interleaved (doubles in-flight gathers
//     per wave -- r12 post-mortem: gather_t is latency-bound, not BW-bound).
//     8 slots x 8 lanes x uint4; relu/bias + layer-2 collapse -> t[v0], t[v1] ---
__global__ __launch_bounds__(256) void gather_t_kernel(const unsigned short* __restrict__ y,
                                                       const int* __restrict__ offs,
                                                       const int* __restrict__ csr_src,
                                                       const float* __restrict__ c_src,
                                                       const float* __restrict__ c_dst,
                                                       const float* __restrict__ b1,
                                                       const float* __restrict__ w2s,
                                                       const float* __restrict__ w2d,
                                                       float2* __restrict__ t) {
    int wid = threadIdx.x >> 6, l = threadIdx.x & 63;
    int slot = l >> 3, q8 = l & 7;      // 8 edge-slots x 8 feature-octets
    int v0 = blockIdx.x * 8 + wid * 2;  // grid exact: 6250 * 8 = 50000
    int v1 = v0 + 1;
    int beg0 = offs[v0], end0 = offs[v0 + 1], end1 = offs[v0 + 2];
    int k0 = beg0, k1 = end0;  // v1's edges start where v0's end
    float acc0[8] = {0.f, 0.f, 0.f, 0.f, 0.f, 0.f, 0.f, 0.f};
    float acc1[8] = {0.f, 0.f, 0.f, 0.f, 0.f, 0.f, 0.f, 0.f};
    // dual main loop: 2 independent gather streams in flight
    while (k0 + 8 <= end0 && k1 + 8 <= end1) {
        int sA = csr_src[k0 + slot];
        int sB = csr_src[k1 + slot];
        uint4 rA = *reinterpret_cast<const uint4*>(y + (size_t)sA * HIDDEN + q8 * 8);
        uint4 rB = *reinterpret_cast<const uint4*>(y + (size_t)sB * HIDDEN + q8 * 8);
        ACC8(acc0, rA);
        ACC8(acc1, rB);
        k0 += 8;
        k1 += 8;
    }
    while (k0 + 8 <= end0) {
        int s = csr_src[k0 + slot];
        uint4 r = *reinterpret_cast<const uint4*>(y + (size_t)s * HIDDEN + q8 * 8);
        ACC8(acc0, r);
        k0 += 8;
    }
    while (k1 + 8 <= end1) {
        int s = csr_src[k1 + slot];
        uint4 r = *reinterpret_cast<const uint4*>(y + (size_t)s * HIDDEN + q8 * 8);
        ACC8(acc1, r);
        k1 += 8;
    }
    if (slot < end0 - k0) {
        int s = csr_src[k0 + slot];
        uint4 r = *reinterpret_cast<const uint4*>(y + (size_t)s * HIDDEN + q8 * 8);
        ACC8(acc0, r);
    }
    if (slot < end1 - k1) {
        int s = csr_src[k1 + slot];
        uint4 r = *reinterpret_cast<const uint4*>(y + (size_t)s * HIDDEN + q8 * 8);
        ACC8(acc1, r);
    }
    // combine 8 slots (lanes with equal q8), both nodes
#pragma unroll
    for (int i = 0; i < 8; ++i) {
        acc0[i] += __shfl_xor(acc0[i], 8, 64);
        acc0[i] += __shfl_xor(acc0[i], 16, 64);
        acc0[i] += __shfl_xor(acc0[i], 32, 64);
        acc1[i] += __shfl_xor(acc1[i], 8, 64);
        acc1[i] += __shfl_xor(acc1[i], 16, 64);
        acc1[i] += __shfl_xor(acc1[i], 32, 64);
    }
    float4 ba = *reinterpret_cast<const float4*>(b1 + q8 * 8);
    float4 bb = *reinterpret_cast<const float4*>(b1 + q8 * 8 + 4);
    float4 wsa = *reinterpret_cast<const float4*>(w2s + q8 * 8);
    float4 wsb = *reinterpret_cast<const float4*>(w2s + q8 * 8 + 4);
    float4 wda = *reinterpret_cast<const float4*>(w2d + q8 * 8);
    float4 wdb = *reinterpret_cast<const float4*>(w2d + q8 * 8 + 4);
    float c0 = c_dst[v0], c1 = c_dst[v1];
    float h0, h1, h2, h3, h4, h5, h6, h7;
    h0 = fmaxf(fmaf(c0, acc0[0], ba.x), 0.f);
    h1 = fmaxf(fmaf(c0, acc0[1], ba.y), 0.f);
    h2 = fmaxf(fmaf(c0, acc0[2], ba.z), 0.f);
    h3 = fmaxf(fmaf(c0, acc0[3], ba.w), 0.f);
    h4 = fmaxf(fmaf(c0, acc0[4], bb.x), 0.f);
    h5 = fmaxf(fmaf(c0, acc0[5], bb.y), 0.f);
    h6 = fmaxf(fmaf(c0, acc0[6], bb.z), 0.f);
    h7 = fmaxf(fmaf(c0, acc0[7], bb.w), 0.f);
    float ps0 = h0 * wsa.x + h1 * wsa.y + h2 * wsa.z + h3 * wsa.w
              + h4 * wsb.x + h5 * wsb.y + h6 * wsb.z + h7 * wsb.w;
    float pd0 = h0 * wda.x + h1 * wda.y + h2 * wda.z + h3 * wda.w
              + h4 * wdb.x + h5 * wdb.y + h6 * wdb.z + h7 * wdb.w;
    h0 = fmaxf(fmaf(c1, acc1[0], ba.x), 0.f);
    h1 = fmaxf(fmaf(c1, acc1[1], ba.y), 0.f);
    h2 = fmaxf(fmaf(c1, acc1[2], ba.z), 0.f);
    h3 = fmaxf(fmaf(c1, acc1[3], ba.w), 0.f);
    h4 = fmaxf(fmaf(c1, acc1[4], bb.x), 0.f);
    h5 = fmaxf(fmaf(c1, acc1[5], bb.y), 0.f);
    h6 = fmaxf(fmaf(c1, acc1[6], bb.z), 0.f);
    h7 = fmaxf(fmaf(c1, acc1[7], bb.w), 0.f);
    float ps1 = h0 * wsa.x + h1 * wsa.y + h2 * wsa.z + h3 * wsa.w
              + h4 * wsb.x + h5 * wsb.y + h6 * wsb.z + h7 * wsb.w;
    float pd1 = h0 * wda.x + h1 * wda.y + h2 * wda.z + h3 * wda.w
              + h4 * wdb.x + h5 * wdb.y + h6 * wdb.z + h7 * wdb.w;
#pragma unroll
    for (int o = 1; o <= 4; o <<= 1) {
        ps0 += __shfl_xor(ps0, o, 64);
        pd0 += __shfl_xor(pd0, o, 64);
        ps1 += __shfl_xor(ps1, o, 64);
        pd1 += __shfl_xor(pd1, o, 64);
    }
    if (l == 0) {
        float cs0 = c_src[v0], cs1 = c_src[v1];
        // t[v0], t[v1] are consecutive float2 -> one float4 store (v0 even)
        *reinterpret_cast<float4*>(t + v0) =
            make_float4(cs0 * ps0, cs0 * pd0, cs1 * ps1, cs1 * pd1);
    }
}

// --- layer2 scalar gather: a_s[v] = c_dst[v]*sum(t_s over in-edges) + Ws.b2 ---
__global__ __launch_bounds__(256) void gather2_kernel(const float2* __restrict__ t,
                                                      const int* __restrict__ offs,
                                                      const int* __restrict__ csr_src,
                                                      const float* __restrict__ c_dst,
                                                      const float* __restrict__ w2c,
                                                      float* __restrict__ a_s,
                                                      float* __restrict__ a_d) {
    int wid = threadIdx.x >> 6, l = threadIdx.x & 63;
    int sub = l >> 4, q = l & 15;
    int v = blockIdx.x * 16 + wid * 4 + sub;  // grid exact: 3125 * 16 = 50000
    int beg = offs[v], end = offs[v + 1];
    float ps = 0.f, pd = 0.f;
    for (int k = beg + q; k < end; k += 16) {
        float2 tv = t[csr_src[k]];
        ps += tv.x;
        pd += tv.y;
    }
#pragma unroll
    for (int o = 1; o <= 8; o <<= 1) {
        ps += __shfl_xor(ps, o, 64);
        pd += __shfl_xor(pd, o, 64);
    }
    if (q == 0) {
        float c = c_dst[v];
        a_s[v] = fmaf(c, ps, w2c[0]);
        a_d[v] = fmaf(c, pd, w2c[1]);
    }
}

// --- out[e] = sigmoid(a_s[src] + a_d[dst] + efeat.Wf + be), 8 edges/thread
//     (8 independent a_s/a_d random loads in flight) ---
__global__ __launch_bounds__(256) void edge_out_kernel(const int* __restrict__ src,
                                                       const int* __restrict__ dst,
                                                       const float* __restrict__ efeat,
                                                       const float* __restrict__ We,
                                                       const float* __restrict__ be,
                                                       const float* __restrict__ a_s,
                                                       const float* __restrict__ a_d,
                                                       float* __restrict__ out) {
    int t = blockIdx.x * 256 + threadIdx.x;
    int e0 = t * 8;
    if (e0 >= N_EDGES) return;  // N_EDGES % 8 == 0 -> full octets
    float w0 = We[2 * HIDDEN + 0], w1 = We[2 * HIDDEN + 1], w2 = We[2 * HIDDEN + 2];
    float b = be[0];
    int4 sA = *reinterpret_cast<const int4*>(src + e0);
    int4 sB = *reinterpret_cast<const int4*>(src + e0 + 4);
    int4 dA = *reinterpret_cast<const int4*>(dst + e0);
    int4 dB = *reinterpret_cast<const int4*>(dst + e0 + 4);
    const float4* f = reinterpret_cast<const float4*>(efeat + (long)e0 * 3);
    float4 f0 = f[0], f1 = f[1], f2 = f[2], f3 = f[3], f4 = f[4], f5 = f[5];
    float as0 = a_s[sA.x], as1 = a_s[sA.y], as2 = a_s[sA.z], as3 = a_s[sA.w];
    float as4 = a_s[sB.x], as5 = a_s[sB.y], as6 = a_s[sB.z], as7 = a_s[sB.w];
    float ad0 = a_d[dA.x], ad1 = a_d[dA.y], ad2 = a_d[dA.z], ad3 = a_d[dA.w];
    float ad4 = a_d[dB.x], ad5 = a_d[dB.y], ad6 = a_d[dB.z], ad7 = a_d[dB.w];
    float4 oA, oB;
    float z;
    z = as0 + ad0 + f0.x * w0 + f0.y * w1 + f0.z * w2 + b;
    oA.x = 1.0f / (1.0f + __expf(-z));
    z = as1 + ad1 + f0.w * w0 + f1.x * w1 + f1.y * w2 + b;
    oA.y = 1.0f / (1.0f + __expf(-z));
    z = as2 + ad2 + f1.z * w0 + f1.w * w1 + f2.x * w2 + b;
    oA.z = 1.0f / (1.0f + __expf(-z));
    z = as3 + ad3 + f2.y * w0 + f2.z * w1 + f2.w * w2 + b;
    oA.w = 1.0f / (1.0f + __expf(-z));
    z = as4 + ad4 + f3.x * w0 + f3.y * w1 + f3.z * w2 + b;
    oB.x = 1.0f / (1.0f + __expf(-z));
    z = as5 + ad5 + f3.w * w0 + f4.x * w1 + f4.y * w2 + b;
    oB.y = 1.0f / (1.0f + __expf(-z));
    z = as6 + ad6 + f4.z * w0 + f4.w * w1 + f5.x * w2 + b;
    oB.z = 1.0f / (1.0f + __expf(-z));
    z = as7 + ad7 + f5.y * w0 + f5.z * w1 + f5.w * w2 + b;
    oB.w = 1.0f / (1.0f + __expf(-z));
    *reinterpret_cast<float4*>(out + e0) = oA;
    *reinterpret_cast<float4*>(out + e0 + 4) = oB;
}

extern "C" void kernel_launch(void* const* d_in, const int* in_sizes, int n_in,
                              void* d_out, int out_size, void* d_ws, size_t ws_size,
                              hipStream_t stream) {
    const float* x     = (const float*)d_in[0];
    const float* efeat = (const float*)d_in[1];
    const int*   src   = (const int*)d_in[2];
    const int*   dst   = (const int*)d_in[3];
    const float* W1    = (const float*)d_in[4];
    const float* b1    = (const float*)d_in[5];
    const float* W2    = (const float*)d_in[6];
    const float* b2    = (const float*)d_in[7];
    const float* We    = (const float*)d_in[8];
    const float* be    = (const float*)d_in[9];
    float* out = (float*)d_out;

    // 256B-aligned workspace carve-up; ~22 MB total.
    char* p = (char*)d_ws;
    auto alloc = [&](size_t bytes) {
        char* r = p;
        p += (bytes + 255) & ~(size_t)255;
        return r;
    };
    float* c_src   = (float*)alloc((size_t)N_NODES * 4);
    float* c_dst   = (float*)alloc((size_t)N_NODES * 4);
    float* a_s     = (float*)alloc((size_t)N_NODES * 4);
    float* a_d     = (float*)alloc((size_t)N_NODES * 4);
    int*   offs    = (int*)alloc((size_t)(N_NODES + 1) * 4);
    int*   bsum    = (int*)alloc(64 * 4);
    float* w2s     = (float*)alloc(HIDDEN * 4);
    float* w2d     = (float*)alloc(HIDDEN * 4);
    float* w2c     = (float*)alloc(2 * 4);
    unsigned*       pin   = (unsigned*)alloc((size_t)CSPLIT * (N_NODES / 2) * 4);  // 3.2 MB
    unsigned*       pout  = (unsigned*)alloc((size_t)CSPLIT * (N_NODES / 2) * 4);  // 3.2 MB
    unsigned short* epos  = (unsigned short*)alloc((size_t)N_EDGES * 2);           // 1.6 MB
    unsigned short* baser = (unsigned short*)alloc((size_t)CSPLIT * N_NODES * 2);  // 3.2 MB
    int*            csr_src = (int*)alloc((size_t)N_EDGES * 4);                    // 3.2 MB
    unsigned short* yb    = (unsigned short*)alloc((size_t)N_NODES * HIDDEN * 2);  // 6.4 MB
    float2*         t     = (float2*)alloc((size_t)N_NODES * 8);                   // 400 KB

    const int NB_V = (N_NODES + 255) / 256;  // 196

    // CSR build (zero global atomics) + fused degree/scan/w2 prep
    hist2_kernel<<<CSPLIT * 8, 256, 0, stream>>>(src, dst, epos, pin, pout);
    prep_kernel<<<50, 256, 0, stream>>>(pin, pout, c_src, c_dst, offs, bsum,
                                        W2, We, b2, w2s, w2d, w2c);
    scan3_base_kernel<<<NB_V, 256, 0, stream>>>(offs, bsum, pin, baser);

    // fused: CSR fill (scattered stores) overlapped with MFMA layer-1 GEMM
    fill_gemm_kernel<<<NB_E4 + NB_GEMM, 256, 0, stream>>>(src, dst, epos, offs, baser,
                                                          csr_src, x, c_src, W1, yb);

    // fused gather1 + relu + layer-2 dots -> t (2 nodes/wave)
    gather_t_kernel<<<N_NODES / 8, 256, 0, stream>>>(yb, offs, csr_src, c_src, c_dst,
                                                     b1, w2s, w2d, t);

    // layer-2 scalar gather -> a_s, a_d
    gather2_kernel<<<N_NODES / 16, 256, 0, stream>>>(t, offs, csr_src, c_dst, w2c, a_s, a_d);

    // edge output
    edge_out_kernel<<<(N_EDGES / 8 + 255) / 256, 256, 0, stream>>>(src, dst, efeat, We, be,
                                                                   a_s, a_d, out);
}

// Round 14
// 93.629 us; speedup vs baseline: 2.8200x; 1.0403x over previous
//
#include <hip/hip_runtime.h>
#include <math.h>
#include <stdint.h>

#define N_NODES 50000
#define N_EDGES 800000
#define IN_FEATS 128
#define HIDDEN 64

// CSR build: 32 edge-chunks x (in|out) x 4 node-quarters, counts in LDS (packed
// 2 nodes per u32). The in-histogram pass ALSO emits each edge's slot index
// (epos, u16) so the CSR fill is a single coalesced pass. Zero global atomics
// (r6 post-mortem: device atomics write ~32B through to HBM each; spreading
// them doesn't help -- only reducing their count to zero does).
#define CSPLIT 32
#define CHUNK (N_EDGES / CSPLIT)   // 25000 edges, exact
#define NQUART (N_NODES / 4)       // 12500 nodes per quarter
#define NQWORDS (NQUART / 2)       // 6250 packed u32 (25 KB LDS)

#define NB_HIST 256                // 32 chunks x 2 kinds x 4 quarters
#define NB_E4 782                  // ceil(200000/256) edge-quad blocks
#define NB_GEMM 782                // ceil(50000/64) 64-row MFMA tiles

typedef __attribute__((ext_vector_type(8))) short bf16x8;
typedef __attribute__((ext_vector_type(4))) float f32x4;

__device__ __forceinline__ unsigned short f2bf(float f) {
    unsigned u = __float_as_uint(f);
    u = (u + 0x7FFF + ((u >> 16) & 1)) >> 16;  // RNE
    return (unsigned short)u;
}

// scaled accumulate of a bf16x8 row (uint4) with per-edge c_src factor
#define ACC8F(A, r, cs)                                        \
    A[0] = fmaf(cs, __uint_as_float((r).x << 16), A[0]);       \
    A[1] = fmaf(cs, __uint_as_float((r).x & 0xffff0000u), A[1]); \
    A[2] = fmaf(cs, __uint_as_float((r).y << 16), A[2]);       \
    A[3] = fmaf(cs, __uint_as_float((r).y & 0xffff0000u), A[3]); \
    A[4] = fmaf(cs, __uint_as_float((r).z << 16), A[4]);       \
    A[5] = fmaf(cs, __uint_as_float((r).z & 0xffff0000u), A[5]); \
    A[6] = fmaf(cs, __uint_as_float((r).w << 16), A[6]);       \
    A[7] = fmaf(cs, __uint_as_float((r).w & 0xffff0000u), A[7]);

// --- FUSED launch 1: blocks [0, NB_HIST) = per-(chunk,kind,quarter) packed
//     histograms (LDS atomics, low HBM) ; blocks [NB_HIST, +NB_GEMM) = MFMA
//     GEMM yb = bf16(x @ W1), UNSCALED (c_src applied at gather time -- gemm
//     has no deps so it hides under the histogram pass). ---
__global__ __launch_bounds__(256) void hist_gemm_kernel(const int* __restrict__ src,
                                                        const int* __restrict__ dst,
                                                        unsigned short* __restrict__ epos,
                                                        unsigned* __restrict__ pin,
                                                        unsigned* __restrict__ pout,
                                                        const float* __restrict__ x,
                                                        const float* __restrict__ W,
                                                        unsigned short* __restrict__ yb) {
    __shared__ union {
        unsigned cnt[NQWORDS];   // 25 KB (hist blocks)
        bf16x8 bfrag[16][64];    // 16 KB (gemm blocks)
    } u;
    if (blockIdx.x < NB_HIST) {
        int b = blockIdx.x;
        int c = b >> 3;
        int kind = (b >> 2) & 1;   // 0 = in (dst) + epos, 1 = out (src)
        int quar = b & 3;
        int lo = quar * NQUART;
        for (int i = threadIdx.x; i < NQWORDS; i += 256) u.cnt[i] = 0;
        __syncthreads();
        if (kind == 0) {
            const int4* d4 = reinterpret_cast<const int4*>(dst + c * CHUNK);
            for (int i = threadIdx.x; i < CHUNK / 4; i += 256) {
                int4 d = d4[i];
                int e = c * CHUNK + i * 4;
                unsigned q, old;
                q = (unsigned)(d.x - lo);
                if (q < NQUART) { old = atomicAdd(&u.cnt[q >> 1], 1u << ((q & 1) * 16));
                                  epos[e + 0] = (unsigned short)(old >> ((q & 1) * 16)); }
                q = (unsigned)(d.y - lo);
                if (q < NQUART) { old = atomicAdd(&u.cnt[q >> 1], 1u << ((q & 1) * 16));
                                  epos[e + 1] = (unsigned short)(old >> ((q & 1) * 16)); }
                q = (unsigned)(d.z - lo);
                if (q < NQUART) { old = atomicAdd(&u.cnt[q >> 1], 1u << ((q & 1) * 16));
                                  epos[e + 2] = (unsigned short)(old >> ((q & 1) * 16)); }
                q = (unsigned)(d.w - lo);
                if (q < NQUART) { old = atomicAdd(&u.cnt[q >> 1], 1u << ((q & 1) * 16));
                                  epos[e + 3] = (unsigned short)(old >> ((q & 1) * 16)); }
            }
        } else {
            const int4* s4 = reinterpret_cast<const int4*>(src + c * CHUNK);
            for (int i = threadIdx.x; i < CHUNK / 4; i += 256) {
                int4 s = s4[i];
                unsigned q;
                q = (unsigned)(s.x - lo); if (q < NQUART) atomicAdd(&u.cnt[q >> 1], 1u << ((q & 1) * 16));
                q = (unsigned)(s.y - lo); if (q < NQUART) atomicAdd(&u.cnt[q >> 1], 1u << ((q & 1) * 16));
                q = (unsigned)(s.z - lo); if (q < NQUART) atomicAdd(&u.cnt[q >> 1], 1u << ((q & 1) * 16));
                q = (unsigned)(s.w - lo); if (q < NQUART) atomicAdd(&u.cnt[q >> 1], 1u << ((q & 1) * 16));
            }
        }
        __syncthreads();
        // global layout: word w = node/2
        unsigned* outp = (kind ? pout : pin) + c * (N_NODES / 2) + quar * NQWORDS;
        for (int i = threadIdx.x; i < NQWORDS; i += 256) outp[i] = u.cnt[i];
        return;
    }
    // ---- MFMA GEMM: yb = bf16(x @ W1), unscaled ----
    // C layout (m89): col = lane&15, row = (lane>>4)*4 + reg.
    int gb = blockIdx.x - NB_HIST;
    for (int idx = threadIdx.x; idx < 16 * 64; idx += 256) {
        int f = idx >> 6, l = idx & 63;
        int nt = f >> 2, kt = f & 3;
        int col = nt * 16 + (l & 15);
        int k0 = kt * 32 + (l >> 4) * 8;
        bf16x8 bv;
#pragma unroll
        for (int j = 0; j < 8; ++j) bv[j] = (short)f2bf(W[(k0 + j) * HIDDEN + col]);
        u.bfrag[f][l] = bv;
    }
    __syncthreads();
    int wid = threadIdx.x >> 6, l = threadIdx.x & 63;
    bf16x8 Breg[16];
#pragma unroll
    for (int f = 0; f < 16; ++f) Breg[f] = u.bfrag[f][l];

    int row0 = gb * 64 + wid * 16;  // this wave's 16-row tile
    int arow = row0 + (l & 15);
    int asafe = min(arow, N_NODES - 1);  // clamp OOB rows (stores guarded)
    const float* xr = x + (size_t)asafe * IN_FEATS + (l >> 4) * 8;
    f32x4 acc0 = {0.f, 0.f, 0.f, 0.f};
    f32x4 acc1 = {0.f, 0.f, 0.f, 0.f};
    f32x4 acc2 = {0.f, 0.f, 0.f, 0.f};
    f32x4 acc3 = {0.f, 0.f, 0.f, 0.f};
#pragma unroll
    for (int kt = 0; kt < 4; ++kt) {
        float4 a0 = *reinterpret_cast<const float4*>(xr + kt * 32);
        float4 a1 = *reinterpret_cast<const float4*>(xr + kt * 32 + 4);
        bf16x8 av;
        av[0] = (short)f2bf(a0.x); av[1] = (short)f2bf(a0.y);
        av[2] = (short)f2bf(a0.z); av[3] = (short)f2bf(a0.w);
        av[4] = (short)f2bf(a1.x); av[5] = (short)f2bf(a1.y);
        av[6] = (short)f2bf(a1.z); av[7] = (short)f2bf(a1.w);
        acc0 = __builtin_amdgcn_mfma_f32_16x16x32_bf16(av, Breg[0 * 4 + kt], acc0, 0, 0, 0);
        acc1 = __builtin_amdgcn_mfma_f32_16x16x32_bf16(av, Breg[1 * 4 + kt], acc1, 0, 0, 0);
        acc2 = __builtin_amdgcn_mfma_f32_16x16x32_bf16(av, Breg[2 * 4 + kt], acc2, 0, 0, 0);
        acc3 = __builtin_amdgcn_mfma_f32_16x16x32_bf16(av, Breg[3 * 4 + kt], acc3, 0, 0, 0);
    }
#pragma unroll
    for (int i = 0; i < 4; ++i) {
        int row = row0 + (l >> 4) * 4 + i;
        if (row < N_NODES) {
            unsigned short* yr = yb + (size_t)row * HIDDEN + (l & 15);
            yr[0]  = f2bf(acc0[i]);
            yr[16] = f2bf(acc1[i]);
            yr[32] = f2bf(acc2[i]);
            yr[48] = f2bf(acc3[i]);
        }
    }
}

// --- fused: degree-sum + c_src/c_dst + per-block exclusive scan (blocks 0..48,
//     1024 nodes each, 4/thread) ; block 49 = w2prep (w2s=W2@Ws, w2d=W2@Wd) ---
__global__ __launch_bounds__(256) void prep_kernel(const unsigned* __restrict__ pin,
                                                   const unsigned* __restrict__ pout,
                                                   float* __restrict__ cs,
                                                   float* __restrict__ cd,
                                                   int* __restrict__ offs,
                                                   int* __restrict__ bsum,
                                                   const float* __restrict__ W2,
                                                   const float* __restrict__ We,
                                                   const float* __restrict__ b2,
                                                   float* __restrict__ w2s,
                                                   float* __restrict__ w2d,
                                                   float* __restrict__ w2c) {
    int b = blockIdx.x;
    int t = threadIdx.x;
    if (b == 49) {  // w2prep tail block (no barriers on this path)
        if (t < 64) {
            float s = 0.f, d = 0.f;
            for (int j = 0; j < HIDDEN; ++j) {
                float w = W2[t * HIDDEN + j];
                s = fmaf(w, We[j], s);
                d = fmaf(w, We[HIDDEN + j], d);
            }
            w2s[t] = s;
            w2d[t] = d;
        } else if (t == 64) {
            float s = 0.f, d = 0.f;
            for (int j = 0; j < HIDDEN; ++j) {
                s = fmaf(We[j], b2[j], s);
                d = fmaf(We[HIDDEN + j], b2[j], d);
            }
            w2c[0] = s;
            w2c[1] = d;
        }
        return;
    }
    __shared__ int sums[256];
    int v0 = b * 1024 + t * 4;
    bool ok = v0 < N_NODES;
    unsigned si0 = 0, si1 = 0, si2 = 0, si3 = 0;
    unsigned so0 = 0, so1 = 0, so2 = 0, so3 = 0;
    if (ok) {
        int w0 = v0 >> 1;  // even (v0 % 4 == 0) -> uint2 aligned
#pragma unroll
        for (int c = 0; c < CSPLIT; ++c) {
            uint2 a = *reinterpret_cast<const uint2*>(pin + (size_t)c * (N_NODES / 2) + w0);
            uint2 o = *reinterpret_cast<const uint2*>(pout + (size_t)c * (N_NODES / 2) + w0);
            si0 += a.x & 0xffffu; si1 += a.x >> 16;
            si2 += a.y & 0xffffu; si3 += a.y >> 16;
            so0 += o.x & 0xffffu; so1 += o.x >> 16;
            so2 += o.y & 0xffffu; so3 += o.y >> 16;
        }
        *reinterpret_cast<float4*>(cs + v0) =
            make_float4(rsqrtf(fmaxf((float)so0, 1.f)), rsqrtf(fmaxf((float)so1, 1.f)),
                        rsqrtf(fmaxf((float)so2, 1.f)), rsqrtf(fmaxf((float)so3, 1.f)));
        *reinterpret_cast<float4*>(cd + v0) =
            make_float4(rsqrtf(fmaxf((float)si0, 1.f)), rsqrtf(fmaxf((float)si1, 1.f)),
                        rsqrtf(fmaxf((float)si2, 1.f)), rsqrtf(fmaxf((float)si3, 1.f)));
    }
    int d0 = (int)si0, d1 = (int)si1, d2 = (int)si2, d3 = (int)si3;
    sums[t] = d0 + d1 + d2 + d3;
    __syncthreads();
    for (int o = 1; o < 256; o <<= 1) {
        int v = (t >= o) ? sums[t - o] : 0;
        __syncthreads();
        sums[t] += v;
        __syncthreads();
    }
    int excl = (t == 0) ? 0 : sums[t - 1];
    if (ok) {
        *reinterpret_cast<int4*>(offs + v0) =
            make_int4(excl, excl + d0, excl + d0 + d1, excl + d0 + d1 + d2);
    }
    if (t == 255) bsum[b] = sums[255];
}

// --- finalize offs + RELATIVE per-chunk base offsets (u16: rel <= in-deg[v]);
//     the 49-entry bsum scan runs redundantly per block (cheaper than a launch) ---
__global__ __launch_bounds__(256) void scan3_base_kernel(int* __restrict__ offs,
                                                         const int* __restrict__ bsum,
                                                         const unsigned* __restrict__ pin,
                                                         unsigned short* __restrict__ baser) {
    __shared__ int sbase[64];
    int t = threadIdx.x;
    if (t < 64) {
        int val = (t < 49) ? bsum[t] : 0;
        int s = val;
#pragma unroll
        for (int o = 1; o < 64; o <<= 1) {
            int u = __shfl_up(s, o, 64);
            if (t >= o) s += u;
        }
        sbase[t] = s - val;  // exclusive
    }
    __syncthreads();
    int v = blockIdx.x * 256 + t;
    if (v >= N_NODES) return;
    int off = offs[v] + sbase[v >> 10];
    offs[v] = off;
    int rel = 0;
    int sh = (v & 1) * 16;
#pragma unroll
    for (int c = 0; c < CSPLIT; ++c) {
        baser[(size_t)c * N_NODES + v] = (unsigned short)rel;
        rel += (int)((pin[(size_t)c * (N_NODES / 2) + (v >> 1)] >> sh) & 0xffffu);
    }
    if (v == 0) offs[N_NODES] = N_EDGES;
}

// --- CSR fill: slot = offs[dst] + baser[c][dst] + epos ---
__global__ __launch_bounds__(256) void fill_kernel(const int* __restrict__ src,
                                                   const int* __restrict__ dst,
                                                   const unsigned short* __restrict__ epos,
                                                   const int* __restrict__ offs,
                                                   const unsigned short* __restrict__ baser,
                                                   int* __restrict__ csr_src) {
    int t = blockIdx.x * 256 + threadIdx.x;
    int e0 = t * 4;
    if (e0 >= N_EDGES) return;
    int c = e0 / CHUNK;  // CHUNK % 4 == 0 -> uniform over the 4 edges
    const unsigned short* brc = baser + (size_t)c * N_NODES;
    int4 s = *reinterpret_cast<const int4*>(src + e0);
    int4 d = *reinterpret_cast<const int4*>(dst + e0);
    ushort4 ep = *reinterpret_cast<const ushort4*>(epos + e0);
    csr_src[offs[d.x] + brc[d.x] + ep.x] = s.x;
    csr_src[offs[d.y] + brc[d.y] + ep.y] = s.y;
    csr_src[offs[d.z] + brc[d.z] + ep.z] = s.z;
    csr_src[offs[d.w] + brc[d.w] + ep.w] = s.w;
}

// --- layer1 gather, TWO nodes per wave interleaved; y rows are UNSCALED, the
//     c_src[src] factor is applied per-edge via fmaf (200 KB table, L2-hot).
//     8 slots x 8 lanes x uint4; relu/bias + layer-2 collapse -> t[v0], t[v1] ---
__global__ __launch_bounds__(256) void gather_t_kernel(const unsigned short* __restrict__ y,
                                                       const int* __restrict__ offs,
                                                       const int* __restrict__ csr_src,
                                                       const float* __restrict__ c_src,
                                                       const float* __restrict__ c_dst,
                                                       const float* __restrict__ b1,
                                                       const float* __restrict__ w2s,
                                                       const float* __restrict__ w2d,
                                                       float2* __restrict__ t) {
    int wid = threadIdx.x >> 6, l = threadIdx.x & 63;
    int slot = l >> 3, q8 = l & 7;      // 8 edge-slots x 8 feature-octets
    int v0 = blockIdx.x * 8 + wid * 2;  // grid exact: 6250 * 8 = 50000
    int v1 = v0 + 1;
    int beg0 = offs[v0], end0 = offs[v0 + 1], end1 = offs[v0 + 2];
    int k0 = beg0, k1 = end0;  // v1's edges start where v0's end
    float acc0[8] = {0.f, 0.f, 0.f, 0.f, 0.f, 0.f, 0.f, 0.f};
    float acc1[8] = {0.f, 0.f, 0.f, 0.f, 0.f, 0.f, 0.f, 0.f};
    // dual main loop: 2 independent gather streams in flight
    while (k0 + 8 <= end0 && k1 + 8 <= end1) {
        int sA = csr_src[k0 + slot];
        int sB = csr_src[k1 + slot];
        float csA = c_src[sA];
        float csB = c_src[sB];
        uint4 rA = *reinterpret_cast<const uint4*>(y + (size_t)sA * HIDDEN + q8 * 8);
        uint4 rB = *reinterpret_cast<const uint4*>(y + (size_t)sB * HIDDEN + q8 * 8);
        ACC8F(acc0, rA, csA);
        ACC8F(acc1, rB, csB);
        k0 += 8;
        k1 += 8;
    }
    while (k0 + 8 <= end0) {
        int s = csr_src[k0 + slot];
        float cs = c_src[s];
        uint4 r = *reinterpret_cast<const uint4*>(y + (size_t)s * HIDDEN + q8 * 8);
        ACC8F(acc0, r, cs);
        k0 += 8;
    }
    while (k1 + 8 <= end1) {
        int s = csr_src[k1 + slot];
        float cs = c_src[s];
        uint4 r = *reinterpret_cast<const uint4*>(y + (size_t)s * HIDDEN + q8 * 8);
        ACC8F(acc1, r, cs);
        k1 += 8;
    }
    if (slot < end0 - k0) {
        int s = csr_src[k0 + slot];
        float cs = c_src[s];
        uint4 r = *reinterpret_cast<const uint4*>(y + (size_t)s * HIDDEN + q8 * 8);
        ACC8F(acc0, r, cs);
    }
    if (slot < end1 - k1) {
        int s = csr_src[k1 + slot];
        float cs = c_src[s];
        uint4 r = *reinterpret_cast<const uint4*>(y + (size_t)s * HIDDEN + q8 * 8);
        ACC8F(acc1, r, cs);
    }
    // combine 8 slots (lanes with equal q8), both nodes
#pragma unroll
    for (int i = 0; i < 8; ++i) {
        acc0[i] += __shfl_xor(acc0[i], 8, 64);
        acc0[i] += __shfl_xor(acc0[i], 16, 64);
        acc0[i] += __shfl_xor(acc0[i], 32, 64);
        acc1[i] += __shfl_xor(acc1[i], 8, 64);
        acc1[i] += __shfl_xor(acc1[i], 16, 64);
        acc1[i] += __shfl_xor(acc1[i], 32, 64);
    }
    float4 ba = *reinterpret_cast<const float4*>(b1 + q8 * 8);
    float4 bb = *reinterpret_cast<const float4*>(b1 + q8 * 8 + 4);
    float4 wsa = *reinterpret_cast<const float4*>(w2s + q8 * 8);
    float4 wsb = *reinterpret_cast<const float4*>(w2s + q8 * 8 + 4);
    float4 wda = *reinterpret_cast<const float4*>(w2d + q8 * 8);
    float4 wdb = *reinterpret_cast<const float4*>(w2d + q8 * 8 + 4);
    float c0 = c_dst[v0], c1 = c_dst[v1];
    float h0, h1, h2, h3, h4, h5, h6, h7;
    h0 = fmaxf(fmaf(c0, acc0[0], ba.x), 0.f);
    h1 = fmaxf(fmaf(c0, acc0[1], ba.y), 0.f);
    h2 = fmaxf(fmaf(c0, acc0[2], ba.z), 0.f);
    h3 = fmaxf(fmaf(c0, acc0[3], ba.w), 0.f);
    h4 = fmaxf(fmaf(c0, acc0[4], bb.x), 0.f);
    h5 = fmaxf(fmaf(c0, acc0[5], bb.y), 0.f);
    h6 = fmaxf(fmaf(c0, acc0[6], bb.z), 0.f);
    h7 = fmaxf(fmaf(c0, acc0[7], bb.w), 0.f);
    float ps0 = h0 * wsa.x + h1 * wsa.y + h2 * wsa.z + h3 * wsa.w
              + h4 * wsb.x + h5 * wsb.y + h6 * wsb.z + h7 * wsb.w;
    float pd0 = h0 * wda.x + h1 * wda.y + h2 * wda.z + h3 * wda.w
              + h4 * wdb.x + h5 * wdb.y + h6 * wdb.z + h7 * wdb.w;
    h0 = fmaxf(fmaf(c1, acc1[0], ba.x), 0.f);
    h1 = fmaxf(fmaf(c1, acc1[1], ba.y), 0.f);
    h2 = fmaxf(fmaf(c1, acc1[2], ba.z), 0.f);
    h3 = fmaxf(fmaf(c1, acc1[3], ba.w), 0.f);
    h4 = fmaxf(fmaf(c1, acc1[4], bb.x), 0.f);
    h5 = fmaxf(fmaf(c1, acc1[5], bb.y), 0.f);
    h6 = fmaxf(fmaf(c1, acc1[6], bb.z), 0.f);
    h7 = fmaxf(fmaf(c1, acc1[7], bb.w), 0.f);
    float ps1 = h0 * wsa.x + h1 * wsa.y + h2 * wsa.z + h3 * wsa.w
              + h4 * wsb.x + h5 * wsb.y + h6 * wsb.z + h7 * wsb.w;
    float pd1 = h0 * wda.x + h1 * wda.y + h2 * wda.z + h3 * wda.w
              + h4 * wdb.x + h5 * wdb.y + h6 * wdb.z + h7 * wdb.w;
#pragma unroll
    for (int o = 1; o <= 4; o <<= 1) {
        ps0 += __shfl_xor(ps0, o, 64);
        pd0 += __shfl_xor(pd0, o, 64);
        ps1 += __shfl_xor(ps1, o, 64);
        pd1 += __shfl_xor(pd1, o, 64);
    }
    if (l == 0) {
        float cs0 = c_src[v0], cs1 = c_src[v1];
        // t[v0], t[v1] are consecutive float2 -> one float4 store (v0 even)
        *reinterpret_cast<float4*>(t + v0) =
            make_float4(cs0 * ps0, cs0 * pd0, cs1 * ps1, cs1 * pd1);
    }
}

// --- layer2 scalar gather: a_s[v] = c_dst[v]*sum(t_s over in-edges) + Ws.b2 ---
__global__ __launch_bounds__(256) void gather2_kernel(const float2* __restrict__ t,
                                                      const int* __restrict__ offs,
                                                      const int* __restrict__ csr_src,
                                                      const float* __restrict__ c_dst,
                                                      const float* __restrict__ w2c,
                                                      float* __restrict__ a_s,
                                                      float* __restrict__ a_d) {
    int wid = threadIdx.x >> 6, l = threadIdx.x & 63;
    int sub = l >> 4, q = l & 15;
    int v = blockIdx.x * 16 + wid * 4 + sub;  // grid exact: 3125 * 16 = 50000
    int beg = offs[v], end = offs[v + 1];
    float ps = 0.f, pd = 0.f;
    for (int k = beg + q; k < end; k += 16) {
        float2 tv = t[csr_src[k]];
        ps += tv.x;
        pd += tv.y;
    }
#pragma unroll
    for (int o = 1; o <= 8; o <<= 1) {
        ps += __shfl_xor(ps, o, 64);
        pd += __shfl_xor(pd, o, 64);
    }
    if (q == 0) {
        float c = c_dst[v];
        a_s[v] = fmaf(c, ps, w2c[0]);
        a_d[v] = fmaf(c, pd, w2c[1]);
    }
}

// --- out[e] = sigmoid(a_s[src] + a_d[dst] + efeat.Wf + be), 8 edges/thread ---
__global__ __launch_bounds__(256) void edge_out_kernel(const int* __restrict__ src,
                                                       const int* __restrict__ dst,
                                                       const float* __restrict__ efeat,
                                                       const float* __restrict__ We,
                                                       const float* __restrict__ be,
                                                       const float* __restrict__ a_s,
                                                       const float* __restrict__ a_d,
                                                       float* __restrict__ out) {
    int t = blockIdx.x * 256 + threadIdx.x;
    int e0 = t * 8;
    if (e0 >= N_EDGES) return;  // N_EDGES % 8 == 0 -> full octets
    float w0 = We[2 * HIDDEN + 0], w1 = We[2 * HIDDEN + 1], w2 = We[2 * HIDDEN + 2];
    float b = be[0];
    int4 sA = *reinterpret_cast<const int4*>(src + e0);
    int4 sB = *reinterpret_cast<const int4*>(src + e0 + 4);
    int4 dA = *reinterpret_cast<const int4*>(dst + e0);
    int4 dB = *reinterpret_cast<const int4*>(dst + e0 + 4);
    const float4* f = reinterpret_cast<const float4*>(efeat + (long)e0 * 3);
    float4 f0 = f[0], f1 = f[1], f2 = f[2], f3 = f[3], f4 = f[4], f5 = f[5];
    float as0 = a_s[sA.x], as1 = a_s[sA.y], as2 = a_s[sA.z], as3 = a_s[sA.w];
    float as4 = a_s[sB.x], as5 = a_s[sB.y], as6 = a_s[sB.z], as7 = a_s[sB.w];
    float ad0 = a_d[dA.x], ad1 = a_d[dA.y], ad2 = a_d[dA.z], ad3 = a_d[dA.w];
    float ad4 = a_d[dB.x], ad5 = a_d[dB.y], ad6 = a_d[dB.z], ad7 = a_d[dB.w];
    float4 oA, oB;
    float z;
    z = as0 + ad0 + f0.x * w0 + f0.y * w1 + f0.z * w2 + b;
    oA.x = 1.0f / (1.0f + __expf(-z));
    z = as1 + ad1 + f0.w * w0 + f1.x * w1 + f1.y * w2 + b;
    oA.y = 1.0f / (1.0f + __expf(-z));
    z = as2 + ad2 + f1.z * w0 + f1.w * w1 + f2.x * w2 + b;
    oA.z = 1.0f / (1.0f + __expf(-z));
    z = as3 + ad3 + f2.y * w0 + f2.z * w1 + f2.w * w2 + b;
    oA.w = 1.0f / (1.0f + __expf(-z));
    z = as4 + ad4 + f3.x * w0 + f3.y * w1 + f3.z * w2 + b;
    oB.x = 1.0f / (1.0f + __expf(-z));
    z = as5 + ad5 + f3.w * w0 + f4.x * w1 + f4.y * w2 + b;
    oB.y = 1.0f / (1.0f + __expf(-z));
    z = as6 + ad6 + f4.z * w0 + f4.w * w1 + f5.x * w2 + b;
    oB.z = 1.0f / (1.0f + __expf(-z));
    z = as7 + ad7 + f5.y * w0 + f5.z * w1 + f5.w * w2 + b;
    oB.w = 1.0f / (1.0f + __expf(-z));
    *reinterpret_cast<float4*>(out + e0) = oA;
    *reinterpret_cast<float4*>(out + e0 + 4) = oB;
}

extern "C" void kernel_launch(void* const* d_in, const int* in_sizes, int n_in,
                              void* d_out, int out_size, void* d_ws, size_t ws_size,
                              hipStream_t stream) {
    const float* x     = (const float*)d_in[0];
    const float* efeat = (const float*)d_in[1];
    const int*   src   = (const int*)d_in[2];
    const int*   dst   = (const int*)d_in[3];
    const float* W1    = (const float*)d_in[4];
    const float* b1    = (const float*)d_in[5];
    const float* W2    = (const float*)d_in[6];
    const float* b2    = (const float*)d_in[7];
    const float* We    = (const float*)d_in[8];
    const float* be    = (const float*)d_in[9];
    float* out = (float*)d_out;

    // 256B-aligned workspace carve-up; ~22 MB total.
    char* p = (char*)d_ws;
    auto alloc = [&](size_t bytes) {
        char* r = p;
        p += (bytes + 255) & ~(size_t)255;
        return r;
    };
    float* c_src   = (float*)alloc((size_t)N_NODES * 4);
    float* c_dst   = (float*)alloc((size_t)N_NODES * 4);
    float* a_s     = (float*)alloc((size_t)N_NODES * 4);
    float* a_d     = (float*)alloc((size_t)N_NODES * 4);
    int*   offs    = (int*)alloc((size_t)(N_NODES + 1) * 4);
    int*   bsum    = (int*)alloc(64 * 4);
    float* w2s     = (float*)alloc(HIDDEN * 4);
    float* w2d     = (float*)alloc(HIDDEN * 4);
    float* w2c     = (float*)alloc(2 * 4);
    unsigned*       pin   = (unsigned*)alloc((size_t)CSPLIT * (N_NODES / 2) * 4);  // 3.2 MB
    unsigned*       pout  = (unsigned*)alloc((size_t)CSPLIT * (N_NODES / 2) * 4);  // 3.2 MB
    unsigned short* epos  = (unsigned short*)alloc((size_t)N_EDGES * 2);           // 1.6 MB
    unsigned short* baser = (unsigned short*)alloc((size_t)CSPLIT * N_NODES * 2);  // 3.2 MB
    int*            csr_src = (int*)alloc((size_t)N_EDGES * 4);                    // 3.2 MB
    unsigned short* yb    = (unsigned short*)alloc((size_t)N_NODES * HIDDEN * 2);  // 6.4 MB
    float2*         t     = (float2*)alloc((size_t)N_NODES * 8);                   // 400 KB

    const int NB_V = (N_NODES + 255) / 256;  // 196

    // launch 1: histograms (LDS atomics) overlapped with dep-free MFMA GEMM
    hist_gemm_kernel<<<NB_HIST + NB_GEMM, 256, 0, stream>>>(src, dst, epos, pin, pout,
                                                            x, W1, yb);
    // degree/scan/w2 prep ; offs + relative base finalize
    prep_kernel<<<50, 256, 0, stream>>>(pin, pout, c_src, c_dst, offs, bsum,
                                        W2, We, b2, w2s, w2d, w2c);
    scan3_base_kernel<<<NB_V, 256, 0, stream>>>(offs, bsum, pin, baser);
    // CSR fill
    fill_kernel<<<NB_E4, 256, 0, stream>>>(src, dst, epos, offs, baser, csr_src);
    // fused gather1 + relu + layer-2 dots -> t (2 nodes/wave, c_src at gather)
    gather_t_kernel<<<N_NODES / 8, 256, 0, stream>>>(yb, offs, csr_src, c_src, c_dst,
                                                     b1, w2s, w2d, t);
    // layer-2 scalar gather -> a_s, a_d
    gather2_kernel<<<N_NODES / 16, 256, 0, stream>>>(t, offs, csr_src, c_dst, w2c, a_s, a_d);
    // edge output
    edge_out_kernel<<<(N_EDGES / 8 + 255) / 256, 256, 0, stream>>>(src, dst, efeat, We, be,
                                                                   a_s, a_d, out);
}